// Round 1
// baseline (2528.324 us; speedup 1.0000x reference)
//
#include <hip/hip_runtime.h>
#include <math.h>

#define NEG_SLOPE 0.2f

__device__ __forceinline__ float lrelu(float x){ return x > 0.f ? x : NEG_SLOPE*x; }

// ---------------- K0: zero the accumulator/denominator region ----------------
__global__ void k_zero(float4* __restrict__ p, int n4){
  int i = blockIdx.x*blockDim.x + threadIdx.x;
  int stride = gridDim.x*blockDim.x;
  float4 z = make_float4(0.f,0.f,0.f,0.f);
  for (; i < n4; i += stride) p[i] = z;
}

// ---------------- K1: h1[N,128] = x[N,256] @ W1[256,128] (fp32) ----------------
// 128x128 tile per block, BK=32, 256 threads, 16 rows x 4 cols per thread.
__global__ __launch_bounds__(256) void k_gemm1(const float* __restrict__ x,
                                               const float* __restrict__ W,
                                               float* __restrict__ h1, int N){
  __shared__ float xs[32][132];   // x^T tile [k][r], padded stride 132 (16B-aligned, conflict-spread)
  __shared__ float wsh[32][128];  // W tile [k][c]
  int tid = threadIdx.x;
  int cg = tid & 31, rg = tid >> 5;
  int row0 = blockIdx.x * 128;
  float acc[16][4];
  #pragma unroll
  for (int i=0;i<16;i++)
    #pragma unroll
    for (int j=0;j<4;j++) acc[i][j]=0.f;

  for (int kk=0; kk<256; kk+=32){
    #pragma unroll
    for (int it=0; it<4; it++){           // stage x transposed
      int r = it*32 + (tid>>3);
      int kc = (tid&7)*4;
      float4 v = make_float4(0.f,0.f,0.f,0.f);
      int grow = row0 + r;
      if (grow < N) v = *(const float4*)&x[(size_t)grow*256 + kk + kc];
      xs[kc+0][r]=v.x; xs[kc+1][r]=v.y; xs[kc+2][r]=v.z; xs[kc+3][r]=v.w;
    }
    #pragma unroll
    for (int it=0; it<4; it++){           // stage W
      int k = it*8 + (tid>>5);
      int c = (tid&31)*4;
      *(float4*)&wsh[k][c] = *(const float4*)&W[(size_t)(kk+k)*128 + c];
    }
    __syncthreads();
    #pragma unroll
    for (int k=0;k<32;k++){
      float4 b = *(float4*)&wsh[k][cg*4];
      float a[16];
      *(float4*)&a[0]  = *(float4*)&xs[k][rg*16+0];
      *(float4*)&a[4]  = *(float4*)&xs[k][rg*16+4];
      *(float4*)&a[8]  = *(float4*)&xs[k][rg*16+8];
      *(float4*)&a[12] = *(float4*)&xs[k][rg*16+12];
      #pragma unroll
      for (int i=0;i<16;i++){
        acc[i][0] = fmaf(a[i], b.x, acc[i][0]);
        acc[i][1] = fmaf(a[i], b.y, acc[i][1]);
        acc[i][2] = fmaf(a[i], b.z, acc[i][2]);
        acc[i][3] = fmaf(a[i], b.w, acc[i][3]);
      }
    }
    __syncthreads();
  }
  int c0 = cg*4;
  #pragma unroll
  for (int i=0;i<16;i++){
    int grow = row0 + rg*16 + i;
    if (grow < N)
      *(float4*)&h1[(size_t)grow*128 + c0] = make_float4(acc[i][0],acc[i][1],acc[i][2],acc[i][3]);
  }
}

// ---------------- K2: per-(node,head) attention logits layer 1 ----------------
__global__ void k_att1(const float* __restrict__ h1, const float* __restrict__ as_w,
                       const float* __restrict__ ad_w,
                       float* __restrict__ a_s, float* __restrict__ a_d, int N){
  int t = blockIdx.x*blockDim.x + threadIdx.x;
  if (t >= N*8) return;
  int n = t >> 3, h = t & 7;
  const float* hp = &h1[(size_t)n*128 + h*16];
  const float* wsp = &as_w[h*16];
  const float* wdp = &ad_w[h*16];
  float s=0.f, d=0.f;
  #pragma unroll
  for (int j=0;j<16;j++){ float v = hp[j]; s = fmaf(v, wsp[j], s); d = fmaf(v, wdp[j], d); }
  a_s[t] = s; a_d[t] = d;
}

// ---------------- K3: softmax denominators layer 1 (no max-shift) ----------------
__global__ void k_denom1(const int* __restrict__ src, const int* __restrict__ dst,
                         const float* __restrict__ a_s, const float* __restrict__ a_d,
                         float* __restrict__ denom, int E, int EE){
  int e = blockIdx.x*blockDim.x + threadIdx.x;
  if (e >= EE) return;
  int s, d;
  if (e < E){ s = src[e]; d = dst[e]; } else { s = e - E; d = s; }
  const float* as = &a_s[(size_t)s*8];
  const float* ad = &a_d[(size_t)d*8];
  #pragma unroll
  for (int h=0;h<8;h++){
    float ex = __expf(lrelu(as[h]+ad[h]));
    atomicAdd(&denom[(size_t)d*8+h], ex);
  }
}

// ---------------- K4: weighted message scatter layer 1 (wave per edge) ----------------
__global__ void k_scatter1(const int* __restrict__ src, const int* __restrict__ dst,
                           const float* __restrict__ a_s, const float* __restrict__ a_d,
                           const float* __restrict__ denom, const float* __restrict__ h1,
                           float* __restrict__ acc, int E, int EE){
  int gt = blockIdx.x*blockDim.x + threadIdx.x;
  int w = gt >> 6;
  int lane = threadIdx.x & 63;
  int nw = (gridDim.x*blockDim.x) >> 6;
  for (int e = w; e < EE; e += nw){
    int s, d;
    if (e < E){ s = src[e]; d = dst[e]; } else { s = e - E; d = s; }
    float alpha = 0.f;
    if (lane < 8){
      float v = lrelu(a_s[(size_t)s*8+lane] + a_d[(size_t)d*8+lane]);
      alpha = __expf(v) / denom[(size_t)d*8+lane];
    }
    float al = __shfl(alpha, lane>>3);   // head = (lane*2)/16 = lane>>3
    float2 hv = *(const float2*)&h1[(size_t)s*128 + lane*2];
    atomicAdd(&acc[(size_t)d*128 + lane*2    ], hv.x*al);
    atomicAdd(&acc[(size_t)d*128 + lane*2 + 1], hv.y*al);
  }
}

// ---------------- K5: elu + per-node [128]x[128,32] projection + layer-2 logits ----------------
__global__ __launch_bounds__(256) void k_layer2(const float* __restrict__ acc1, const float* __restrict__ b1,
                        const float* __restrict__ W2, const float* __restrict__ as2w,
                        const float* __restrict__ ad2w,
                        float* __restrict__ h2p, float* __restrict__ a_s2,
                        float* __restrict__ a_d2, int N){
  __shared__ float w2s[128][32];  // 16 KB
  __shared__ float hs[8][128];    // 4 KB
  int tid = threadIdx.x;
  #pragma unroll
  for (int it=0; it<16; it++){
    int idx = it*256 + tid;
    ((float*)w2s)[idx] = W2[idx];
  }
  int sub = tid>>5, ln = tid&31;
  int n = blockIdx.x*8 + sub;
  if (n < N){
    #pragma unroll
    for (int j=0;j<4;j++){
      int k = j*32 + ln;
      float v = acc1[(size_t)n*128+k] + b1[k];
      hs[sub][k] = v > 0.f ? v : (__expf(v) - 1.f);   // elu
    }
  }
  __syncthreads();
  if (n >= N) return;
  float o = 0.f;
  #pragma unroll
  for (int k=0;k<128;k++) o = fmaf(hs[sub][k], w2s[k][ln], o);
  h2p[(size_t)n*32+ln] = o;
  float ps = o*as2w[ln], pd = o*ad2w[ln];
  #pragma unroll
  for (int m=16;m;m>>=1){ ps += __shfl_xor(ps,m); pd += __shfl_xor(pd,m); }
  if (ln==0){ a_s2[n]=ps; a_d2[n]=pd; }
}

// ---------------- K6: softmax denominators layer 2 ----------------
__global__ void k_denom2(const int* __restrict__ src, const int* __restrict__ dst,
                         const float* __restrict__ a_s2, const float* __restrict__ a_d2,
                         float* __restrict__ denom2, int E, int EE){
  int e = blockIdx.x*blockDim.x + threadIdx.x;
  if (e >= EE) return;
  int s, d;
  if (e < E){ s = src[e]; d = dst[e]; } else { s = e - E; d = s; }
  atomicAdd(&denom2[d], __expf(lrelu(a_s2[s]+a_d2[d])));
}

// ---------------- K7: weighted message scatter layer 2 (32 lanes per edge) ----------------
__global__ void k_scatter2(const int* __restrict__ src, const int* __restrict__ dst,
                           const float* __restrict__ a_s2, const float* __restrict__ a_d2,
                           const float* __restrict__ denom2, const float* __restrict__ h2p,
                           float* __restrict__ acc2, int E, int EE){
  int gt = blockIdx.x*blockDim.x + threadIdx.x;
  int hw = gt >> 5;
  int ln = threadIdx.x & 31;
  int nhw = (gridDim.x*blockDim.x) >> 5;
  for (int e = hw; e < EE; e += nhw){
    int s, d;
    if (e < E){ s = src[e]; d = dst[e]; } else { s = e - E; d = s; }
    float al = __expf(lrelu(a_s2[s]+a_d2[d])) / denom2[d];
    atomicAdd(&acc2[(size_t)d*32+ln], h2p[(size_t)s*32+ln]*al);
  }
}

// ---------------- K8: bias + log_softmax over 32 classes ----------------
__global__ void k_out(const float* __restrict__ acc2, const float* __restrict__ b2,
                      float* __restrict__ out, int N){
  int tid = threadIdx.x;
  int sub = tid>>5, ln = tid&31;
  int n = blockIdx.x*8 + sub;
  if (n >= N) return;
  float v = acc2[(size_t)n*32+ln] + b2[ln];
  float mx = v;
  #pragma unroll
  for (int m=16;m;m>>=1) mx = fmaxf(mx, __shfl_xor(mx,m));
  float ex = __expf(v-mx);
  float sm = ex;
  #pragma unroll
  for (int m=16;m;m>>=1) sm += __shfl_xor(sm,m);
  out[(size_t)n*32+ln] = v - mx - __logf(sm);
}

extern "C" void kernel_launch(void* const* d_in, const int* in_sizes, int n_in,
                              void* d_out, int out_size, void* d_ws, size_t ws_size,
                              hipStream_t stream){
  const float* x   = (const float*)d_in[0];
  const int*   ei  = (const int*)d_in[1];
  // d_in[2] = edge_weight (unused by GATConv)
  const float* W1  = (const float*)d_in[3];
  const float* as1 = (const float*)d_in[4];
  const float* ad1 = (const float*)d_in[5];
  const float* b1  = (const float*)d_in[6];
  const float* W2  = (const float*)d_in[7];
  const float* as2 = (const float*)d_in[8];
  const float* ad2 = (const float*)d_in[9];
  const float* b2  = (const float*)d_in[10];

  int N  = in_sizes[0] / 256;
  int E  = in_sizes[2];
  int EE = E + N;
  const int* src = ei;
  const int* dst = ei + E;

  float* w = (float*)d_ws;
  float* acc1   = w; w += (size_t)N*128;
  float* denom1 = w; w += (size_t)N*8;
  float* acc2   = w; w += (size_t)N*32;
  float* denom2 = w; w += (size_t)N;
  size_t zcount = (size_t)N*169;          // contiguous zero region above
  float* h1     = w; w += (size_t)N*128;
  float* a_s1   = w; w += (size_t)N*8;
  float* a_d1   = w; w += (size_t)N*8;
  float* h2p    = w; w += (size_t)N*32;
  float* a_s2   = w; w += (size_t)N;
  float* a_d2   = w; w += (size_t)N;
  float* out    = (float*)d_out;

  int zn4 = (int)((zcount+3)/4);
  hipLaunchKernelGGL(k_zero, dim3(2048), dim3(256), 0, stream, (float4*)d_ws, zn4);
  hipLaunchKernelGGL(k_gemm1, dim3((N+127)/128), dim3(256), 0, stream, x, W1, h1, N);
  hipLaunchKernelGGL(k_att1, dim3((N*8+255)/256), dim3(256), 0, stream, h1, as1, ad1, a_s1, a_d1, N);
  hipLaunchKernelGGL(k_denom1, dim3((EE+255)/256), dim3(256), 0, stream, src, dst, a_s1, a_d1, denom1, E, EE);
  hipLaunchKernelGGL(k_scatter1, dim3(16384), dim3(256), 0, stream, src, dst, a_s1, a_d1, denom1, h1, acc1, E, EE);
  hipLaunchKernelGGL(k_layer2, dim3((N+7)/8), dim3(256), 0, stream, acc1, b1, W2, as2, ad2, h2p, a_s2, a_d2, N);
  hipLaunchKernelGGL(k_denom2, dim3((EE+255)/256), dim3(256), 0, stream, src, dst, a_s2, a_d2, denom2, E, EE);
  hipLaunchKernelGGL(k_scatter2, dim3(16384), dim3(256), 0, stream, src, dst, a_s2, a_d2, denom2, h2p, acc2, E, EE);
  hipLaunchKernelGGL(k_out, dim3((N+7)/8), dim3(256), 0, stream, acc2, b2, out, N);
}

// Round 4
// 681.208 us; speedup vs baseline: 3.7115x; 3.7115x over previous
//
#include <hip/hip_runtime.h>
#include <math.h>

#define NEG_SLOPE 0.2f

__device__ __forceinline__ float lrelu(float x){ return x > 0.f ? x : NEG_SLOPE*x; }

// ---------------- K0: zero a region of ints ----------------
__global__ void k_zero(int* __restrict__ p, int n){
  int i = blockIdx.x*blockDim.x + threadIdx.x;
  int stride = gridDim.x*blockDim.x;
  for (; i < n; i += stride) p[i] = 0;
}

// ---------------- K1: h1[N,128] = x[N,256] @ W1[256,128] (fp32) ----------------
__global__ __launch_bounds__(256) void k_gemm1(const float* __restrict__ x,
                                               const float* __restrict__ W,
                                               float* __restrict__ h1, int N){
  __shared__ float xs[32][132];
  __shared__ float wsh[32][128];
  int tid = threadIdx.x;
  int cg = tid & 31, rg = tid >> 5;
  int row0 = blockIdx.x * 128;
  float acc[16][4];
  #pragma unroll
  for (int i=0;i<16;i++)
    #pragma unroll
    for (int j=0;j<4;j++) acc[i][j]=0.f;

  for (int kk=0; kk<256; kk+=32){
    #pragma unroll
    for (int it=0; it<4; it++){
      int r = it*32 + (tid>>3);
      int kc = (tid&7)*4;
      float4 v = make_float4(0.f,0.f,0.f,0.f);
      int grow = row0 + r;
      if (grow < N) v = *(const float4*)&x[(size_t)grow*256 + kk + kc];
      xs[kc+0][r]=v.x; xs[kc+1][r]=v.y; xs[kc+2][r]=v.z; xs[kc+3][r]=v.w;
    }
    #pragma unroll
    for (int it=0; it<4; it++){
      int k = it*8 + (tid>>5);
      int c = (tid&31)*4;
      *(float4*)&wsh[k][c] = *(const float4*)&W[(size_t)(kk+k)*128 + c];
    }
    __syncthreads();
    #pragma unroll
    for (int k=0;k<32;k++){
      float4 b = *(float4*)&wsh[k][cg*4];
      float a[16];
      *(float4*)&a[0]  = *(float4*)&xs[k][rg*16+0];
      *(float4*)&a[4]  = *(float4*)&xs[k][rg*16+4];
      *(float4*)&a[8]  = *(float4*)&xs[k][rg*16+8];
      *(float4*)&a[12] = *(float4*)&xs[k][rg*16+12];
      #pragma unroll
      for (int i=0;i<16;i++){
        acc[i][0] = fmaf(a[i], b.x, acc[i][0]);
        acc[i][1] = fmaf(a[i], b.y, acc[i][1]);
        acc[i][2] = fmaf(a[i], b.z, acc[i][2]);
        acc[i][3] = fmaf(a[i], b.w, acc[i][3]);
      }
    }
    __syncthreads();
  }
  int c0 = cg*4;
  #pragma unroll
  for (int i=0;i<16;i++){
    int grow = row0 + rg*16 + i;
    if (grow < N)
      *(float4*)&h1[(size_t)grow*128 + c0] = make_float4(acc[i][0],acc[i][1],acc[i][2],acc[i][3]);
  }
}

// ---------------- K2: per-(node,head) attention logits layer 1 ----------------
__global__ void k_att1(const float* __restrict__ h1, const float* __restrict__ as_w,
                       const float* __restrict__ ad_w,
                       float* __restrict__ a_s, float* __restrict__ a_d, int N){
  int t = blockIdx.x*blockDim.x + threadIdx.x;
  if (t >= N*8) return;
  int n = t >> 3, h = t & 7;
  const float* hp = &h1[(size_t)n*128 + h*16];
  const float* wsp = &as_w[h*16];
  const float* wdp = &ad_w[h*16];
  float s=0.f, d=0.f;
  #pragma unroll
  for (int j=0;j<16;j++){ float v = hp[j]; s = fmaf(v, wsp[j], s); d = fmaf(v, wdp[j], d); }
  a_s[t] = s; a_d[t] = d;
}

// ---------------- CSR build: histogram of in-degrees ----------------
__global__ void k_hist(const int* __restrict__ dst, int* __restrict__ deg, int E, int EE){
  int e = blockIdx.x*blockDim.x + threadIdx.x;
  if (e >= EE) return;
  int d = (e < E) ? dst[e] : (e - E);
  atomicAdd(&deg[d], 1);
}

// ---------------- CSR build: per-1024-block reduction ----------------
__global__ __launch_bounds__(256) void k_scan1(const int* __restrict__ deg, int* __restrict__ bsum){
  __shared__ int sred[256];
  int b = blockIdx.x, t = threadIdx.x;
  int4 v = *(const int4*)&deg[b*1024 + t*4];   // deg padded to 1024-multiple
  sred[t] = v.x+v.y+v.z+v.w;
  __syncthreads();
  for (int off=128; off; off>>=1){ if (t<off) sred[t]+=sred[t+off]; __syncthreads(); }
  if (t==0) bsum[b]=sred[0];
}

// ---------------- CSR build: scan of block sums (single tiny block) ----------------
__global__ void k_scan2(int* __restrict__ bsum, int nb){
  if (threadIdx.x==0 && blockIdx.x==0){
    int acc=0;
    for (int i=0;i<nb;i++){ int v=bsum[i]; bsum[i]=acc; acc+=v; }
  }
}

// ---------------- CSR build: final per-element exclusive scan ----------------
__global__ __launch_bounds__(256) void k_scan3(const int* __restrict__ deg, const int* __restrict__ bsum,
                        int* __restrict__ start, int* __restrict__ cursor, int N, int EE){
  __shared__ int sc[256];
  int b = blockIdx.x, t = threadIdx.x;
  int bi = b*1024 + t*4;
  int4 v = *(const int4*)&deg[bi];
  int ts = v.x+v.y+v.z+v.w;
  sc[t]=ts; __syncthreads();
  for (int off=1; off<256; off<<=1){
    int p = (t>=off)? sc[t-off] : 0;
    __syncthreads();
    sc[t]+=p;
    __syncthreads();
  }
  int excl = sc[t]-ts + bsum[b];
  int p0=excl, p1=p0+v.x, p2=p1+v.y, p3=p2+v.z;
  if (bi+0<N){ start[bi+0]=p0; cursor[bi+0]=p0; }
  if (bi+1<N){ start[bi+1]=p1; cursor[bi+1]=p1; }
  if (bi+2<N){ start[bi+2]=p2; cursor[bi+2]=p2; }
  if (bi+3<N){ start[bi+3]=p3; cursor[bi+3]=p3; }
  if (b==0 && t==0) start[N]=EE;
}

// ---------------- CSR build: fill source lists ----------------
__global__ void k_fill(const int* __restrict__ src, const int* __restrict__ dst,
                       int* __restrict__ cursor, int* __restrict__ csr_src, int E, int EE){
  int e = blockIdx.x*blockDim.x + threadIdx.x;
  if (e >= EE) return;
  int s, d;
  if (e < E){ s = src[e]; d = dst[e]; } else { s = e - E; d = s; }
  int p = atomicAdd(&cursor[d], 1);
  csr_src[p] = s;
}

// ---------------- K4: gather-side aggregation layer 1 (wave per dst node) ----------------
// lane l covers channels (2l, 2l+1); head = l>>3. Accumulates numerator and
// softmax denominator together; divides at the end. No atomics.
__global__ __launch_bounds__(256) void k_agg1(const int* __restrict__ start, const int* __restrict__ csr_src,
                      const float* __restrict__ a_s, const float* __restrict__ a_d,
                      const float* __restrict__ h1, float* __restrict__ acc1, int N){
  int wid = (blockIdx.x*blockDim.x + threadIdx.x) >> 6;
  int lane = threadIdx.x & 63;
  if (wid >= N) return;
  int d = wid;
  int head = lane >> 3;
  float ad = a_d[(size_t)d*8 + head];
  int beg = start[d], end = start[d+1];
  float ax=0.f, ay=0.f, den=0.f;
  for (int j=beg; j<end; j++){
    int s = csr_src[j];
    float ex = __expf(lrelu(a_s[(size_t)s*8 + head] + ad));
    float2 hv = *(const float2*)&h1[(size_t)s*128 + lane*2];
    ax = fmaf(ex, hv.x, ax);
    ay = fmaf(ex, hv.y, ay);
    den += ex;
  }
  float inv = (den > 0.f) ? 1.f/den : 0.f;   // den identical across the 8 lanes of a head
  acc1[(size_t)d*128 + lane*2    ] = ax*inv;
  acc1[(size_t)d*128 + lane*2 + 1] = ay*inv;
}

// ---------------- K5: elu + per-node [128]x[128,32] projection + layer-2 logits ----------------
__global__ __launch_bounds__(256) void k_layer2(const float* __restrict__ acc1, const float* __restrict__ b1,
                        const float* __restrict__ W2, const float* __restrict__ as2w,
                        const float* __restrict__ ad2w,
                        float* __restrict__ h2p, float* __restrict__ a_s2,
                        float* __restrict__ a_d2, int N){
  __shared__ float w2s[128][32];
  __shared__ float hs[8][128];
  int tid = threadIdx.x;
  #pragma unroll
  for (int it=0; it<16; it++){
    int idx = it*256 + tid;
    ((float*)w2s)[idx] = W2[idx];
  }
  int sub = tid>>5, ln = tid&31;
  int n = blockIdx.x*8 + sub;
  if (n < N){
    #pragma unroll
    for (int j=0;j<4;j++){
      int k = j*32 + ln;
      float v = acc1[(size_t)n*128+k] + b1[k];
      hs[sub][k] = v > 0.f ? v : (__expf(v) - 1.f);
    }
  }
  __syncthreads();
  if (n >= N) return;
  float o = 0.f;
  #pragma unroll
  for (int k=0;k<128;k++) o = fmaf(hs[sub][k], w2s[k][ln], o);
  h2p[(size_t)n*32+ln] = o;
  float ps = o*as2w[ln], pd = o*ad2w[ln];
  #pragma unroll
  for (int m=16;m;m>>=1){ ps += __shfl_xor(ps,m); pd += __shfl_xor(pd,m); }
  if (ln==0){ a_s2[n]=ps; a_d2[n]=pd; }
}

// ---------------- K6: gather aggregation layer 2 + bias + log_softmax ----------------
__global__ __launch_bounds__(256) void k_agg2(const int* __restrict__ start, const int* __restrict__ csr_src,
                      const float* __restrict__ a_s2, const float* __restrict__ a_d2,
                      const float* __restrict__ h2p, const float* __restrict__ b2,
                      float* __restrict__ out, int N){
  int g = (blockIdx.x*blockDim.x + threadIdx.x) >> 5;
  int ln = threadIdx.x & 31;
  if (g >= N) return;
  int d = g;
  float ad = a_d2[d];
  int beg = start[d], end = start[d+1];
  float acc=0.f, den=0.f;
  for (int j=beg; j<end; j++){
    int s = csr_src[j];
    float ex = __expf(lrelu(a_s2[s] + ad));
    acc = fmaf(ex, h2p[(size_t)s*32 + ln], acc);
    den += ex;
  }
  float v = acc/den + b2[ln];
  float mx = v;
  #pragma unroll
  for (int m=16;m;m>>=1) mx = fmaxf(mx, __shfl_xor(mx,m));
  float ex2 = __expf(v-mx);
  float sm = ex2;
  #pragma unroll
  for (int m=16;m;m>>=1) sm += __shfl_xor(sm,m);
  out[(size_t)d*32+ln] = v - mx - __logf(sm);
}

extern "C" void kernel_launch(void* const* d_in, const int* in_sizes, int n_in,
                              void* d_out, int out_size, void* d_ws, size_t ws_size,
                              hipStream_t stream){
  const float* x   = (const float*)d_in[0];
  const int*   ei  = (const int*)d_in[1];
  const float* W1  = (const float*)d_in[3];
  const float* as1 = (const float*)d_in[4];
  const float* ad1 = (const float*)d_in[5];
  const float* b1  = (const float*)d_in[6];
  const float* W2  = (const float*)d_in[7];
  const float* as2 = (const float*)d_in[8];
  const float* ad2 = (const float*)d_in[9];
  const float* b2  = (const float*)d_in[10];

  int N  = in_sizes[0] / 256;
  int E  = in_sizes[2];
  int EE = E + N;
  const int* src = ei;
  const int* dst = ei + E;

  int nb = (N + 1023) / 1024;
  int NP = nb * 1024;

  // ---- workspace layout: ints first (16B-aligned), then floats ----
  int* iw = (int*)d_ws;
  int* deg     = iw;                 iw += NP;
  int* bsum    = iw;                 iw += ((nb+255)/256)*256;
  int* start_  = iw;                 iw += ((N+1+3)/4)*4;
  int* cursor  = iw;                 iw += ((N+3)/4)*4;
  int* csr_src = iw;                 iw += ((EE+3)/4)*4;

  float* w = (float*)iw;
  float* h1     = w; w += (size_t)N*128;
  float* a_s1   = w; w += (size_t)N*8;
  float* a_d1   = w; w += (size_t)N*8;
  float* acc1   = w; w += (size_t)N*128;
  float* h2p    = w; w += (size_t)N*32;
  float* a_s2   = w; w += (size_t)N;
  float* a_d2   = w; w += (size_t)N;
  float* out    = (float*)d_out;

  // zero in-degree histogram (padded region)
  hipLaunchKernelGGL(k_zero, dim3(512), dim3(256), 0, stream, deg, NP);
  // dense transforms
  hipLaunchKernelGGL(k_gemm1, dim3((N+127)/128), dim3(256), 0, stream, x, W1, h1, N);
  hipLaunchKernelGGL(k_att1, dim3((N*8+255)/256), dim3(256), 0, stream, h1, as1, ad1, a_s1, a_d1, N);
  // CSR build (shared by both layers)
  hipLaunchKernelGGL(k_hist, dim3((EE+255)/256), dim3(256), 0, stream, dst, deg, E, EE);
  hipLaunchKernelGGL(k_scan1, dim3(nb), dim3(256), 0, stream, deg, bsum);
  hipLaunchKernelGGL(k_scan2, dim3(1), dim3(64), 0, stream, bsum, nb);
  hipLaunchKernelGGL(k_scan3, dim3(nb), dim3(256), 0, stream, deg, bsum, start_, cursor, N, EE);
  hipLaunchKernelGGL(k_fill, dim3((EE+255)/256), dim3(256), 0, stream, src, dst, cursor, csr_src, E, EE);
  // layer 1: gather aggregation (no atomics)
  hipLaunchKernelGGL(k_agg1, dim3((N+3)/4), dim3(256), 0, stream, start_, csr_src, a_s1, a_d1, h1, acc1, N);
  // layer 2: elu + projection + logits
  hipLaunchKernelGGL(k_layer2, dim3((N+7)/8), dim3(256), 0, stream, acc1, b1, W2, as2, ad2, h2p, a_s2, a_d2, N);
  // layer 2 aggregation fused with bias + log_softmax
  hipLaunchKernelGGL(k_agg2, dim3((N+7)/8), dim3(256), 0, stream, start_, csr_src, a_s2, a_d2, h2p, b2, out, N);
}

// Round 5
// 628.741 us; speedup vs baseline: 4.0212x; 1.0834x over previous
//
#include <hip/hip_runtime.h>
#include <math.h>

#define NEG_SLOPE 0.2f

__device__ __forceinline__ float lrelu(float x){ return x > 0.f ? x : NEG_SLOPE*x; }

// ---------------- K0: zero a region of ints ----------------
__global__ void k_zero(int* __restrict__ p, int n){
  int i = blockIdx.x*blockDim.x + threadIdx.x;
  int stride = gridDim.x*blockDim.x;
  for (; i < n; i += stride) p[i] = 0;
}

// ---------------- K1: h1[N,128] = x[N,256] @ W1[256,128] (fp32) ----------------
__global__ __launch_bounds__(256) void k_gemm1(const float* __restrict__ x,
                                               const float* __restrict__ W,
                                               float* __restrict__ h1, int N){
  __shared__ float xs[32][132];
  __shared__ float wsh[32][128];
  int tid = threadIdx.x;
  int cg = tid & 31, rg = tid >> 5;
  int row0 = blockIdx.x * 128;
  float acc[16][4];
  #pragma unroll
  for (int i=0;i<16;i++)
    #pragma unroll
    for (int j=0;j<4;j++) acc[i][j]=0.f;

  for (int kk=0; kk<256; kk+=32){
    #pragma unroll
    for (int it=0; it<4; it++){
      int r = it*32 + (tid>>3);
      int kc = (tid&7)*4;
      float4 v = make_float4(0.f,0.f,0.f,0.f);
      int grow = row0 + r;
      if (grow < N) v = *(const float4*)&x[(size_t)grow*256 + kk + kc];
      xs[kc+0][r]=v.x; xs[kc+1][r]=v.y; xs[kc+2][r]=v.z; xs[kc+3][r]=v.w;
    }
    #pragma unroll
    for (int it=0; it<4; it++){
      int k = it*8 + (tid>>5);
      int c = (tid&31)*4;
      *(float4*)&wsh[k][c] = *(const float4*)&W[(size_t)(kk+k)*128 + c];
    }
    __syncthreads();
    #pragma unroll
    for (int k=0;k<32;k++){
      float4 b = *(float4*)&wsh[k][cg*4];
      float a[16];
      *(float4*)&a[0]  = *(float4*)&xs[k][rg*16+0];
      *(float4*)&a[4]  = *(float4*)&xs[k][rg*16+4];
      *(float4*)&a[8]  = *(float4*)&xs[k][rg*16+8];
      *(float4*)&a[12] = *(float4*)&xs[k][rg*16+12];
      #pragma unroll
      for (int i=0;i<16;i++){
        acc[i][0] = fmaf(a[i], b.x, acc[i][0]);
        acc[i][1] = fmaf(a[i], b.y, acc[i][1]);
        acc[i][2] = fmaf(a[i], b.z, acc[i][2]);
        acc[i][3] = fmaf(a[i], b.w, acc[i][3]);
      }
    }
    __syncthreads();
  }
  int c0 = cg*4;
  #pragma unroll
  for (int i=0;i<16;i++){
    int grow = row0 + rg*16 + i;
    if (grow < N)
      *(float4*)&h1[(size_t)grow*128 + c0] = make_float4(acc[i][0],acc[i][1],acc[i][2],acc[i][3]);
  }
}

// ---------------- K2: per-(node,head) attention logits layer 1 ----------------
__global__ void k_att1(const float* __restrict__ h1, const float* __restrict__ as_w,
                       const float* __restrict__ ad_w,
                       float* __restrict__ a_s, float* __restrict__ a_d, int N){
  int t = blockIdx.x*blockDim.x + threadIdx.x;
  if (t >= N*8) return;
  int n = t >> 3, h = t & 7;
  const float* hp = &h1[(size_t)n*128 + h*16];
  const float* wsp = &as_w[h*16];
  const float* wdp = &ad_w[h*16];
  float s=0.f, d=0.f;
  #pragma unroll
  for (int j=0;j<16;j++){ float v = hp[j]; s = fmaf(v, wsp[j], s); d = fmaf(v, wdp[j], d); }
  a_s[t] = s; a_d[t] = d;
}

// ---------------- CSR build: histogram of in-degrees ----------------
__global__ void k_hist(const int* __restrict__ dst, int* __restrict__ deg, int E, int EE){
  int e = blockIdx.x*blockDim.x + threadIdx.x;
  if (e >= EE) return;
  int d = (e < E) ? dst[e] : (e - E);
  atomicAdd(&deg[d], 1);
}

// ---------------- CSR build: per-1024-block reduction ----------------
__global__ __launch_bounds__(256) void k_scan1(const int* __restrict__ deg, int* __restrict__ bsum){
  __shared__ int sred[256];
  int b = blockIdx.x, t = threadIdx.x;
  int4 v = *(const int4*)&deg[b*1024 + t*4];   // deg padded to 1024-multiple
  sred[t] = v.x+v.y+v.z+v.w;
  __syncthreads();
  for (int off=128; off; off>>=1){ if (t<off) sred[t]+=sred[t+off]; __syncthreads(); }
  if (t==0) bsum[b]=sred[0];
}

// ---------------- CSR build: scan of block sums (single tiny block) ----------------
__global__ void k_scan2(int* __restrict__ bsum, int nb){
  if (threadIdx.x==0 && blockIdx.x==0){
    int acc=0;
    for (int i=0;i<nb;i++){ int v=bsum[i]; bsum[i]=acc; acc+=v; }
  }
}

// ---------------- CSR build: final per-element exclusive scan ----------------
__global__ __launch_bounds__(256) void k_scan3(const int* __restrict__ deg, const int* __restrict__ bsum,
                        int* __restrict__ start, int* __restrict__ cursor, int N, int EE){
  __shared__ int sc[256];
  int b = blockIdx.x, t = threadIdx.x;
  int bi = b*1024 + t*4;
  int4 v = *(const int4*)&deg[bi];
  int ts = v.x+v.y+v.z+v.w;
  sc[t]=ts; __syncthreads();
  for (int off=1; off<256; off<<=1){
    int p = (t>=off)? sc[t-off] : 0;
    __syncthreads();
    sc[t]+=p;
    __syncthreads();
  }
  int excl = sc[t]-ts + bsum[b];
  int p0=excl, p1=p0+v.x, p2=p1+v.y, p3=p2+v.z;
  if (bi+0<N){ start[bi+0]=p0; cursor[bi+0]=p0; }
  if (bi+1<N){ start[bi+1]=p1; cursor[bi+1]=p1; }
  if (bi+2<N){ start[bi+2]=p2; cursor[bi+2]=p2; }
  if (bi+3<N){ start[bi+3]=p3; cursor[bi+3]=p3; }
  if (b==0 && t==0) start[N]=EE;
}

// ---------------- CSR build: fill source lists ----------------
__global__ void k_fill(const int* __restrict__ src, const int* __restrict__ dst,
                       int* __restrict__ cursor, int* __restrict__ csr_src, int E, int EE){
  int e = blockIdx.x*blockDim.x + threadIdx.x;
  if (e >= EE) return;
  int s, d;
  if (e < E){ s = src[e]; d = dst[e]; } else { s = e - E; d = s; }
  int p = atomicAdd(&cursor[d], 1);
  csr_src[p] = s;
}

// ---------------- K4: gather-side aggregation layer 1 ----------------
// Wave per dst node. Two half-waves each process one edge: lane = 32*half + l32,
// lane covers channels [4*l32, 4*l32+3] (all in head l32>>2). 2x manual unroll
// per half => 4 independent gather chains in flight per wave. Halves combined
// with shfl_xor(32). No atomics.
__global__ __launch_bounds__(256) void k_agg1(const int* __restrict__ start, const int* __restrict__ csr_src,
                      const float* __restrict__ a_s, const float* __restrict__ a_d,
                      const float* __restrict__ h1, float* __restrict__ acc1, int N){
  int wid = (blockIdx.x*blockDim.x + threadIdx.x) >> 6;
  int lane = threadIdx.x & 63;
  if (wid >= N) return;
  int d = wid;
  int half = lane >> 5;
  int l32  = lane & 31;
  int head = l32 >> 2;
  float ad = a_d[(size_t)d*8 + head];
  int beg = start[d], end = start[d+1];
  float ax=0.f, ay=0.f, az=0.f, aw=0.f, den=0.f;
  int j = beg + half;
  for (; j + 2 < end; j += 4){
    int s0 = csr_src[j];
    int s1 = csr_src[j+2];
    float e0 = __expf(lrelu(a_s[(size_t)s0*8 + head] + ad));
    float e1 = __expf(lrelu(a_s[(size_t)s1*8 + head] + ad));
    float4 h0 = *(const float4*)&h1[(size_t)s0*128 + l32*4];
    float4 h1v = *(const float4*)&h1[(size_t)s1*128 + l32*4];
    ax = fmaf(e0, h0.x, ax);  ay = fmaf(e0, h0.y, ay);
    az = fmaf(e0, h0.z, az);  aw = fmaf(e0, h0.w, aw);
    ax = fmaf(e1, h1v.x, ax); ay = fmaf(e1, h1v.y, ay);
    az = fmaf(e1, h1v.z, az); aw = fmaf(e1, h1v.w, aw);
    den += e0 + e1;
  }
  if (j < end){
    int s0 = csr_src[j];
    float e0 = __expf(lrelu(a_s[(size_t)s0*8 + head] + ad));
    float4 h0 = *(const float4*)&h1[(size_t)s0*128 + l32*4];
    ax = fmaf(e0, h0.x, ax);  ay = fmaf(e0, h0.y, ay);
    az = fmaf(e0, h0.z, az);  aw = fmaf(e0, h0.w, aw);
    den += e0;
  }
  // combine the two halves
  ax += __shfl_xor(ax, 32);
  ay += __shfl_xor(ay, 32);
  az += __shfl_xor(az, 32);
  aw += __shfl_xor(aw, 32);
  den += __shfl_xor(den, 32);
  float inv = (den > 0.f) ? 1.f/den : 0.f;
  if (half == 0){
    float4 o = make_float4(ax*inv, ay*inv, az*inv, aw*inv);
    *(float4*)&acc1[(size_t)d*128 + l32*4] = o;
  }
}

// ---------------- K5: elu + per-node [128]x[128,32] projection + layer-2 logits ----------------
__global__ __launch_bounds__(256) void k_layer2(const float* __restrict__ acc1, const float* __restrict__ b1,
                        const float* __restrict__ W2, const float* __restrict__ as2w,
                        const float* __restrict__ ad2w,
                        float* __restrict__ h2p, float* __restrict__ a_s2,
                        float* __restrict__ a_d2, int N){
  __shared__ float w2s[128][32];
  __shared__ float hs[8][128];
  int tid = threadIdx.x;
  #pragma unroll
  for (int it=0; it<16; it++){
    int idx = it*256 + tid;
    ((float*)w2s)[idx] = W2[idx];
  }
  int sub = tid>>5, ln = tid&31;
  int n = blockIdx.x*8 + sub;
  if (n < N){
    #pragma unroll
    for (int j=0;j<4;j++){
      int k = j*32 + ln;
      float v = acc1[(size_t)n*128+k] + b1[k];
      hs[sub][k] = v > 0.f ? v : (__expf(v) - 1.f);
    }
  }
  __syncthreads();
  if (n >= N) return;
  float o = 0.f;
  #pragma unroll
  for (int k=0;k<128;k++) o = fmaf(hs[sub][k], w2s[k][ln], o);
  h2p[(size_t)n*32+ln] = o;
  float ps = o*as2w[ln], pd = o*ad2w[ln];
  #pragma unroll
  for (int m=16;m;m>>=1){ ps += __shfl_xor(ps,m); pd += __shfl_xor(pd,m); }
  if (ln==0){ a_s2[n]=ps; a_d2[n]=pd; }
}

// ---------------- K6: gather aggregation layer 2 + bias + log_softmax ----------------
// Half-wave per dst node, 2x manual unroll for MLP.
__global__ __launch_bounds__(256) void k_agg2(const int* __restrict__ start, const int* __restrict__ csr_src,
                      const float* __restrict__ a_s2, const float* __restrict__ a_d2,
                      const float* __restrict__ h2p, const float* __restrict__ b2,
                      float* __restrict__ out, int N){
  int g = (blockIdx.x*blockDim.x + threadIdx.x) >> 5;
  int ln = threadIdx.x & 31;
  if (g >= N) return;
  int d = g;
  float ad = a_d2[d];
  int beg = start[d], end = start[d+1];
  float acc=0.f, den=0.f;
  int j = beg;
  for (; j + 1 < end; j += 2){
    int s0 = csr_src[j];
    int s1 = csr_src[j+1];
    float e0 = __expf(lrelu(a_s2[s0] + ad));
    float e1 = __expf(lrelu(a_s2[s1] + ad));
    float v0 = h2p[(size_t)s0*32 + ln];
    float v1 = h2p[(size_t)s1*32 + ln];
    acc = fmaf(e0, v0, acc);
    acc = fmaf(e1, v1, acc);
    den += e0 + e1;
  }
  if (j < end){
    int s0 = csr_src[j];
    float e0 = __expf(lrelu(a_s2[s0] + ad));
    acc = fmaf(e0, h2p[(size_t)s0*32 + ln], acc);
    den += e0;
  }
  float v = acc/den + b2[ln];
  float mx = v;
  #pragma unroll
  for (int m=16;m;m>>=1) mx = fmaxf(mx, __shfl_xor(mx,m));
  float ex2 = __expf(v-mx);
  float sm = ex2;
  #pragma unroll
  for (int m=16;m;m>>=1) sm += __shfl_xor(sm,m);
  out[(size_t)d*32+ln] = v - mx - __logf(sm);
}

extern "C" void kernel_launch(void* const* d_in, const int* in_sizes, int n_in,
                              void* d_out, int out_size, void* d_ws, size_t ws_size,
                              hipStream_t stream){
  const float* x   = (const float*)d_in[0];
  const int*   ei  = (const int*)d_in[1];
  const float* W1  = (const float*)d_in[3];
  const float* as1 = (const float*)d_in[4];
  const float* ad1 = (const float*)d_in[5];
  const float* b1  = (const float*)d_in[6];
  const float* W2  = (const float*)d_in[7];
  const float* as2 = (const float*)d_in[8];
  const float* ad2 = (const float*)d_in[9];
  const float* b2  = (const float*)d_in[10];

  int N  = in_sizes[0] / 256;
  int E  = in_sizes[2];
  int EE = E + N;
  const int* src = ei;
  const int* dst = ei + E;

  int nb = (N + 1023) / 1024;
  int NP = nb * 1024;

  // ---- workspace layout: ints first (16B-aligned), then floats ----
  int* iw = (int*)d_ws;
  int* deg     = iw;                 iw += NP;
  int* bsum    = iw;                 iw += ((nb+255)/256)*256;
  int* start_  = iw;                 iw += ((N+1+3)/4)*4;
  int* cursor  = iw;                 iw += ((N+3)/4)*4;
  int* csr_src = iw;                 iw += ((EE+3)/4)*4;

  float* w = (float*)iw;
  float* h1     = w; w += (size_t)N*128;
  float* a_s1   = w; w += (size_t)N*8;
  float* a_d1   = w; w += (size_t)N*8;
  float* acc1   = w; w += (size_t)N*128;
  float* h2p    = w; w += (size_t)N*32;
  float* a_s2   = w; w += (size_t)N;
  float* a_d2   = w; w += (size_t)N;
  float* out    = (float*)d_out;

  // zero in-degree histogram (padded region)
  hipLaunchKernelGGL(k_zero, dim3(512), dim3(256), 0, stream, deg, NP);
  // dense transforms
  hipLaunchKernelGGL(k_gemm1, dim3((N+127)/128), dim3(256), 0, stream, x, W1, h1, N);
  hipLaunchKernelGGL(k_att1, dim3((N*8+255)/256), dim3(256), 0, stream, h1, as1, ad1, a_s1, a_d1, N);
  // CSR build (shared by both layers)
  hipLaunchKernelGGL(k_hist, dim3((EE+255)/256), dim3(256), 0, stream, dst, deg, E, EE);
  hipLaunchKernelGGL(k_scan1, dim3(nb), dim3(256), 0, stream, deg, bsum);
  hipLaunchKernelGGL(k_scan2, dim3(1), dim3(64), 0, stream, bsum, nb);
  hipLaunchKernelGGL(k_scan3, dim3(nb), dim3(256), 0, stream, deg, bsum, start_, cursor, N, EE);
  hipLaunchKernelGGL(k_fill, dim3((EE+255)/256), dim3(256), 0, stream, src, dst, cursor, csr_src, E, EE);
  // layer 1: gather aggregation (no atomics)
  hipLaunchKernelGGL(k_agg1, dim3((N+3)/4), dim3(256), 0, stream, start_, csr_src, a_s1, a_d1, h1, acc1, N);
  // layer 2: elu + projection + logits
  hipLaunchKernelGGL(k_layer2, dim3((N+7)/8), dim3(256), 0, stream, acc1, b1, W2, as2, ad2, h2p, a_s2, a_d2, N);
  // layer 2 aggregation fused with bias + log_softmax
  hipLaunchKernelGGL(k_agg2, dim3((N+7)/8), dim3(256), 0, stream, start_, csr_src, a_s2, a_d2, h2p, b2, out, N);
}

// Round 6
// 615.190 us; speedup vs baseline: 4.1098x; 1.0220x over previous
//
#include <hip/hip_runtime.h>
#include <math.h>

#define NEG_SLOPE 0.2f

__device__ __forceinline__ float lrelu(float x){ return x > 0.f ? x : NEG_SLOPE*x; }

// ---------------- K0: zero a region of ints ----------------
__global__ void k_zero(int* __restrict__ p, int n){
  int i = blockIdx.x*blockDim.x + threadIdx.x;
  int stride = gridDim.x*blockDim.x;
  for (; i < n; i += stride) p[i] = 0;
}

// ---------------- K1: h1[N,128] = x[N,256] @ W1[256,128] (fp32) ----------------
__global__ __launch_bounds__(256) void k_gemm1(const float* __restrict__ x,
                                               const float* __restrict__ W,
                                               float* __restrict__ h1, int N){
  __shared__ float xs[32][132];
  __shared__ float wsh[32][128];
  int tid = threadIdx.x;
  int cg = tid & 31, rg = tid >> 5;
  int row0 = blockIdx.x * 128;
  float acc[16][4];
  #pragma unroll
  for (int i=0;i<16;i++)
    #pragma unroll
    for (int j=0;j<4;j++) acc[i][j]=0.f;

  for (int kk=0; kk<256; kk+=32){
    #pragma unroll
    for (int it=0; it<4; it++){
      int r = it*32 + (tid>>3);
      int kc = (tid&7)*4;
      float4 v = make_float4(0.f,0.f,0.f,0.f);
      int grow = row0 + r;
      if (grow < N) v = *(const float4*)&x[(size_t)grow*256 + kk + kc];
      xs[kc+0][r]=v.x; xs[kc+1][r]=v.y; xs[kc+2][r]=v.z; xs[kc+3][r]=v.w;
    }
    #pragma unroll
    for (int it=0; it<4; it++){
      int k = it*8 + (tid>>5);
      int c = (tid&31)*4;
      *(float4*)&wsh[k][c] = *(const float4*)&W[(size_t)(kk+k)*128 + c];
    }
    __syncthreads();
    #pragma unroll
    for (int k=0;k<32;k++){
      float4 b = *(float4*)&wsh[k][cg*4];
      float a[16];
      *(float4*)&a[0]  = *(float4*)&xs[k][rg*16+0];
      *(float4*)&a[4]  = *(float4*)&xs[k][rg*16+4];
      *(float4*)&a[8]  = *(float4*)&xs[k][rg*16+8];
      *(float4*)&a[12] = *(float4*)&xs[k][rg*16+12];
      #pragma unroll
      for (int i=0;i<16;i++){
        acc[i][0] = fmaf(a[i], b.x, acc[i][0]);
        acc[i][1] = fmaf(a[i], b.y, acc[i][1]);
        acc[i][2] = fmaf(a[i], b.z, acc[i][2]);
        acc[i][3] = fmaf(a[i], b.w, acc[i][3]);
      }
    }
    __syncthreads();
  }
  int c0 = cg*4;
  #pragma unroll
  for (int i=0;i<16;i++){
    int grow = row0 + rg*16 + i;
    if (grow < N)
      *(float4*)&h1[(size_t)grow*128 + c0] = make_float4(acc[i][0],acc[i][1],acc[i][2],acc[i][3]);
  }
}

// ---------------- K2: per-(node,head) attention logits layer 1 ----------------
__global__ void k_att1(const float* __restrict__ h1, const float* __restrict__ as_w,
                       const float* __restrict__ ad_w,
                       float* __restrict__ a_s, float* __restrict__ a_d, int N){
  int t = blockIdx.x*blockDim.x + threadIdx.x;
  if (t >= N*8) return;
  int n = t >> 3, h = t & 7;
  const float* hp = &h1[(size_t)n*128 + h*16];
  const float* wsp = &as_w[h*16];
  const float* wdp = &ad_w[h*16];
  float s=0.f, d=0.f;
  #pragma unroll
  for (int j=0;j<16;j++){ float v = hp[j]; s = fmaf(v, wsp[j], s); d = fmaf(v, wdp[j], d); }
  a_s[t] = s; a_d[t] = d;
}

// ---------------- CSR build: histogram of in-degrees ----------------
__global__ void k_hist(const int* __restrict__ dst, int* __restrict__ deg, int E, int EE){
  int e = blockIdx.x*blockDim.x + threadIdx.x;
  if (e >= EE) return;
  int d = (e < E) ? dst[e] : (e - E);
  atomicAdd(&deg[d], 1);
}

// ---------------- CSR build: per-1024-block reduction ----------------
__global__ __launch_bounds__(256) void k_scan1(const int* __restrict__ deg, int* __restrict__ bsum){
  __shared__ int sred[256];
  int b = blockIdx.x, t = threadIdx.x;
  int4 v = *(const int4*)&deg[b*1024 + t*4];   // deg padded to 1024-multiple
  sred[t] = v.x+v.y+v.z+v.w;
  __syncthreads();
  for (int off=128; off; off>>=1){ if (t<off) sred[t]+=sred[t+off]; __syncthreads(); }
  if (t==0) bsum[b]=sred[0];
}

// ---------------- CSR build: scan of block sums (single tiny block) ----------------
__global__ void k_scan2(int* __restrict__ bsum, int nb){
  if (threadIdx.x==0 && blockIdx.x==0){
    int acc=0;
    for (int i=0;i<nb;i++){ int v=bsum[i]; bsum[i]=acc; acc+=v; }
  }
}

// ---------------- CSR build: final per-element exclusive scan ----------------
__global__ __launch_bounds__(256) void k_scan3(const int* __restrict__ deg, const int* __restrict__ bsum,
                        int* __restrict__ start, int* __restrict__ cursor, int N, int EE){
  __shared__ int sc[256];
  int b = blockIdx.x, t = threadIdx.x;
  int bi = b*1024 + t*4;
  int4 v = *(const int4*)&deg[bi];
  int ts = v.x+v.y+v.z+v.w;
  sc[t]=ts; __syncthreads();
  for (int off=1; off<256; off<<=1){
    int p = (t>=off)? sc[t-off] : 0;
    __syncthreads();
    sc[t]+=p;
    __syncthreads();
  }
  int excl = sc[t]-ts + bsum[b];
  int p0=excl, p1=p0+v.x, p2=p1+v.y, p3=p2+v.z;
  if (bi+0<N){ start[bi+0]=p0; cursor[bi+0]=p0; }
  if (bi+1<N){ start[bi+1]=p1; cursor[bi+1]=p1; }
  if (bi+2<N){ start[bi+2]=p2; cursor[bi+2]=p2; }
  if (bi+3<N){ start[bi+3]=p3; cursor[bi+3]=p3; }
  if (b==0 && t==0) start[N]=EE;
}

// ---------------- CSR build: fill source lists ----------------
__global__ void k_fill(const int* __restrict__ src, const int* __restrict__ dst,
                       int* __restrict__ cursor, int* __restrict__ csr_src, int E, int EE){
  int e = blockIdx.x*blockDim.x + threadIdx.x;
  if (e >= EE) return;
  int s, d;
  if (e < E){ s = src[e]; d = dst[e]; } else { s = e - E; d = s; }
  int p = atomicAdd(&cursor[d], 1);
  csr_src[p] = s;
}

// ---------------- K4: gather-side aggregation layer 1 ----------------
// Wave per dst node. Two half-waves; lane = 32*half + l32 covers channels
// [4*l32, 4*l32+3] (head = l32>>2). 4x manual unroll per half => 8 independent
// gather chains in flight per wave. Halves combined via shfl_xor(32).
__global__ __launch_bounds__(256) void k_agg1(const int* __restrict__ start, const int* __restrict__ csr_src,
                      const float* __restrict__ a_s, const float* __restrict__ a_d,
                      const float* __restrict__ h1, float* __restrict__ acc1, int N){
  int wid = (blockIdx.x*blockDim.x + threadIdx.x) >> 6;
  int lane = threadIdx.x & 63;
  if (wid >= N) return;
  int d = wid;
  int half = lane >> 5;
  int l32  = lane & 31;
  int head = l32 >> 2;
  float ad = a_d[(size_t)d*8 + head];
  int beg = start[d], end = start[d+1];
  float ax=0.f, ay=0.f, az=0.f, aw=0.f, den=0.f;
  int j = beg + half;
  for (; j + 6 < end; j += 8){
    int s0 = csr_src[j];
    int s1 = csr_src[j+2];
    int s2 = csr_src[j+4];
    int s3 = csr_src[j+6];
    float e0 = __expf(lrelu(a_s[(size_t)s0*8 + head] + ad));
    float e1 = __expf(lrelu(a_s[(size_t)s1*8 + head] + ad));
    float e2 = __expf(lrelu(a_s[(size_t)s2*8 + head] + ad));
    float e3 = __expf(lrelu(a_s[(size_t)s3*8 + head] + ad));
    float4 v0 = *(const float4*)&h1[(size_t)s0*128 + l32*4];
    float4 v1 = *(const float4*)&h1[(size_t)s1*128 + l32*4];
    float4 v2 = *(const float4*)&h1[(size_t)s2*128 + l32*4];
    float4 v3 = *(const float4*)&h1[(size_t)s3*128 + l32*4];
    ax = fmaf(e0, v0.x, ax); ay = fmaf(e0, v0.y, ay); az = fmaf(e0, v0.z, az); aw = fmaf(e0, v0.w, aw);
    ax = fmaf(e1, v1.x, ax); ay = fmaf(e1, v1.y, ay); az = fmaf(e1, v1.z, az); aw = fmaf(e1, v1.w, aw);
    ax = fmaf(e2, v2.x, ax); ay = fmaf(e2, v2.y, ay); az = fmaf(e2, v2.z, az); aw = fmaf(e2, v2.w, aw);
    ax = fmaf(e3, v3.x, ax); ay = fmaf(e3, v3.y, ay); az = fmaf(e3, v3.z, az); aw = fmaf(e3, v3.w, aw);
    den += (e0 + e1) + (e2 + e3);
  }
  for (; j < end; j += 2){
    int s0 = csr_src[j];
    float e0 = __expf(lrelu(a_s[(size_t)s0*8 + head] + ad));
    float4 v0 = *(const float4*)&h1[(size_t)s0*128 + l32*4];
    ax = fmaf(e0, v0.x, ax); ay = fmaf(e0, v0.y, ay); az = fmaf(e0, v0.z, az); aw = fmaf(e0, v0.w, aw);
    den += e0;
  }
  // combine the two halves
  ax += __shfl_xor(ax, 32);
  ay += __shfl_xor(ay, 32);
  az += __shfl_xor(az, 32);
  aw += __shfl_xor(aw, 32);
  den += __shfl_xor(den, 32);
  float inv = (den > 0.f) ? 1.f/den : 0.f;
  if (half == 0){
    float4 o = make_float4(ax*inv, ay*inv, az*inv, aw*inv);
    *(float4*)&acc1[(size_t)d*128 + l32*4] = o;
  }
}

// ---------------- K5: elu + per-node [128]x[128,32] projection + layer-2 logits ----------------
__global__ __launch_bounds__(256) void k_layer2(const float* __restrict__ acc1, const float* __restrict__ b1,
                        const float* __restrict__ W2, const float* __restrict__ as2w,
                        const float* __restrict__ ad2w,
                        float* __restrict__ h2p, float* __restrict__ a_s2,
                        float* __restrict__ a_d2, int N){
  __shared__ float w2s[128][32];
  __shared__ float hs[8][128];
  int tid = threadIdx.x;
  #pragma unroll
  for (int it=0; it<16; it++){
    int idx = it*256 + tid;
    ((float*)w2s)[idx] = W2[idx];
  }
  int sub = tid>>5, ln = tid&31;
  int n = blockIdx.x*8 + sub;
  if (n < N){
    #pragma unroll
    for (int j=0;j<4;j++){
      int k = j*32 + ln;
      float v = acc1[(size_t)n*128+k] + b1[k];
      hs[sub][k] = v > 0.f ? v : (__expf(v) - 1.f);
    }
  }
  __syncthreads();
  if (n >= N) return;
  float o = 0.f;
  #pragma unroll
  for (int k=0;k<128;k++) o = fmaf(hs[sub][k], w2s[k][ln], o);
  h2p[(size_t)n*32+ln] = o;
  float ps = o*as2w[ln], pd = o*ad2w[ln];
  #pragma unroll
  for (int m=16;m;m>>=1){ ps += __shfl_xor(ps,m); pd += __shfl_xor(pd,m); }
  if (ln==0){ a_s2[n]=ps; a_d2[n]=pd; }
}

// ---------------- K6: gather aggregation layer 2 + bias + log_softmax ----------------
// Half-wave per dst node, 4x manual unroll => 4 gather chains in flight.
__global__ __launch_bounds__(256) void k_agg2(const int* __restrict__ start, const int* __restrict__ csr_src,
                      const float* __restrict__ a_s2, const float* __restrict__ a_d2,
                      const float* __restrict__ h2p, const float* __restrict__ b2,
                      float* __restrict__ out, int N){
  int g = (blockIdx.x*blockDim.x + threadIdx.x) >> 5;
  int ln = threadIdx.x & 31;
  if (g >= N) return;
  int d = g;
  float ad = a_d2[d];
  int beg = start[d], end = start[d+1];
  float acc=0.f, den=0.f;
  int j = beg;
  for (; j + 3 < end; j += 4){
    int s0 = csr_src[j];
    int s1 = csr_src[j+1];
    int s2 = csr_src[j+2];
    int s3 = csr_src[j+3];
    float e0 = __expf(lrelu(a_s2[s0] + ad));
    float e1 = __expf(lrelu(a_s2[s1] + ad));
    float e2 = __expf(lrelu(a_s2[s2] + ad));
    float e3 = __expf(lrelu(a_s2[s3] + ad));
    float v0 = h2p[(size_t)s0*32 + ln];
    float v1 = h2p[(size_t)s1*32 + ln];
    float v2 = h2p[(size_t)s2*32 + ln];
    float v3 = h2p[(size_t)s3*32 + ln];
    acc = fmaf(e0, v0, acc);
    acc = fmaf(e1, v1, acc);
    acc = fmaf(e2, v2, acc);
    acc = fmaf(e3, v3, acc);
    den += (e0 + e1) + (e2 + e3);
  }
  for (; j < end; j++){
    int s0 = csr_src[j];
    float e0 = __expf(lrelu(a_s2[s0] + ad));
    acc = fmaf(e0, h2p[(size_t)s0*32 + ln], acc);
    den += e0;
  }
  float v = acc/den + b2[ln];
  float mx = v;
  #pragma unroll
  for (int m=16;m;m>>=1) mx = fmaxf(mx, __shfl_xor(mx,m));
  float ex2 = __expf(v-mx);
  float sm = ex2;
  #pragma unroll
  for (int m=16;m;m>>=1) sm += __shfl_xor(sm,m);
  out[(size_t)d*32+ln] = v - mx - __logf(sm);
}

extern "C" void kernel_launch(void* const* d_in, const int* in_sizes, int n_in,
                              void* d_out, int out_size, void* d_ws, size_t ws_size,
                              hipStream_t stream){
  const float* x   = (const float*)d_in[0];
  const int*   ei  = (const int*)d_in[1];
  const float* W1  = (const float*)d_in[3];
  const float* as1 = (const float*)d_in[4];
  const float* ad1 = (const float*)d_in[5];
  const float* b1  = (const float*)d_in[6];
  const float* W2  = (const float*)d_in[7];
  const float* as2 = (const float*)d_in[8];
  const float* ad2 = (const float*)d_in[9];
  const float* b2  = (const float*)d_in[10];

  int N  = in_sizes[0] / 256;
  int E  = in_sizes[2];
  int EE = E + N;
  const int* src = ei;
  const int* dst = ei + E;

  int nb = (N + 1023) / 1024;
  int NP = nb * 1024;

  // ---- workspace layout: ints first (16B-aligned), then floats ----
  int* iw = (int*)d_ws;
  int* deg     = iw;                 iw += NP;
  int* bsum    = iw;                 iw += ((nb+255)/256)*256;
  int* start_  = iw;                 iw += ((N+1+3)/4)*4;
  int* cursor  = iw;                 iw += ((N+3)/4)*4;
  int* csr_src = iw;                 iw += ((EE+3)/4)*4;

  float* w = (float*)iw;
  float* h1     = w; w += (size_t)N*128;
  float* a_s1   = w; w += (size_t)N*8;
  float* a_d1   = w; w += (size_t)N*8;
  float* acc1   = w; w += (size_t)N*128;
  float* h2p    = w; w += (size_t)N*32;
  float* a_s2   = w; w += (size_t)N;
  float* a_d2   = w; w += (size_t)N;
  float* out    = (float*)d_out;

  // zero in-degree histogram (padded region)
  hipLaunchKernelGGL(k_zero, dim3(512), dim3(256), 0, stream, deg, NP);
  // dense transforms
  hipLaunchKernelGGL(k_gemm1, dim3((N+127)/128), dim3(256), 0, stream, x, W1, h1, N);
  hipLaunchKernelGGL(k_att1, dim3((N*8+255)/256), dim3(256), 0, stream, h1, as1, ad1, a_s1, a_d1, N);
  // CSR build (shared by both layers)
  hipLaunchKernelGGL(k_hist, dim3((EE+255)/256), dim3(256), 0, stream, dst, deg, E, EE);
  hipLaunchKernelGGL(k_scan1, dim3(nb), dim3(256), 0, stream, deg, bsum);
  hipLaunchKernelGGL(k_scan2, dim3(1), dim3(64), 0, stream, bsum, nb);
  hipLaunchKernelGGL(k_scan3, dim3(nb), dim3(256), 0, stream, deg, bsum, start_, cursor, N, EE);
  hipLaunchKernelGGL(k_fill, dim3((EE+255)/256), dim3(256), 0, stream, src, dst, cursor, csr_src, E, EE);
  // layer 1: gather aggregation (no atomics)
  hipLaunchKernelGGL(k_agg1, dim3((N+3)/4), dim3(256), 0, stream, start_, csr_src, a_s1, a_d1, h1, acc1, N);
  // layer 2: elu + projection + logits
  hipLaunchKernelGGL(k_layer2, dim3((N+7)/8), dim3(256), 0, stream, acc1, b1, W2, as2, ad2, h2p, a_s2, a_d2, N);
  // layer 2 aggregation fused with bias + log_softmax
  hipLaunchKernelGGL(k_agg2, dim3((N+7)/8), dim3(256), 0, stream, start_, csr_src, a_s2, a_d2, h2p, b2, out, N);
}

// Round 7
// 536.230 us; speedup vs baseline: 4.7150x; 1.1473x over previous
//
#include <hip/hip_runtime.h>
#include <hip/hip_fp16.h>
#include <math.h>

#define NEG_SLOPE 0.2f

__device__ __forceinline__ float lrelu(float x){ return x > 0.f ? x : NEG_SLOPE*x; }

// ---------------- K0: zero a region of ints ----------------
__global__ void k_zero(int* __restrict__ p, int n){
  int i = blockIdx.x*blockDim.x + threadIdx.x;
  int stride = gridDim.x*blockDim.x;
  for (; i < n; i += stride) p[i] = 0;
}

// ---------------- K1: h1h[N,128](fp16) = x[N,256] @ W1[256,128] (fp32 math) ----------------
__global__ __launch_bounds__(256) void k_gemm1(const float* __restrict__ x,
                                               const float* __restrict__ W,
                                               __half* __restrict__ h1h, int N){
  __shared__ float xs[32][132];
  __shared__ float wsh[32][128];
  int tid = threadIdx.x;
  int cg = tid & 31, rg = tid >> 5;
  int row0 = blockIdx.x * 128;
  float acc[16][4];
  #pragma unroll
  for (int i=0;i<16;i++)
    #pragma unroll
    for (int j=0;j<4;j++) acc[i][j]=0.f;

  for (int kk=0; kk<256; kk+=32){
    #pragma unroll
    for (int it=0; it<4; it++){
      int r = it*32 + (tid>>3);
      int kc = (tid&7)*4;
      float4 v = make_float4(0.f,0.f,0.f,0.f);
      int grow = row0 + r;
      if (grow < N) v = *(const float4*)&x[(size_t)grow*256 + kk + kc];
      xs[kc+0][r]=v.x; xs[kc+1][r]=v.y; xs[kc+2][r]=v.z; xs[kc+3][r]=v.w;
    }
    #pragma unroll
    for (int it=0; it<4; it++){
      int k = it*8 + (tid>>5);
      int c = (tid&31)*4;
      *(float4*)&wsh[k][c] = *(const float4*)&W[(size_t)(kk+k)*128 + c];
    }
    __syncthreads();
    #pragma unroll
    for (int k=0;k<32;k++){
      float4 b = *(float4*)&wsh[k][cg*4];
      float a[16];
      *(float4*)&a[0]  = *(float4*)&xs[k][rg*16+0];
      *(float4*)&a[4]  = *(float4*)&xs[k][rg*16+4];
      *(float4*)&a[8]  = *(float4*)&xs[k][rg*16+8];
      *(float4*)&a[12] = *(float4*)&xs[k][rg*16+12];
      #pragma unroll
      for (int i=0;i<16;i++){
        acc[i][0] = fmaf(a[i], b.x, acc[i][0]);
        acc[i][1] = fmaf(a[i], b.y, acc[i][1]);
        acc[i][2] = fmaf(a[i], b.z, acc[i][2]);
        acc[i][3] = fmaf(a[i], b.w, acc[i][3]);
      }
    }
    __syncthreads();
  }
  int c0 = cg*4;
  #pragma unroll
  for (int i=0;i<16;i++){
    int grow = row0 + rg*16 + i;
    if (grow < N){
      __half2 p01 = __floats2half2_rn(acc[i][0], acc[i][1]);
      __half2 p23 = __floats2half2_rn(acc[i][2], acc[i][3]);
      float2 st;
      *(__half2*)&st.x = p01;
      *(__half2*)&st.y = p23;
      *(float2*)&h1h[(size_t)grow*128 + c0] = st;
    }
  }
}

// ---------------- K2: per-(node,head) attention logits layer 1 (reads fp16 h) ----------------
__global__ void k_att1(const __half* __restrict__ h1h, const float* __restrict__ as_w,
                       const float* __restrict__ ad_w,
                       float* __restrict__ a_s, float* __restrict__ a_d, int N){
  int t = blockIdx.x*blockDim.x + threadIdx.x;
  if (t >= N*8) return;
  int n = t >> 3, h = t & 7;
  const __half* hp = &h1h[(size_t)n*128 + h*16];
  const float* wsp = &as_w[h*16];
  const float* wdp = &ad_w[h*16];
  float s=0.f, d=0.f;
  #pragma unroll
  for (int j=0;j<8;j++){
    __half2 hv = *(const __half2*)&hp[j*2];
    float2 f = __half22float2(hv);
    s = fmaf(f.x, wsp[j*2],   s); d = fmaf(f.x, wdp[j*2],   d);
    s = fmaf(f.y, wsp[j*2+1], s); d = fmaf(f.y, wdp[j*2+1], d);
  }
  a_s[t] = s; a_d[t] = d;
}

// ---------------- CSR build: histogram of in-degrees ----------------
__global__ void k_hist(const int* __restrict__ dst, int* __restrict__ deg, int E, int EE){
  int e = blockIdx.x*blockDim.x + threadIdx.x;
  if (e >= EE) return;
  int d = (e < E) ? dst[e] : (e - E);
  atomicAdd(&deg[d], 1);
}

// ---------------- CSR build: per-1024-block reduction ----------------
__global__ __launch_bounds__(256) void k_scan1(const int* __restrict__ deg, int* __restrict__ bsum){
  __shared__ int sred[256];
  int b = blockIdx.x, t = threadIdx.x;
  int4 v = *(const int4*)&deg[b*1024 + t*4];   // deg padded to 1024-multiple
  sred[t] = v.x+v.y+v.z+v.w;
  __syncthreads();
  for (int off=128; off; off>>=1){ if (t<off) sred[t]+=sred[t+off]; __syncthreads(); }
  if (t==0) bsum[b]=sred[0];
}

// ---------------- CSR build: scan of block sums (single tiny block) ----------------
__global__ void k_scan2(int* __restrict__ bsum, int nb){
  if (threadIdx.x==0 && blockIdx.x==0){
    int acc=0;
    for (int i=0;i<nb;i++){ int v=bsum[i]; bsum[i]=acc; acc+=v; }
  }
}

// ---------------- CSR build: final per-element exclusive scan ----------------
__global__ __launch_bounds__(256) void k_scan3(const int* __restrict__ deg, const int* __restrict__ bsum,
                        int* __restrict__ start, int* __restrict__ cursor, int N, int EE){
  __shared__ int sc[256];
  int b = blockIdx.x, t = threadIdx.x;
  int bi = b*1024 + t*4;
  int4 v = *(const int4*)&deg[bi];
  int ts = v.x+v.y+v.z+v.w;
  sc[t]=ts; __syncthreads();
  for (int off=1; off<256; off<<=1){
    int p = (t>=off)? sc[t-off] : 0;
    __syncthreads();
    sc[t]+=p;
    __syncthreads();
  }
  int excl = sc[t]-ts + bsum[b];
  int p0=excl, p1=p0+v.x, p2=p1+v.y, p3=p2+v.z;
  if (bi+0<N){ start[bi+0]=p0; cursor[bi+0]=p0; }
  if (bi+1<N){ start[bi+1]=p1; cursor[bi+1]=p1; }
  if (bi+2<N){ start[bi+2]=p2; cursor[bi+2]=p2; }
  if (bi+3<N){ start[bi+3]=p3; cursor[bi+3]=p3; }
  if (b==0 && t==0) start[N]=EE;
}

// ---------------- CSR build: fill source lists ----------------
__global__ void k_fill(const int* __restrict__ src, const int* __restrict__ dst,
                       int* __restrict__ cursor, int* __restrict__ csr_src, int E, int EE){
  int e = blockIdx.x*blockDim.x + threadIdx.x;
  if (e >= EE) return;
  int s, d;
  if (e < E){ s = src[e]; d = dst[e]; } else { s = e - E; d = s; }
  int p = atomicAdd(&cursor[d], 1);
  csr_src[p] = s;
}

// ---------------- K4: gather-side aggregation layer 1 (fp16 payload) ----------------
// Wave per dst node. Two half-waves; lane = 32*half + l32 covers channels
// [4*l32, 4*l32+3] (head = l32>>2). 4x unroll per half => 8 gather chains in
// flight; each chain now fetches 256 B/edge (fp16) instead of 512 B.
__global__ __launch_bounds__(256) void k_agg1(const int* __restrict__ start, const int* __restrict__ csr_src,
                      const float* __restrict__ a_s, const float* __restrict__ a_d,
                      const __half* __restrict__ h1h, float* __restrict__ acc1, int N){
  int wid = (blockIdx.x*blockDim.x + threadIdx.x) >> 6;
  int lane = threadIdx.x & 63;
  if (wid >= N) return;
  int d = wid;
  int half = lane >> 5;
  int l32  = lane & 31;
  int head = l32 >> 2;
  float ad = a_d[(size_t)d*8 + head];
  int beg = start[d], end = start[d+1];
  float ax=0.f, ay=0.f, az=0.f, aw=0.f, den=0.f;
  int j = beg + half;
  for (; j + 6 < end; j += 8){
    int s0 = csr_src[j];
    int s1 = csr_src[j+2];
    int s2 = csr_src[j+4];
    int s3 = csr_src[j+6];
    float e0 = __expf(lrelu(a_s[(size_t)s0*8 + head] + ad));
    float e1 = __expf(lrelu(a_s[(size_t)s1*8 + head] + ad));
    float e2 = __expf(lrelu(a_s[(size_t)s2*8 + head] + ad));
    float e3 = __expf(lrelu(a_s[(size_t)s3*8 + head] + ad));
    float2 r0 = *(const float2*)&h1h[(size_t)s0*128 + l32*4];
    float2 r1 = *(const float2*)&h1h[(size_t)s1*128 + l32*4];
    float2 r2 = *(const float2*)&h1h[(size_t)s2*128 + l32*4];
    float2 r3 = *(const float2*)&h1h[(size_t)s3*128 + l32*4];
    float2 f0a = __half22float2(*(__half2*)&r0.x), f0b = __half22float2(*(__half2*)&r0.y);
    float2 f1a = __half22float2(*(__half2*)&r1.x), f1b = __half22float2(*(__half2*)&r1.y);
    float2 f2a = __half22float2(*(__half2*)&r2.x), f2b = __half22float2(*(__half2*)&r2.y);
    float2 f3a = __half22float2(*(__half2*)&r3.x), f3b = __half22float2(*(__half2*)&r3.y);
    ax = fmaf(e0, f0a.x, ax); ay = fmaf(e0, f0a.y, ay); az = fmaf(e0, f0b.x, az); aw = fmaf(e0, f0b.y, aw);
    ax = fmaf(e1, f1a.x, ax); ay = fmaf(e1, f1a.y, ay); az = fmaf(e1, f1b.x, az); aw = fmaf(e1, f1b.y, aw);
    ax = fmaf(e2, f2a.x, ax); ay = fmaf(e2, f2a.y, ay); az = fmaf(e2, f2b.x, az); aw = fmaf(e2, f2b.y, aw);
    ax = fmaf(e3, f3a.x, ax); ay = fmaf(e3, f3a.y, ay); az = fmaf(e3, f3b.x, az); aw = fmaf(e3, f3b.y, aw);
    den += (e0 + e1) + (e2 + e3);
  }
  for (; j < end; j += 2){
    int s0 = csr_src[j];
    float e0 = __expf(lrelu(a_s[(size_t)s0*8 + head] + ad));
    float2 r0 = *(const float2*)&h1h[(size_t)s0*128 + l32*4];
    float2 f0a = __half22float2(*(__half2*)&r0.x), f0b = __half22float2(*(__half2*)&r0.y);
    ax = fmaf(e0, f0a.x, ax); ay = fmaf(e0, f0a.y, ay); az = fmaf(e0, f0b.x, az); aw = fmaf(e0, f0b.y, aw);
    den += e0;
  }
  // combine the two halves
  ax += __shfl_xor(ax, 32);
  ay += __shfl_xor(ay, 32);
  az += __shfl_xor(az, 32);
  aw += __shfl_xor(aw, 32);
  den += __shfl_xor(den, 32);
  float inv = (den > 0.f) ? 1.f/den : 0.f;
  if (half == 0){
    float4 o = make_float4(ax*inv, ay*inv, az*inv, aw*inv);
    *(float4*)&acc1[(size_t)d*128 + l32*4] = o;
  }
}

// ---------------- K5: elu + per-node [128]x[128,32] projection + layer-2 logits ----------------
__global__ __launch_bounds__(256) void k_layer2(const float* __restrict__ acc1, const float* __restrict__ b1,
                        const float* __restrict__ W2, const float* __restrict__ as2w,
                        const float* __restrict__ ad2w,
                        __half* __restrict__ h2ph, float* __restrict__ a_s2,
                        float* __restrict__ a_d2, int N){
  __shared__ float w2s[128][32];
  __shared__ float hs[8][128];
  int tid = threadIdx.x;
  #pragma unroll
  for (int it=0; it<16; it++){
    int idx = it*256 + tid;
    ((float*)w2s)[idx] = W2[idx];
  }
  int sub = tid>>5, ln = tid&31;
  int n = blockIdx.x*8 + sub;
  if (n < N){
    #pragma unroll
    for (int j=0;j<4;j++){
      int k = j*32 + ln;
      float v = acc1[(size_t)n*128+k] + b1[k];
      hs[sub][k] = v > 0.f ? v : (__expf(v) - 1.f);
    }
  }
  __syncthreads();
  if (n >= N) return;
  float o = 0.f;
  #pragma unroll
  for (int k=0;k<128;k++) o = fmaf(hs[sub][k], w2s[k][ln], o);
  h2ph[(size_t)n*32+ln] = __float2half_rn(o);
  float ps = o*as2w[ln], pd = o*ad2w[ln];
  #pragma unroll
  for (int m=16;m;m>>=1){ ps += __shfl_xor(ps,m); pd += __shfl_xor(pd,m); }
  if (ln==0){ a_s2[n]=ps; a_d2[n]=pd; }
}

// ---------------- K6: gather aggregation layer 2 + bias + log_softmax (fp16 payload) ----------------
__global__ __launch_bounds__(256) void k_agg2(const int* __restrict__ start, const int* __restrict__ csr_src,
                      const float* __restrict__ a_s2, const float* __restrict__ a_d2,
                      const __half* __restrict__ h2ph, const float* __restrict__ b2,
                      float* __restrict__ out, int N){
  int g = (blockIdx.x*blockDim.x + threadIdx.x) >> 5;
  int ln = threadIdx.x & 31;
  if (g >= N) return;
  int d = g;
  float ad = a_d2[d];
  int beg = start[d], end = start[d+1];
  float acc=0.f, den=0.f;
  int j = beg;
  for (; j + 3 < end; j += 4){
    int s0 = csr_src[j];
    int s1 = csr_src[j+1];
    int s2 = csr_src[j+2];
    int s3 = csr_src[j+3];
    float e0 = __expf(lrelu(a_s2[s0] + ad));
    float e1 = __expf(lrelu(a_s2[s1] + ad));
    float e2 = __expf(lrelu(a_s2[s2] + ad));
    float e3 = __expf(lrelu(a_s2[s3] + ad));
    float v0 = __half2float(h2ph[(size_t)s0*32 + ln]);
    float v1 = __half2float(h2ph[(size_t)s1*32 + ln]);
    float v2 = __half2float(h2ph[(size_t)s2*32 + ln]);
    float v3 = __half2float(h2ph[(size_t)s3*32 + ln]);
    acc = fmaf(e0, v0, acc);
    acc = fmaf(e1, v1, acc);
    acc = fmaf(e2, v2, acc);
    acc = fmaf(e3, v3, acc);
    den += (e0 + e1) + (e2 + e3);
  }
  for (; j < end; j++){
    int s0 = csr_src[j];
    float e0 = __expf(lrelu(a_s2[s0] + ad));
    acc = fmaf(e0, __half2float(h2ph[(size_t)s0*32 + ln]), acc);
    den += e0;
  }
  float v = acc/den + b2[ln];
  float mx = v;
  #pragma unroll
  for (int m=16;m;m>>=1) mx = fmaxf(mx, __shfl_xor(mx,m));
  float ex2 = __expf(v-mx);
  float sm = ex2;
  #pragma unroll
  for (int m=16;m;m>>=1) sm += __shfl_xor(sm,m);
  out[(size_t)d*32+ln] = v - mx - __logf(sm);
}

extern "C" void kernel_launch(void* const* d_in, const int* in_sizes, int n_in,
                              void* d_out, int out_size, void* d_ws, size_t ws_size,
                              hipStream_t stream){
  const float* x   = (const float*)d_in[0];
  const int*   ei  = (const int*)d_in[1];
  const float* W1  = (const float*)d_in[3];
  const float* as1 = (const float*)d_in[4];
  const float* ad1 = (const float*)d_in[5];
  const float* b1  = (const float*)d_in[6];
  const float* W2  = (const float*)d_in[7];
  const float* as2 = (const float*)d_in[8];
  const float* ad2 = (const float*)d_in[9];
  const float* b2  = (const float*)d_in[10];

  int N  = in_sizes[0] / 256;
  int E  = in_sizes[2];
  int EE = E + N;
  const int* src = ei;
  const int* dst = ei + E;

  int nb = (N + 1023) / 1024;
  int NP = nb * 1024;

  // ---- workspace layout: ints first (16B-aligned), then floats, then halfs ----
  int* iw = (int*)d_ws;
  int* deg     = iw;                 iw += NP;
  int* bsum    = iw;                 iw += ((nb+255)/256)*256;
  int* start_  = iw;                 iw += ((N+1+3)/4)*4;
  int* cursor  = iw;                 iw += ((N+3)/4)*4;
  int* csr_src = iw;                 iw += ((EE+3)/4)*4;

  float* w = (float*)iw;
  float* a_s1   = w; w += (size_t)N*8;
  float* a_d1   = w; w += (size_t)N*8;
  float* acc1   = w; w += (size_t)N*128;
  float* a_s2   = w; w += (size_t)N;
  float* a_d2   = w; w += (size_t)N;
  __half* h1h   = (__half*)w; w += (size_t)N*64;   // N*128 halfs
  __half* h2ph  = (__half*)w; w += (size_t)N*16;   // N*32 halfs
  float* out    = (float*)d_out;

  // zero in-degree histogram (padded region)
  hipLaunchKernelGGL(k_zero, dim3(512), dim3(256), 0, stream, deg, NP);
  // dense transforms
  hipLaunchKernelGGL(k_gemm1, dim3((N+127)/128), dim3(256), 0, stream, x, W1, h1h, N);
  hipLaunchKernelGGL(k_att1, dim3((N*8+255)/256), dim3(256), 0, stream, h1h, as1, ad1, a_s1, a_d1, N);
  // CSR build (shared by both layers)
  hipLaunchKernelGGL(k_hist, dim3((EE+255)/256), dim3(256), 0, stream, dst, deg, E, EE);
  hipLaunchKernelGGL(k_scan1, dim3(nb), dim3(256), 0, stream, deg, bsum);
  hipLaunchKernelGGL(k_scan2, dim3(1), dim3(64), 0, stream, bsum, nb);
  hipLaunchKernelGGL(k_scan3, dim3(nb), dim3(256), 0, stream, deg, bsum, start_, cursor, N, EE);
  hipLaunchKernelGGL(k_fill, dim3((EE+255)/256), dim3(256), 0, stream, src, dst, cursor, csr_src, E, EE);
  // layer 1: gather aggregation (no atomics)
  hipLaunchKernelGGL(k_agg1, dim3((N+3)/4), dim3(256), 0, stream, start_, csr_src, a_s1, a_d1, h1h, acc1, N);
  // layer 2: elu + projection + logits
  hipLaunchKernelGGL(k_layer2, dim3((N+7)/8), dim3(256), 0, stream, acc1, b1, W2, as2, ad2, h2ph, a_s2, a_d2, N);
  // layer 2 aggregation fused with bias + log_softmax
  hipLaunchKernelGGL(k_agg2, dim3((N+7)/8), dim3(256), 0, stream, start_, csr_src, a_s2, a_d2, h2ph, b2, out, N);
}

// Round 8
// 477.808 us; speedup vs baseline: 5.2915x; 1.1223x over previous
//
#include <hip/hip_runtime.h>
#include <hip/hip_fp16.h>
#include <math.h>

#define NEG_SLOPE 0.2f

typedef _Float16 half8 __attribute__((ext_vector_type(8)));
typedef _Float16 half4 __attribute__((ext_vector_type(4)));
typedef float f32x4 __attribute__((ext_vector_type(4)));

__device__ __forceinline__ float lrelu(float x){ return x > 0.f ? x : NEG_SLOPE*x; }

// ---------------- K0: zero a region of ints ----------------
__global__ void k_zero(int* __restrict__ p, int n){
  int i = blockIdx.x*blockDim.x + threadIdx.x;
  int stride = gridDim.x*blockDim.x;
  for (; i < n; i += stride) p[i] = 0;
}

// ---------------- prep: Wt[128][256] fp16 = transpose(W1[256,128]) ----------------
__global__ void k_prepw(const float* __restrict__ W, _Float16* __restrict__ Wt){
  int t = blockIdx.x*blockDim.x + threadIdx.x;   // 32768
  int c = t >> 8, k = t & 255;
  Wt[t] = (_Float16)W[k*128 + c];
}

// ---------------- K1: h1h[N,128](fp16) = x[N,256] @ W1 via MFMA f16 ----------------
// 128x128 tile, 4 waves; wave w: rows w*32..w*32+31 (2 row-frags) x 128 cols (8 col-frags).
// LDS stride 40 halfs => <=2-way bank conflicts everywhere.
__global__ __launch_bounds__(256) void k_gemm1(const float* __restrict__ x,
                                               const _Float16* __restrict__ Wt,
                                               _Float16* __restrict__ h1h, int N){
  __shared__ _Float16 aL[128*40];
  __shared__ _Float16 bL[128*40];
  int tid = threadIdx.x;
  int w = tid >> 6, lane = tid & 63;
  int fq = lane >> 4, fr = lane & 15;
  int row0 = blockIdx.x * 128;
  f32x4 acc[2][8];
  #pragma unroll
  for (int m=0;m<2;m++)
    #pragma unroll
    for (int n=0;n<8;n++) acc[m][n] = (f32x4){0.f,0.f,0.f,0.f};

  for (int kk=0; kk<256; kk+=32){
    // stage A: x[row0+r][kk+kc..kc+3] fp32 -> fp16 LDS
    #pragma unroll
    for (int it=0; it<4; it++){
      int r = it*32 + (tid>>3);
      int kc = (tid&7)*4;
      float4 v = make_float4(0.f,0.f,0.f,0.f);
      int gr = row0 + r;
      if (gr < N) v = *(const float4*)&x[(size_t)gr*256 + kk + kc];
      half4 hv;
      hv[0]=(_Float16)v.x; hv[1]=(_Float16)v.y; hv[2]=(_Float16)v.z; hv[3]=(_Float16)v.w;
      *(half4*)&aL[r*40 + kc] = hv;
    }
    // stage B: Wt[c][kk+ch..ch+7] -> LDS (col-major along k)
    #pragma unroll
    for (int it=0; it<2; it++){
      int chunk = it*256 + tid;
      int c = chunk >> 2;
      int ch = (chunk & 3) * 8;
      half8 v = *(const half8*)&Wt[(size_t)c*256 + kk + ch];
      *(half8*)&bL[c*40 + ch] = v;
    }
    __syncthreads();
    int kb = fq*8;
    half8 afrag[2], bfrag[8];
    #pragma unroll
    for (int m=0;m<2;m++) afrag[m] = *(half8*)&aL[(w*32 + m*16 + fr)*40 + kb];
    #pragma unroll
    for (int n=0;n<8;n++) bfrag[n] = *(half8*)&bL[(n*16 + fr)*40 + kb];
    #pragma unroll
    for (int m=0;m<2;m++)
      #pragma unroll
      for (int n=0;n<8;n++)
        acc[m][n] = __builtin_amdgcn_mfma_f32_16x16x32_f16(afrag[m], bfrag[n], acc[m][n], 0, 0, 0);
    __syncthreads();
  }
  // write: D row = w*32 + m*16 + fq*4 + j, col = n*16 + fr
  #pragma unroll
  for (int m=0;m<2;m++){
    #pragma unroll
    for (int j=0;j<4;j++){
      int gr = row0 + w*32 + m*16 + fq*4 + j;
      if (gr < N){
        #pragma unroll
        for (int n=0;n<8;n++)
          h1h[(size_t)gr*128 + n*16 + fr] = (_Float16)acc[m][n][j];
      }
    }
  }
}

// ---------------- K2: per-(node,head) attention logits layer 1 (reads fp16 h) ----------------
__global__ void k_att1(const __half* __restrict__ h1h, const float* __restrict__ as_w,
                       const float* __restrict__ ad_w,
                       float* __restrict__ a_s, float* __restrict__ a_d, int N){
  int t = blockIdx.x*blockDim.x + threadIdx.x;
  if (t >= N*8) return;
  int n = t >> 3, h = t & 7;
  const __half* hp = &h1h[(size_t)n*128 + h*16];
  const float* wsp = &as_w[h*16];
  const float* wdp = &ad_w[h*16];
  float s=0.f, d=0.f;
  #pragma unroll
  for (int j=0;j<8;j++){
    __half2 hv = *(const __half2*)&hp[j*2];
    float2 f = __half22float2(hv);
    s = fmaf(f.x, wsp[j*2],   s); d = fmaf(f.x, wdp[j*2],   d);
    s = fmaf(f.y, wsp[j*2+1], s); d = fmaf(f.y, wdp[j*2+1], d);
  }
  a_s[t] = s; a_d[t] = d;
}

// ---------------- CSR build: histogram of in-degrees ----------------
__global__ void k_hist(const int* __restrict__ dst, int* __restrict__ deg, int E, int EE){
  int e = blockIdx.x*blockDim.x + threadIdx.x;
  if (e >= EE) return;
  int d = (e < E) ? dst[e] : (e - E);
  atomicAdd(&deg[d], 1);
}

// ---------------- CSR build: per-1024-block reduction ----------------
__global__ __launch_bounds__(256) void k_scan1(const int* __restrict__ deg, int* __restrict__ bsum){
  __shared__ int sred[256];
  int b = blockIdx.x, t = threadIdx.x;
  int4 v = *(const int4*)&deg[b*1024 + t*4];   // deg padded to 1024-multiple
  sred[t] = v.x+v.y+v.z+v.w;
  __syncthreads();
  for (int off=128; off; off>>=1){ if (t<off) sred[t]+=sred[t+off]; __syncthreads(); }
  if (t==0) bsum[b]=sred[0];
}

// ---------------- CSR build: scan of block sums (single tiny block) ----------------
__global__ void k_scan2(int* __restrict__ bsum, int nb){
  if (threadIdx.x==0 && blockIdx.x==0){
    int acc=0;
    for (int i=0;i<nb;i++){ int v=bsum[i]; bsum[i]=acc; acc+=v; }
  }
}

// ---------------- CSR build: final per-element exclusive scan ----------------
__global__ __launch_bounds__(256) void k_scan3(const int* __restrict__ deg, const int* __restrict__ bsum,
                        int* __restrict__ start, int* __restrict__ cursor, int N, int EE){
  __shared__ int sc[256];
  int b = blockIdx.x, t = threadIdx.x;
  int bi = b*1024 + t*4;
  int4 v = *(const int4*)&deg[bi];
  int ts = v.x+v.y+v.z+v.w;
  sc[t]=ts; __syncthreads();
  for (int off=1; off<256; off<<=1){
    int p = (t>=off)? sc[t-off] : 0;
    __syncthreads();
    sc[t]+=p;
    __syncthreads();
  }
  int excl = sc[t]-ts + bsum[b];
  int p0=excl, p1=p0+v.x, p2=p1+v.y, p3=p2+v.z;
  if (bi+0<N){ start[bi+0]=p0; cursor[bi+0]=p0; }
  if (bi+1<N){ start[bi+1]=p1; cursor[bi+1]=p1; }
  if (bi+2<N){ start[bi+2]=p2; cursor[bi+2]=p2; }
  if (bi+3<N){ start[bi+3]=p3; cursor[bi+3]=p3; }
  if (b==0 && t==0) start[N]=EE;
}

// ---------------- CSR build: fill source lists ----------------
__global__ void k_fill(const int* __restrict__ src, const int* __restrict__ dst,
                       int* __restrict__ cursor, int* __restrict__ csr_src, int E, int EE){
  int e = blockIdx.x*blockDim.x + threadIdx.x;
  if (e >= EE) return;
  int s, d;
  if (e < E){ s = src[e]; d = dst[e]; } else { s = e - E; d = s; }
  int p = atomicAdd(&cursor[d], 1);
  csr_src[p] = s;
}

// ---------------- K4: gather-side aggregation layer 1 (fp16 payload) ----------------
__global__ __launch_bounds__(256) void k_agg1(const int* __restrict__ start, const int* __restrict__ csr_src,
                      const float* __restrict__ a_s, const float* __restrict__ a_d,
                      const __half* __restrict__ h1h, float* __restrict__ acc1, int N){
  int wid = (blockIdx.x*blockDim.x + threadIdx.x) >> 6;
  int lane = threadIdx.x & 63;
  if (wid >= N) return;
  int d = wid;
  int half = lane >> 5;
  int l32  = lane & 31;
  int head = l32 >> 2;
  float ad = a_d[(size_t)d*8 + head];
  int beg = start[d], end = start[d+1];
  float ax=0.f, ay=0.f, az=0.f, aw=0.f, den=0.f;
  int j = beg + half;
  for (; j + 6 < end; j += 8){
    int s0 = csr_src[j];
    int s1 = csr_src[j+2];
    int s2 = csr_src[j+4];
    int s3 = csr_src[j+6];
    float e0 = __expf(lrelu(a_s[(size_t)s0*8 + head] + ad));
    float e1 = __expf(lrelu(a_s[(size_t)s1*8 + head] + ad));
    float e2 = __expf(lrelu(a_s[(size_t)s2*8 + head] + ad));
    float e3 = __expf(lrelu(a_s[(size_t)s3*8 + head] + ad));
    float2 r0 = *(const float2*)&h1h[(size_t)s0*128 + l32*4];
    float2 r1 = *(const float2*)&h1h[(size_t)s1*128 + l32*4];
    float2 r2 = *(const float2*)&h1h[(size_t)s2*128 + l32*4];
    float2 r3 = *(const float2*)&h1h[(size_t)s3*128 + l32*4];
    float2 f0a = __half22float2(*(__half2*)&r0.x), f0b = __half22float2(*(__half2*)&r0.y);
    float2 f1a = __half22float2(*(__half2*)&r1.x), f1b = __half22float2(*(__half2*)&r1.y);
    float2 f2a = __half22float2(*(__half2*)&r2.x), f2b = __half22float2(*(__half2*)&r2.y);
    float2 f3a = __half22float2(*(__half2*)&r3.x), f3b = __half22float2(*(__half2*)&r3.y);
    ax = fmaf(e0, f0a.x, ax); ay = fmaf(e0, f0a.y, ay); az = fmaf(e0, f0b.x, az); aw = fmaf(e0, f0b.y, aw);
    ax = fmaf(e1, f1a.x, ax); ay = fmaf(e1, f1a.y, ay); az = fmaf(e1, f1b.x, az); aw = fmaf(e1, f1b.y, aw);
    ax = fmaf(e2, f2a.x, ax); ay = fmaf(e2, f2a.y, ay); az = fmaf(e2, f2b.x, az); aw = fmaf(e2, f2b.y, aw);
    ax = fmaf(e3, f3a.x, ax); ay = fmaf(e3, f3a.y, ay); az = fmaf(e3, f3b.x, az); aw = fmaf(e3, f3b.y, aw);
    den += (e0 + e1) + (e2 + e3);
  }
  for (; j < end; j += 2){
    int s0 = csr_src[j];
    float e0 = __expf(lrelu(a_s[(size_t)s0*8 + head] + ad));
    float2 r0 = *(const float2*)&h1h[(size_t)s0*128 + l32*4];
    float2 f0a = __half22float2(*(__half2*)&r0.x), f0b = __half22float2(*(__half2*)&r0.y);
    ax = fmaf(e0, f0a.x, ax); ay = fmaf(e0, f0a.y, ay); az = fmaf(e0, f0b.x, az); aw = fmaf(e0, f0b.y, aw);
    den += e0;
  }
  ax += __shfl_xor(ax, 32);
  ay += __shfl_xor(ay, 32);
  az += __shfl_xor(az, 32);
  aw += __shfl_xor(aw, 32);
  den += __shfl_xor(den, 32);
  float inv = (den > 0.f) ? 1.f/den : 0.f;
  if (half == 0){
    float4 o = make_float4(ax*inv, ay*inv, az*inv, aw*inv);
    *(float4*)&acc1[(size_t)d*128 + l32*4] = o;
  }
}

// ---------------- K5: elu + per-node [128]x[128,32] projection + layer-2 logits ----------------
__global__ __launch_bounds__(256) void k_layer2(const float* __restrict__ acc1, const float* __restrict__ b1,
                        const float* __restrict__ W2, const float* __restrict__ as2w,
                        const float* __restrict__ ad2w,
                        __half* __restrict__ h2ph, float* __restrict__ a_s2,
                        float* __restrict__ a_d2, int N){
  __shared__ float w2s[128][32];
  __shared__ float hs[8][128];
  int tid = threadIdx.x;
  #pragma unroll
  for (int it=0; it<16; it++){
    int idx = it*256 + tid;
    ((float*)w2s)[idx] = W2[idx];
  }
  int sub = tid>>5, ln = tid&31;
  int n = blockIdx.x*8 + sub;
  if (n < N){
    #pragma unroll
    for (int j=0;j<4;j++){
      int k = j*32 + ln;
      float v = acc1[(size_t)n*128+k] + b1[k];
      hs[sub][k] = v > 0.f ? v : (__expf(v) - 1.f);
    }
  }
  __syncthreads();
  if (n >= N) return;
  float o = 0.f;
  #pragma unroll
  for (int k=0;k<128;k++) o = fmaf(hs[sub][k], w2s[k][ln], o);
  h2ph[(size_t)n*32+ln] = __float2half_rn(o);
  float ps = o*as2w[ln], pd = o*ad2w[ln];
  #pragma unroll
  for (int m=16;m;m>>=1){ ps += __shfl_xor(ps,m); pd += __shfl_xor(pd,m); }
  if (ln==0){ a_s2[n]=ps; a_d2[n]=pd; }
}

// ---------------- K6: gather aggregation layer 2 + bias + log_softmax (fp16 payload) ----------------
__global__ __launch_bounds__(256) void k_agg2(const int* __restrict__ start, const int* __restrict__ csr_src,
                      const float* __restrict__ a_s2, const float* __restrict__ a_d2,
                      const __half* __restrict__ h2ph, const float* __restrict__ b2,
                      float* __restrict__ out, int N){
  int g = (blockIdx.x*blockDim.x + threadIdx.x) >> 5;
  int ln = threadIdx.x & 31;
  if (g >= N) return;
  int d = g;
  float ad = a_d2[d];
  int beg = start[d], end = start[d+1];
  float acc=0.f, den=0.f;
  int j = beg;
  for (; j + 3 < end; j += 4){
    int s0 = csr_src[j];
    int s1 = csr_src[j+1];
    int s2 = csr_src[j+2];
    int s3 = csr_src[j+3];
    float e0 = __expf(lrelu(a_s2[s0] + ad));
    float e1 = __expf(lrelu(a_s2[s1] + ad));
    float e2 = __expf(lrelu(a_s2[s2] + ad));
    float e3 = __expf(lrelu(a_s2[s3] + ad));
    float v0 = __half2float(h2ph[(size_t)s0*32 + ln]);
    float v1 = __half2float(h2ph[(size_t)s1*32 + ln]);
    float v2 = __half2float(h2ph[(size_t)s2*32 + ln]);
    float v3 = __half2float(h2ph[(size_t)s3*32 + ln]);
    acc = fmaf(e0, v0, acc);
    acc = fmaf(e1, v1, acc);
    acc = fmaf(e2, v2, acc);
    acc = fmaf(e3, v3, acc);
    den += (e0 + e1) + (e2 + e3);
  }
  for (; j < end; j++){
    int s0 = csr_src[j];
    float e0 = __expf(lrelu(a_s2[s0] + ad));
    acc = fmaf(e0, __half2float(h2ph[(size_t)s0*32 + ln]), acc);
    den += e0;
  }
  float v = acc/den + b2[ln];
  float mx = v;
  #pragma unroll
  for (int m=16;m;m>>=1) mx = fmaxf(mx, __shfl_xor(mx,m));
  float ex2 = __expf(v-mx);
  float sm = ex2;
  #pragma unroll
  for (int m=16;m;m>>=1) sm += __shfl_xor(sm,m);
  out[(size_t)d*32+ln] = v - mx - __logf(sm);
}

extern "C" void kernel_launch(void* const* d_in, const int* in_sizes, int n_in,
                              void* d_out, int out_size, void* d_ws, size_t ws_size,
                              hipStream_t stream){
  const float* x   = (const float*)d_in[0];
  const int*   ei  = (const int*)d_in[1];
  const float* W1  = (const float*)d_in[3];
  const float* as1 = (const float*)d_in[4];
  const float* ad1 = (const float*)d_in[5];
  const float* b1  = (const float*)d_in[6];
  const float* W2  = (const float*)d_in[7];
  const float* as2 = (const float*)d_in[8];
  const float* ad2 = (const float*)d_in[9];
  const float* b2  = (const float*)d_in[10];

  int N  = in_sizes[0] / 256;
  int E  = in_sizes[2];
  int EE = E + N;
  const int* src = ei;
  const int* dst = ei + E;

  int nb = (N + 1023) / 1024;
  int NP = nb * 1024;

  // ---- workspace layout: ints first (16B-aligned), then floats, then halfs ----
  int* iw = (int*)d_ws;
  int* deg     = iw;                 iw += NP;
  int* bsum    = iw;                 iw += ((nb+255)/256)*256;
  int* start_  = iw;                 iw += ((N+1+3)/4)*4;
  int* cursor  = iw;                 iw += ((N+3)/4)*4;
  int* csr_src = iw;                 iw += ((EE+3)/4)*4;

  float* w = (float*)iw;
  float* a_s1   = w; w += (size_t)N*8;
  float* a_d1   = w; w += (size_t)N*8;
  float* acc1   = w; w += (size_t)N*128;
  float* a_s2   = w; w += (size_t)N;
  float* a_d2   = w; w += (size_t)N;
  _Float16* h1h  = (_Float16*)w; w += (size_t)N*64;   // N*128 halfs
  _Float16* h2ph = (_Float16*)w; w += (size_t)N*16;   // N*32 halfs
  _Float16* Wt   = (_Float16*)w; w += 32768/2;        // 128*256 halfs
  float* out    = (float*)d_out;

  // zero in-degree histogram (padded region)
  hipLaunchKernelGGL(k_zero, dim3(512), dim3(256), 0, stream, deg, NP);
  // W1 -> fp16 transpose
  hipLaunchKernelGGL(k_prepw, dim3(128), dim3(256), 0, stream, W1, Wt);
  // dense transforms
  hipLaunchKernelGGL(k_gemm1, dim3((N+127)/128), dim3(256), 0, stream, x, Wt, h1h, N);
  hipLaunchKernelGGL(k_att1, dim3((N*8+255)/256), dim3(256), 0, stream, (const __half*)h1h, as1, ad1, a_s1, a_d1, N);
  // CSR build (shared by both layers)
  hipLaunchKernelGGL(k_hist, dim3((EE+255)/256), dim3(256), 0, stream, dst, deg, E, EE);
  hipLaunchKernelGGL(k_scan1, dim3(nb), dim3(256), 0, stream, deg, bsum);
  hipLaunchKernelGGL(k_scan2, dim3(1), dim3(64), 0, stream, bsum, nb);
  hipLaunchKernelGGL(k_scan3, dim3(nb), dim3(256), 0, stream, deg, bsum, start_, cursor, N, EE);
  hipLaunchKernelGGL(k_fill, dim3((EE+255)/256), dim3(256), 0, stream, src, dst, cursor, csr_src, E, EE);
  // layer 1: gather aggregation (no atomics)
  hipLaunchKernelGGL(k_agg1, dim3((N+3)/4), dim3(256), 0, stream, start_, csr_src, a_s1, a_d1, (const __half*)h1h, acc1, N);
  // layer 2: elu + projection + logits
  hipLaunchKernelGGL(k_layer2, dim3((N+7)/8), dim3(256), 0, stream, acc1, b1, W2, as2, ad2, (__half*)h2ph, a_s2, a_d2, N);
  // layer 2 aggregation fused with bias + log_softmax
  hipLaunchKernelGGL(k_agg2, dim3((N+7)/8), dim3(256), 0, stream, start_, csr_src, a_s2, a_d2, (const __half*)h2ph, b2, out, N);
}

// Round 9
// 322.861 us; speedup vs baseline: 7.8310x; 1.4799x over previous
//
#include <hip/hip_runtime.h>
#include <hip/hip_fp16.h>
#include <math.h>

#define NEG_SLOPE 0.2f
#define NBLK 256   // partition blocks; bh layout depends on this

typedef _Float16 half8 __attribute__((ext_vector_type(8)));
typedef _Float16 half4 __attribute__((ext_vector_type(4)));
typedef float f32x4 __attribute__((ext_vector_type(4)));

__device__ __forceinline__ float lrelu(float x){ return x > 0.f ? x : NEG_SLOPE*x; }

// ---------------- prep: Wt[128][256] fp16 = transpose(W1[256,128]) ----------------
__global__ void k_prepw(const float* __restrict__ W, _Float16* __restrict__ Wt){
  int t = blockIdx.x*blockDim.x + threadIdx.x;   // 32768
  int c = t >> 8, k = t & 255;
  Wt[t] = (_Float16)W[k*128 + c];
}

// ---------------- K1: h1h[N,128](fp16) = x[N,256] @ W1 via MFMA f16 ----------------
__global__ __launch_bounds__(256) void k_gemm1(const float* __restrict__ x,
                                               const _Float16* __restrict__ Wt,
                                               _Float16* __restrict__ h1h, int N){
  __shared__ _Float16 aL[128*40];
  __shared__ _Float16 bL[128*40];
  int tid = threadIdx.x;
  int w = tid >> 6, lane = tid & 63;
  int fq = lane >> 4, fr = lane & 15;
  int row0 = blockIdx.x * 128;
  f32x4 acc[2][8];
  #pragma unroll
  for (int m=0;m<2;m++)
    #pragma unroll
    for (int n=0;n<8;n++) acc[m][n] = (f32x4){0.f,0.f,0.f,0.f};

  for (int kk=0; kk<256; kk+=32){
    #pragma unroll
    for (int it=0; it<4; it++){
      int r = it*32 + (tid>>3);
      int kc = (tid&7)*4;
      float4 v = make_float4(0.f,0.f,0.f,0.f);
      int gr = row0 + r;
      if (gr < N) v = *(const float4*)&x[(size_t)gr*256 + kk + kc];
      half4 hv;
      hv[0]=(_Float16)v.x; hv[1]=(_Float16)v.y; hv[2]=(_Float16)v.z; hv[3]=(_Float16)v.w;
      *(half4*)&aL[r*40 + kc] = hv;
    }
    #pragma unroll
    for (int it=0; it<2; it++){
      int chunk = it*256 + tid;
      int c = chunk >> 2;
      int ch = (chunk & 3) * 8;
      half8 v = *(const half8*)&Wt[(size_t)c*256 + kk + ch];
      *(half8*)&bL[c*40 + ch] = v;
    }
    __syncthreads();
    int kb = fq*8;
    half8 afrag[2], bfrag[8];
    #pragma unroll
    for (int m=0;m<2;m++) afrag[m] = *(half8*)&aL[(w*32 + m*16 + fr)*40 + kb];
    #pragma unroll
    for (int n=0;n<8;n++) bfrag[n] = *(half8*)&bL[(n*16 + fr)*40 + kb];
    #pragma unroll
    for (int m=0;m<2;m++)
      #pragma unroll
      for (int n=0;n<8;n++)
        acc[m][n] = __builtin_amdgcn_mfma_f32_16x16x32_f16(afrag[m], bfrag[n], acc[m][n], 0, 0, 0);
    __syncthreads();
  }
  #pragma unroll
  for (int m=0;m<2;m++){
    #pragma unroll
    for (int j=0;j<4;j++){
      int gr = row0 + w*32 + m*16 + fq*4 + j;
      if (gr < N){
        #pragma unroll
        for (int n=0;n<8;n++)
          h1h[(size_t)gr*128 + n*16 + fr] = (_Float16)acc[m][n][j];
      }
    }
  }
}

// ---------------- K2: per-(node,head) attention logits layer 1 ----------------
__global__ void k_att1(const __half* __restrict__ h1h, const float* __restrict__ as_w,
                       const float* __restrict__ ad_w,
                       float* __restrict__ a_s, float* __restrict__ a_d, int N){
  int t = blockIdx.x*blockDim.x + threadIdx.x;
  if (t >= N*8) return;
  int n = t >> 3, h = t & 7;
  const __half* hp = &h1h[(size_t)n*128 + h*16];
  const float* wsp = &as_w[h*16];
  const float* wdp = &ad_w[h*16];
  float s=0.f, d=0.f;
  #pragma unroll
  for (int j=0;j<8;j++){
    __half2 hv = *(const __half2*)&hp[j*2];
    float2 f = __half22float2(hv);
    s = fmaf(f.x, wsp[j*2],   s); d = fmaf(f.x, wdp[j*2],   d);
    s = fmaf(f.y, wsp[j*2+1], s); d = fmaf(f.y, wdp[j*2+1], d);
  }
  a_s[t] = s; a_d[t] = d;
}

// ---------------- CSR: per-block bucket histogram ----------------
__global__ __launch_bounds__(256) void k_bh(const int* __restrict__ dst, int* __restrict__ bh,
                                            int E, int EE, int NB){
  __shared__ int h[1024];
  int tid = threadIdx.x, blk = blockIdx.x;
  for (int i=tid;i<1024;i+=256) h[i]=0;
  __syncthreads();
  int chunk = (EE + NBLK - 1)/NBLK;
  int e0 = blk*chunk, e1 = min(e0+chunk, EE);
  for (int e=e0+tid; e<e1; e+=256){
    int d = (e<E)? dst[e] : (e-E);
    atomicAdd(&h[d>>7], 1);
  }
  __syncthreads();
  for (int i=tid;i<NB;i+=256) bh[i*NBLK + blk] = h[i];
}

// ---------------- CSR: per-bucket scan over blocks -> relative offsets + totals ----------------
__global__ __launch_bounds__(256) void k_scanA(int* __restrict__ bh, int* __restrict__ btot){
  __shared__ int t[256];
  int b = blockIdx.x, tid = threadIdx.x;
  int v = bh[b*NBLK + tid];
  t[tid] = v;
  __syncthreads();
  for (int off=1; off<256; off<<=1){
    int p = (tid>=off)? t[tid-off] : 0;
    __syncthreads();
    t[tid] += p;
    __syncthreads();
  }
  bh[b*NBLK + tid] = t[tid] - v;     // exclusive within bucket
  if (tid==255) btot[b] = t[255];
}

// ---------------- CSR: scan of bucket totals -> bucket bases ----------------
__global__ __launch_bounds__(256) void k_bscan(const int* __restrict__ btot, int* __restrict__ bbase,
                                               int* __restrict__ start_, int NB, int N, int EE){
  __shared__ int t[256];
  int tid = threadIdx.x;
  int i0 = tid*4;
  int a0 = (i0+0<NB)? btot[i0+0] : 0;
  int a1 = (i0+1<NB)? btot[i0+1] : 0;
  int a2 = (i0+2<NB)? btot[i0+2] : 0;
  int a3 = (i0+3<NB)? btot[i0+3] : 0;
  int s = a0+a1+a2+a3;
  t[tid] = s;
  __syncthreads();
  for (int off=1; off<256; off<<=1){
    int p = (tid>=off)? t[tid-off] : 0;
    __syncthreads();
    t[tid] += p;
    __syncthreads();
  }
  int excl = t[tid] - s;
  int e0=excl, e1=e0+a0, e2=e1+a1, e3=e2+a2;
  if (i0+0<NB) bbase[i0+0]=e0;
  if (i0+1<NB) bbase[i0+1]=e1;
  if (i0+2<NB) bbase[i0+2]=e2;
  if (i0+3<NB) bbase[i0+3]=e3;
  if (tid==0){ bbase[NB] = EE; start_[N] = EE; }
}

// ---------------- CSR: stable partition fill (LDS cursors, contiguous per block) ----------------
__global__ __launch_bounds__(256) void k_bfill(const int* __restrict__ src, const int* __restrict__ dst,
                       const int* __restrict__ bh, const int* __restrict__ bbase,
                       uint2* __restrict__ pairs, int E, int EE, int NB){
  __shared__ int cur[1024];
  int tid = threadIdx.x, blk = blockIdx.x;
  for (int i=tid;i<NB;i+=256) cur[i] = bbase[i] + bh[i*NBLK + blk];
  __syncthreads();
  int chunk = (EE + NBLK - 1)/NBLK;
  int e0 = blk*chunk, e1 = min(e0+chunk, EE);
  for (int e=e0+tid; e<e1; e+=256){
    int s,d;
    if (e<E){ s=src[e]; d=dst[e]; } else { s=e-E; d=s; }
    int p = atomicAdd(&cur[d>>7], 1);
    pairs[p] = make_uint2((unsigned)s,(unsigned)d);
  }
}

// ---------------- CSR: per-bucket local sort -> start_[] + csr_src ----------------
__global__ __launch_bounds__(256) void k_pb(const int* __restrict__ bbase, const uint2* __restrict__ pairs,
                    int* __restrict__ start_, int* __restrict__ csr_src, int N){
  __shared__ int hist[128];
  __shared__ int excl[128];
  int b = blockIdx.x;
  int tid = threadIdx.x;
  int base = bbase[b], cnt = bbase[b+1] - base;
  if (tid<128) hist[tid]=0;
  __syncthreads();
  for (int i=tid;i<cnt;i+=256){
    uint2 p = pairs[base+i];
    atomicAdd(&hist[p.y & 127], 1);
  }
  __syncthreads();
  if (tid < 128) excl[tid] = hist[tid];
  __syncthreads();
  for (int off=1; off<128; off<<=1){
    int p=0;
    if (tid<128 && tid>=off) p = excl[tid-off];
    __syncthreads();
    if (tid<128) excl[tid] += p;
    __syncthreads();
  }
  if (tid < 128){
    int e = excl[tid] - hist[tid];     // exclusive
    int node = (b<<7) + tid;
    if (node < N) start_[node] = base + e;
    hist[tid] = e;                     // reuse as local cursor
  }
  __syncthreads();
  for (int i=tid;i<cnt;i+=256){
    uint2 p = pairs[base+i];
    int pos = atomicAdd(&hist[p.y & 127], 1);
    csr_src[base + pos] = (int)p.x;
  }
}

// ---------------- K4: gather-side aggregation layer 1 (fp16 payload) ----------------
__global__ __launch_bounds__(256) void k_agg1(const int* __restrict__ start, const int* __restrict__ csr_src,
                      const float* __restrict__ a_s, const float* __restrict__ a_d,
                      const __half* __restrict__ h1h, float* __restrict__ acc1, int N){
  int wid = (blockIdx.x*blockDim.x + threadIdx.x) >> 6;
  int lane = threadIdx.x & 63;
  if (wid >= N) return;
  int d = wid;
  int half = lane >> 5;
  int l32  = lane & 31;
  int head = l32 >> 2;
  float ad = a_d[(size_t)d*8 + head];
  int beg = start[d], end = start[d+1];
  float ax=0.f, ay=0.f, az=0.f, aw=0.f, den=0.f;
  int j = beg + half;
  for (; j + 6 < end; j += 8){
    int s0 = csr_src[j];
    int s1 = csr_src[j+2];
    int s2 = csr_src[j+4];
    int s3 = csr_src[j+6];
    float e0 = __expf(lrelu(a_s[(size_t)s0*8 + head] + ad));
    float e1 = __expf(lrelu(a_s[(size_t)s1*8 + head] + ad));
    float e2 = __expf(lrelu(a_s[(size_t)s2*8 + head] + ad));
    float e3 = __expf(lrelu(a_s[(size_t)s3*8 + head] + ad));
    float2 r0 = *(const float2*)&h1h[(size_t)s0*128 + l32*4];
    float2 r1 = *(const float2*)&h1h[(size_t)s1*128 + l32*4];
    float2 r2 = *(const float2*)&h1h[(size_t)s2*128 + l32*4];
    float2 r3 = *(const float2*)&h1h[(size_t)s3*128 + l32*4];
    float2 f0a = __half22float2(*(__half2*)&r0.x), f0b = __half22float2(*(__half2*)&r0.y);
    float2 f1a = __half22float2(*(__half2*)&r1.x), f1b = __half22float2(*(__half2*)&r1.y);
    float2 f2a = __half22float2(*(__half2*)&r2.x), f2b = __half22float2(*(__half2*)&r2.y);
    float2 f3a = __half22float2(*(__half2*)&r3.x), f3b = __half22float2(*(__half2*)&r3.y);
    ax = fmaf(e0, f0a.x, ax); ay = fmaf(e0, f0a.y, ay); az = fmaf(e0, f0b.x, az); aw = fmaf(e0, f0b.y, aw);
    ax = fmaf(e1, f1a.x, ax); ay = fmaf(e1, f1a.y, ay); az = fmaf(e1, f1b.x, az); aw = fmaf(e1, f1b.y, aw);
    ax = fmaf(e2, f2a.x, ax); ay = fmaf(e2, f2a.y, ay); az = fmaf(e2, f2b.x, az); aw = fmaf(e2, f2b.y, aw);
    ax = fmaf(e3, f3a.x, ax); ay = fmaf(e3, f3a.y, ay); az = fmaf(e3, f3b.x, az); aw = fmaf(e3, f3b.y, aw);
    den += (e0 + e1) + (e2 + e3);
  }
  for (; j < end; j += 2){
    int s0 = csr_src[j];
    float e0 = __expf(lrelu(a_s[(size_t)s0*8 + head] + ad));
    float2 r0 = *(const float2*)&h1h[(size_t)s0*128 + l32*4];
    float2 f0a = __half22float2(*(__half2*)&r0.x), f0b = __half22float2(*(__half2*)&r0.y);
    ax = fmaf(e0, f0a.x, ax); ay = fmaf(e0, f0a.y, ay); az = fmaf(e0, f0b.x, az); aw = fmaf(e0, f0b.y, aw);
    den += e0;
  }
  ax += __shfl_xor(ax, 32);
  ay += __shfl_xor(ay, 32);
  az += __shfl_xor(az, 32);
  aw += __shfl_xor(aw, 32);
  den += __shfl_xor(den, 32);
  float inv = (den > 0.f) ? 1.f/den : 0.f;
  if (half == 0){
    float4 o = make_float4(ax*inv, ay*inv, az*inv, aw*inv);
    *(float4*)&acc1[(size_t)d*128 + l32*4] = o;
  }
}

// ---------------- K5: elu + per-node [128]x[128,32] projection + layer-2 logits ----------------
__global__ __launch_bounds__(256) void k_layer2(const float* __restrict__ acc1, const float* __restrict__ b1,
                        const float* __restrict__ W2, const float* __restrict__ as2w,
                        const float* __restrict__ ad2w,
                        __half* __restrict__ h2ph, float* __restrict__ a_s2,
                        float* __restrict__ a_d2, int N){
  __shared__ float w2s[128][32];
  __shared__ float hs[8][128];
  int tid = threadIdx.x;
  #pragma unroll
  for (int it=0; it<16; it++){
    int idx = it*256 + tid;
    ((float*)w2s)[idx] = W2[idx];
  }
  int sub = tid>>5, ln = tid&31;
  int n = blockIdx.x*8 + sub;
  if (n < N){
    #pragma unroll
    for (int j=0;j<4;j++){
      int k = j*32 + ln;
      float v = acc1[(size_t)n*128+k] + b1[k];
      hs[sub][k] = v > 0.f ? v : (__expf(v) - 1.f);
    }
  }
  __syncthreads();
  if (n >= N) return;
  float o = 0.f;
  #pragma unroll
  for (int k=0;k<128;k++) o = fmaf(hs[sub][k], w2s[k][ln], o);
  h2ph[(size_t)n*32+ln] = __float2half_rn(o);
  float ps = o*as2w[ln], pd = o*ad2w[ln];
  #pragma unroll
  for (int m=16;m;m>>=1){ ps += __shfl_xor(ps,m); pd += __shfl_xor(pd,m); }
  if (ln==0){ a_s2[n]=ps; a_d2[n]=pd; }
}

// ---------------- K6: gather aggregation layer 2 + bias + log_softmax ----------------
__global__ __launch_bounds__(256) void k_agg2(const int* __restrict__ start, const int* __restrict__ csr_src,
                      const float* __restrict__ a_s2, const float* __restrict__ a_d2,
                      const __half* __restrict__ h2ph, const float* __restrict__ b2,
                      float* __restrict__ out, int N){
  int g = (blockIdx.x*blockDim.x + threadIdx.x) >> 5;
  int ln = threadIdx.x & 31;
  if (g >= N) return;
  int d = g;
  float ad = a_d2[d];
  int beg = start[d], end = start[d+1];
  float acc=0.f, den=0.f;
  int j = beg;
  for (; j + 3 < end; j += 4){
    int s0 = csr_src[j];
    int s1 = csr_src[j+1];
    int s2 = csr_src[j+2];
    int s3 = csr_src[j+3];
    float e0 = __expf(lrelu(a_s2[s0] + ad));
    float e1 = __expf(lrelu(a_s2[s1] + ad));
    float e2 = __expf(lrelu(a_s2[s2] + ad));
    float e3 = __expf(lrelu(a_s2[s3] + ad));
    float v0 = __half2float(h2ph[(size_t)s0*32 + ln]);
    float v1 = __half2float(h2ph[(size_t)s1*32 + ln]);
    float v2 = __half2float(h2ph[(size_t)s2*32 + ln]);
    float v3 = __half2float(h2ph[(size_t)s3*32 + ln]);
    acc = fmaf(e0, v0, acc);
    acc = fmaf(e1, v1, acc);
    acc = fmaf(e2, v2, acc);
    acc = fmaf(e3, v3, acc);
    den += (e0 + e1) + (e2 + e3);
  }
  for (; j < end; j++){
    int s0 = csr_src[j];
    float e0 = __expf(lrelu(a_s2[s0] + ad));
    acc = fmaf(e0, __half2float(h2ph[(size_t)s0*32 + ln]), acc);
    den += e0;
  }
  float v = acc/den + b2[ln];
  float mx = v;
  #pragma unroll
  for (int m=16;m;m>>=1) mx = fmaxf(mx, __shfl_xor(mx,m));
  float ex2 = __expf(v-mx);
  float sm = ex2;
  #pragma unroll
  for (int m=16;m;m>>=1) sm += __shfl_xor(sm,m);
  out[(size_t)d*32+ln] = v - mx - __logf(sm);
}

extern "C" void kernel_launch(void* const* d_in, const int* in_sizes, int n_in,
                              void* d_out, int out_size, void* d_ws, size_t ws_size,
                              hipStream_t stream){
  const float* x   = (const float*)d_in[0];
  const int*   ei  = (const int*)d_in[1];
  const float* W1  = (const float*)d_in[3];
  const float* as1 = (const float*)d_in[4];
  const float* ad1 = (const float*)d_in[5];
  const float* b1  = (const float*)d_in[6];
  const float* W2  = (const float*)d_in[7];
  const float* as2 = (const float*)d_in[8];
  const float* ad2 = (const float*)d_in[9];
  const float* b2  = (const float*)d_in[10];

  int N  = in_sizes[0] / 256;
  int E  = in_sizes[2];
  int EE = E + N;
  const int* src = ei;
  const int* dst = ei + E;

  int NB = (N + 127) >> 7;   // 128 nodes per bucket; <=1024 for N<=131072

  // ---- workspace layout: ints first (16B-aligned blocks), then floats, then halfs ----
  int* iw = (int*)d_ws;
  int* bh      = iw;                 iw += 1024*NBLK;          // per-(bucket,block) counts/offsets
  int* btot    = iw;                 iw += 1024;
  int* bbase   = iw;                 iw += 1028;               // NB+1, padded
  int* start_  = iw;                 iw += ((N+1+3)/4)*4;
  int* csr_src = iw;                 iw += ((EE+3)/4)*4;

  float* w = (float*)iw;
  float* a_s1   = w; w += (size_t)N*8;
  float* a_d1   = w; w += (size_t)N*8;
  float* acc1   = w; w += (size_t)N*128;
  float* a_s2   = w; w += (size_t)N;
  float* a_d2   = w; w += (size_t)N;
  _Float16* h1h  = (_Float16*)w; w += (size_t)N*64;   // N*128 halfs
  _Float16* h2ph = (_Float16*)w; w += (size_t)N*16;   // N*32 halfs
  _Float16* Wt   = (_Float16*)w; w += 32768/2;        // 128*256 halfs
  float* out    = (float*)d_out;

  // pairs buffer overlays acc1 (dead until k_agg1, which runs after k_pb)
  uint2* pairs = (uint2*)acc1;

  // W1 -> fp16 transpose
  hipLaunchKernelGGL(k_prepw, dim3(128), dim3(256), 0, stream, W1, Wt);
  // dense transforms
  hipLaunchKernelGGL(k_gemm1, dim3((N+127)/128), dim3(256), 0, stream, x, Wt, h1h, N);
  hipLaunchKernelGGL(k_att1, dim3((N*8+255)/256), dim3(256), 0, stream, (const __half*)h1h, as1, ad1, a_s1, a_d1, N);
  // CSR build: stable bucket partition + per-bucket local sort
  hipLaunchKernelGGL(k_bh,    dim3(NBLK), dim3(256), 0, stream, dst, bh, E, EE, NB);
  hipLaunchKernelGGL(k_scanA, dim3(NB),   dim3(256), 0, stream, bh, btot);
  hipLaunchKernelGGL(k_bscan, dim3(1),    dim3(256), 0, stream, btot, bbase, start_, NB, N, EE);
  hipLaunchKernelGGL(k_bfill, dim3(NBLK), dim3(256), 0, stream, src, dst, bh, bbase, pairs, E, EE, NB);
  hipLaunchKernelGGL(k_pb,    dim3(NB),   dim3(256), 0, stream, bbase, pairs, start_, csr_src, N);
  // layer 1: gather aggregation (no atomics)
  hipLaunchKernelGGL(k_agg1, dim3((N+3)/4), dim3(256), 0, stream, start_, csr_src, a_s1, a_d1, (const __half*)h1h, acc1, N);
  // layer 2: elu + projection + logits
  hipLaunchKernelGGL(k_layer2, dim3((N+7)/8), dim3(256), 0, stream, acc1, b1, W2, as2, ad2, (__half*)h2ph, a_s2, a_d2, N);
  // layer 2 aggregation fused with bias + log_softmax
  hipLaunchKernelGGL(k_agg2, dim3((N+7)/8), dim3(256), 0, stream, start_, csr_src, a_s2, a_d2, (const __half*)h2ph, b2, out, N);
}

// Round 10
// 292.065 us; speedup vs baseline: 8.6567x; 1.1054x over previous
//
#include <hip/hip_runtime.h>
#include <hip/hip_fp16.h>
#include <math.h>

#define NEG_SLOPE 0.2f
#define NBLK 256   // partition blocks; bh layout depends on this

typedef _Float16 half8 __attribute__((ext_vector_type(8)));
typedef _Float16 half4 __attribute__((ext_vector_type(4)));
typedef float f32x4 __attribute__((ext_vector_type(4)));

__device__ __forceinline__ float lrelu(float x){ return x > 0.f ? x : NEG_SLOPE*x; }

// ---------------- prep: Wt[128][256] fp16 = transpose(W1[256,128]) ----------------
__global__ void k_prepw(const float* __restrict__ W, _Float16* __restrict__ Wt){
  int t = blockIdx.x*blockDim.x + threadIdx.x;   // 32768
  int c = t >> 8, k = t & 255;
  Wt[t] = (_Float16)W[k*128 + c];
}

// ---------------- K1: h1h[N,128](fp16) = x[N,256] @ W1 via MFMA f16 ----------------
// 128x128 tile, 4 waves, BK=32. Register-prefetch + LDS double-buffer:
// one barrier per K-iter, next tile's global loads overlap current MFMA.
__global__ __launch_bounds__(256) void k_gemm1(const float* __restrict__ x,
                                               const _Float16* __restrict__ Wt,
                                               _Float16* __restrict__ h1h, int N){
  __shared__ _Float16 aL[2][128*40];
  __shared__ _Float16 bL[2][128*40];
  int tid = threadIdx.x;
  int w = tid >> 6, lane = tid & 63;
  int fq = lane >> 4, fr = lane & 15;
  int row0 = blockIdx.x * 128;
  f32x4 acc[2][8];
  #pragma unroll
  for (int m=0;m<2;m++)
    #pragma unroll
    for (int n=0;n<8;n++) acc[m][n] = (f32x4){0.f,0.f,0.f,0.f};

  int rA = tid>>3, kcA = (tid&7)*4;          // A staging coords
  float4 va[4]; half8 vb[2];

  // ---- load tile 0 ----
  #pragma unroll
  for (int it=0; it<4; it++){
    int gr = row0 + it*32 + rA;
    va[it] = make_float4(0.f,0.f,0.f,0.f);
    if (gr < N) va[it] = *(const float4*)&x[(size_t)gr*256 + kcA];
  }
  #pragma unroll
  for (int it=0; it<2; it++){
    int chunk = it*256 + tid;
    vb[it] = *(const half8*)&Wt[(size_t)(chunk>>2)*256 + (chunk&3)*8];
  }
  // ---- write tile 0 ----
  #pragma unroll
  for (int it=0; it<4; it++){
    half4 hv; hv[0]=(_Float16)va[it].x; hv[1]=(_Float16)va[it].y;
    hv[2]=(_Float16)va[it].z; hv[3]=(_Float16)va[it].w;
    *(half4*)&aL[0][(it*32+rA)*40 + kcA] = hv;
  }
  #pragma unroll
  for (int it=0; it<2; it++){
    int chunk = it*256 + tid;
    *(half8*)&bL[0][(chunk>>2)*40 + (chunk&3)*8] = vb[it];
  }
  __syncthreads();

  int cur = 0;
  for (int ki=0; ki<8; ki++){
    int kk = ki*32;
    if (ki < 7){   // prefetch next tile into registers (loads overlap MFMA below)
      #pragma unroll
      for (int it=0; it<4; it++){
        int gr = row0 + it*32 + rA;
        va[it] = make_float4(0.f,0.f,0.f,0.f);
        if (gr < N) va[it] = *(const float4*)&x[(size_t)gr*256 + kk + 32 + kcA];
      }
      #pragma unroll
      for (int it=0; it<2; it++){
        int chunk = it*256 + tid;
        vb[it] = *(const half8*)&Wt[(size_t)(chunk>>2)*256 + kk + 32 + (chunk&3)*8];
      }
    }
    // compute on buffer cur
    int kb = fq*8;
    half8 afrag[2], bfrag[8];
    #pragma unroll
    for (int m=0;m<2;m++) afrag[m] = *(half8*)&aL[cur][(w*32 + m*16 + fr)*40 + kb];
    #pragma unroll
    for (int n=0;n<8;n++) bfrag[n] = *(half8*)&bL[cur][(n*16 + fr)*40 + kb];
    #pragma unroll
    for (int m=0;m<2;m++)
      #pragma unroll
      for (int n=0;n<8;n++)
        acc[m][n] = __builtin_amdgcn_mfma_f32_16x16x32_f16(afrag[m], bfrag[n], acc[m][n], 0, 0, 0);
    if (ki < 7){
      // write prefetched tile to the other buffer, single barrier
      #pragma unroll
      for (int it=0; it<4; it++){
        half4 hv; hv[0]=(_Float16)va[it].x; hv[1]=(_Float16)va[it].y;
        hv[2]=(_Float16)va[it].z; hv[3]=(_Float16)va[it].w;
        *(half4*)&aL[cur^1][(it*32+rA)*40 + kcA] = hv;
      }
      #pragma unroll
      for (int it=0; it<2; it++){
        int chunk = it*256 + tid;
        *(half8*)&bL[cur^1][(chunk>>2)*40 + (chunk&3)*8] = vb[it];
      }
      __syncthreads();
      cur ^= 1;
    }
  }
  #pragma unroll
  for (int m=0;m<2;m++){
    #pragma unroll
    for (int j=0;j<4;j++){
      int gr = row0 + w*32 + m*16 + fq*4 + j;
      if (gr < N){
        #pragma unroll
        for (int n=0;n<8;n++)
          h1h[(size_t)gr*128 + n*16 + fr] = (_Float16)acc[m][n][j];
      }
    }
  }
}

// ---------------- K2: per-(node,head) attention logits layer 1 ----------------
__global__ void k_att1(const __half* __restrict__ h1h, const float* __restrict__ as_w,
                       const float* __restrict__ ad_w,
                       float* __restrict__ a_s, float* __restrict__ a_d, int N){
  int t = blockIdx.x*blockDim.x + threadIdx.x;
  if (t >= N*8) return;
  int n = t >> 3, h = t & 7;
  const __half* hp = &h1h[(size_t)n*128 + h*16];
  const float* wsp = &as_w[h*16];
  const float* wdp = &ad_w[h*16];
  float s=0.f, d=0.f;
  #pragma unroll
  for (int j=0;j<8;j++){
    __half2 hv = *(const __half2*)&hp[j*2];
    float2 f = __half22float2(hv);
    s = fmaf(f.x, wsp[j*2],   s); d = fmaf(f.x, wdp[j*2],   d);
    s = fmaf(f.y, wsp[j*2+1], s); d = fmaf(f.y, wdp[j*2+1], d);
  }
  a_s[t] = s; a_d[t] = d;
}

// ---------------- CSR: per-block bucket histogram ----------------
__global__ __launch_bounds__(256) void k_bh(const int* __restrict__ dst, int* __restrict__ bh,
                                            int E, int EE, int NB){
  __shared__ int h[1024];
  int tid = threadIdx.x, blk = blockIdx.x;
  for (int i=tid;i<1024;i+=256) h[i]=0;
  __syncthreads();
  int chunk = (EE + NBLK - 1)/NBLK;
  int e0 = blk*chunk, e1 = min(e0+chunk, EE);
  for (int e=e0+tid; e<e1; e+=256){
    int d = (e<E)? dst[e] : (e-E);
    atomicAdd(&h[d>>7], 1);
  }
  __syncthreads();
  for (int i=tid;i<NB;i+=256) bh[i*NBLK + blk] = h[i];
}

// ---------------- CSR: per-bucket scan over blocks -> relative offsets + totals ----------------
__global__ __launch_bounds__(256) void k_scanA(int* __restrict__ bh, int* __restrict__ btot){
  __shared__ int t[256];
  int b = blockIdx.x, tid = threadIdx.x;
  int v = bh[b*NBLK + tid];
  t[tid] = v;
  __syncthreads();
  for (int off=1; off<256; off<<=1){
    int p = (tid>=off)? t[tid-off] : 0;
    __syncthreads();
    t[tid] += p;
    __syncthreads();
  }
  bh[b*NBLK + tid] = t[tid] - v;     // exclusive within bucket
  if (tid==255) btot[b] = t[255];
}

// ---------------- CSR: scan of bucket totals -> bucket bases ----------------
__global__ __launch_bounds__(256) void k_bscan(const int* __restrict__ btot, int* __restrict__ bbase,
                                               int* __restrict__ start_, int NB, int N, int EE){
  __shared__ int t[256];
  int tid = threadIdx.x;
  int i0 = tid*4;
  int a0 = (i0+0<NB)? btot[i0+0] : 0;
  int a1 = (i0+1<NB)? btot[i0+1] : 0;
  int a2 = (i0+2<NB)? btot[i0+2] : 0;
  int a3 = (i0+3<NB)? btot[i0+3] : 0;
  int s = a0+a1+a2+a3;
  t[tid] = s;
  __syncthreads();
  for (int off=1; off<256; off<<=1){
    int p = (tid>=off)? t[tid-off] : 0;
    __syncthreads();
    t[tid] += p;
    __syncthreads();
  }
  int excl = t[tid] - s;
  int e0=excl, e1=e0+a0, e2=e1+a1, e3=e2+a2;
  if (i0+0<NB) bbase[i0+0]=e0;
  if (i0+1<NB) bbase[i0+1]=e1;
  if (i0+2<NB) bbase[i0+2]=e2;
  if (i0+3<NB) bbase[i0+3]=e3;
  if (tid==0){ bbase[NB] = EE; start_[N] = EE; }
}

// ---------------- CSR: stable partition fill (LDS cursors, contiguous per block) ----------------
__global__ __launch_bounds__(256) void k_bfill(const int* __restrict__ src, const int* __restrict__ dst,
                       const int* __restrict__ bh, const int* __restrict__ bbase,
                       uint2* __restrict__ pairs, int E, int EE, int NB){
  __shared__ int cur[1024];
  int tid = threadIdx.x, blk = blockIdx.x;
  for (int i=tid;i<NB;i+=256) cur[i] = bbase[i] + bh[i*NBLK + blk];
  __syncthreads();
  int chunk = (EE + NBLK - 1)/NBLK;
  int e0 = blk*chunk, e1 = min(e0+chunk, EE);
  for (int e=e0+tid; e<e1; e+=256){
    int s,d;
    if (e<E){ s=src[e]; d=dst[e]; } else { s=e-E; d=s; }
    int p = atomicAdd(&cur[d>>7], 1);
    pairs[p] = make_uint2((unsigned)s,(unsigned)d);
  }
}

// ---------------- CSR: per-bucket local sort -> start_[] + csr_src ----------------
__global__ __launch_bounds__(256) void k_pb(const int* __restrict__ bbase, const uint2* __restrict__ pairs,
                    int* __restrict__ start_, int* __restrict__ csr_src, int N){
  __shared__ int hist[128];
  __shared__ int excl[128];
  int b = blockIdx.x;
  int tid = threadIdx.x;
  int base = bbase[b], cnt = bbase[b+1] - base;
  if (tid<128) hist[tid]=0;
  __syncthreads();
  for (int i=tid;i<cnt;i+=256){
    uint2 p = pairs[base+i];
    atomicAdd(&hist[p.y & 127], 1);
  }
  __syncthreads();
  if (tid < 128) excl[tid] = hist[tid];
  __syncthreads();
  for (int off=1; off<128; off<<=1){
    int p=0;
    if (tid<128 && tid>=off) p = excl[tid-off];
    __syncthreads();
    if (tid<128) excl[tid] += p;
    __syncthreads();
  }
  if (tid < 128){
    int e = excl[tid] - hist[tid];     // exclusive
    int node = (b<<7) + tid;
    if (node < N) start_[node] = base + e;
    hist[tid] = e;                     // reuse as local cursor
  }
  __syncthreads();
  for (int i=tid;i<cnt;i+=256){
    uint2 p = pairs[base+i];
    int pos = atomicAdd(&hist[p.y & 127], 1);
    csr_src[base + pos] = (int)p.x;
  }
}

// ---------------- K4: gather-side aggregation layer 1 (fp16 payload) ----------------
__global__ __launch_bounds__(256) void k_agg1(const int* __restrict__ start, const int* __restrict__ csr_src,
                      const float* __restrict__ a_s, const float* __restrict__ a_d,
                      const __half* __restrict__ h1h, float* __restrict__ acc1, int N){
  int wid = (blockIdx.x*blockDim.x + threadIdx.x) >> 6;
  int lane = threadIdx.x & 63;
  if (wid >= N) return;
  int d = wid;
  int half = lane >> 5;
  int l32  = lane & 31;
  int head = l32 >> 2;
  float ad = a_d[(size_t)d*8 + head];
  int beg = start[d], end = start[d+1];
  float ax=0.f, ay=0.f, az=0.f, aw=0.f, den=0.f;
  int j = beg + half;
  for (; j + 6 < end; j += 8){
    int s0 = csr_src[j];
    int s1 = csr_src[j+2];
    int s2 = csr_src[j+4];
    int s3 = csr_src[j+6];
    float e0 = __expf(lrelu(a_s[(size_t)s0*8 + head] + ad));
    float e1 = __expf(lrelu(a_s[(size_t)s1*8 + head] + ad));
    float e2 = __expf(lrelu(a_s[(size_t)s2*8 + head] + ad));
    float e3 = __expf(lrelu(a_s[(size_t)s3*8 + head] + ad));
    float2 r0 = *(const float2*)&h1h[(size_t)s0*128 + l32*4];
    float2 r1 = *(const float2*)&h1h[(size_t)s1*128 + l32*4];
    float2 r2 = *(const float2*)&h1h[(size_t)s2*128 + l32*4];
    float2 r3 = *(const float2*)&h1h[(size_t)s3*128 + l32*4];
    float2 f0a = __half22float2(*(__half2*)&r0.x), f0b = __half22float2(*(__half2*)&r0.y);
    float2 f1a = __half22float2(*(__half2*)&r1.x), f1b = __half22float2(*(__half2*)&r1.y);
    float2 f2a = __half22float2(*(__half2*)&r2.x), f2b = __half22float2(*(__half2*)&r2.y);
    float2 f3a = __half22float2(*(__half2*)&r3.x), f3b = __half22float2(*(__half2*)&r3.y);
    ax = fmaf(e0, f0a.x, ax); ay = fmaf(e0, f0a.y, ay); az = fmaf(e0, f0b.x, az); aw = fmaf(e0, f0b.y, aw);
    ax = fmaf(e1, f1a.x, ax); ay = fmaf(e1, f1a.y, ay); az = fmaf(e1, f1b.x, az); aw = fmaf(e1, f1b.y, aw);
    ax = fmaf(e2, f2a.x, ax); ay = fmaf(e2, f2a.y, ay); az = fmaf(e2, f2b.x, az); aw = fmaf(e2, f2b.y, aw);
    ax = fmaf(e3, f3a.x, ax); ay = fmaf(e3, f3a.y, ay); az = fmaf(e3, f3b.x, az); aw = fmaf(e3, f3b.y, aw);
    den += (e0 + e1) + (e2 + e3);
  }
  for (; j < end; j += 2){
    int s0 = csr_src[j];
    float e0 = __expf(lrelu(a_s[(size_t)s0*8 + head] + ad));
    float2 r0 = *(const float2*)&h1h[(size_t)s0*128 + l32*4];
    float2 f0a = __half22float2(*(__half2*)&r0.x), f0b = __half22float2(*(__half2*)&r0.y);
    ax = fmaf(e0, f0a.x, ax); ay = fmaf(e0, f0a.y, ay); az = fmaf(e0, f0b.x, az); aw = fmaf(e0, f0b.y, aw);
    den += e0;
  }
  ax += __shfl_xor(ax, 32);
  ay += __shfl_xor(ay, 32);
  az += __shfl_xor(az, 32);
  aw += __shfl_xor(aw, 32);
  den += __shfl_xor(den, 32);
  float inv = (den > 0.f) ? 1.f/den : 0.f;
  if (half == 0){
    float4 o = make_float4(ax*inv, ay*inv, az*inv, aw*inv);
    *(float4*)&acc1[(size_t)d*128 + l32*4] = o;
  }
}

// ---------------- K5: elu + per-node [128]x[128,32] projection + layer-2 logits ----------------
__global__ __launch_bounds__(256) void k_layer2(const float* __restrict__ acc1, const float* __restrict__ b1,
                        const float* __restrict__ W2, const float* __restrict__ as2w,
                        const float* __restrict__ ad2w,
                        __half* __restrict__ h2ph, float* __restrict__ a_s2,
                        float* __restrict__ a_d2, int N){
  __shared__ float w2s[128][32];
  __shared__ float hs[8][128];
  int tid = threadIdx.x;
  #pragma unroll
  for (int it=0; it<16; it++){
    int idx = it*256 + tid;
    ((float*)w2s)[idx] = W2[idx];
  }
  int sub = tid>>5, ln = tid&31;
  int n = blockIdx.x*8 + sub;
  if (n < N){
    #pragma unroll
    for (int j=0;j<4;j++){
      int k = j*32 + ln;
      float v = acc1[(size_t)n*128+k] + b1[k];
      hs[sub][k] = v > 0.f ? v : (__expf(v) - 1.f);
    }
  }
  __syncthreads();
  if (n >= N) return;
  float o = 0.f;
  #pragma unroll
  for (int k=0;k<128;k++) o = fmaf(hs[sub][k], w2s[k][ln], o);
  h2ph[(size_t)n*32+ln] = __float2half_rn(o);
  float ps = o*as2w[ln], pd = o*ad2w[ln];
  #pragma unroll
  for (int m=16;m;m>>=1){ ps += __shfl_xor(ps,m); pd += __shfl_xor(pd,m); }
  if (ln==0){ a_s2[n]=ps; a_d2[n]=pd; }
}

// ---------------- K6: gather aggregation layer 2 + bias + log_softmax ----------------
// Half-wave per dst; within it, two 16-lane groups each own an edge chain
// (4x unroll => 8 chains/dst). lane16 covers classes [2*lane16, 2*lane16+1]
// via half2 (4B loads instead of 2B).
__global__ __launch_bounds__(256) void k_agg2(const int* __restrict__ start, const int* __restrict__ csr_src,
                      const float* __restrict__ a_s2, const float* __restrict__ a_d2,
                      const __half* __restrict__ h2ph, const float* __restrict__ b2,
                      float* __restrict__ out, int N){
  int g = (blockIdx.x*blockDim.x + threadIdx.x) >> 5;
  int ln = threadIdx.x & 31;
  if (g >= N) return;
  int d = g;
  int grp = ln >> 4;          // 0/1: edge-chain group
  int l16 = ln & 15;          // class pair index
  float ad = a_d2[d];
  int beg = start[d], end = start[d+1];
  float accx=0.f, accy=0.f, den=0.f;
  int j = beg + grp;
  for (; j + 6 < end; j += 8){
    int s0 = csr_src[j];
    int s1 = csr_src[j+2];
    int s2 = csr_src[j+4];
    int s3 = csr_src[j+6];
    float e0 = __expf(lrelu(a_s2[s0] + ad));
    float e1 = __expf(lrelu(a_s2[s1] + ad));
    float e2 = __expf(lrelu(a_s2[s2] + ad));
    float e3 = __expf(lrelu(a_s2[s3] + ad));
    float2 v0 = __half22float2(*(const __half2*)&h2ph[(size_t)s0*32 + l16*2]);
    float2 v1 = __half22float2(*(const __half2*)&h2ph[(size_t)s1*32 + l16*2]);
    float2 v2 = __half22float2(*(const __half2*)&h2ph[(size_t)s2*32 + l16*2]);
    float2 v3 = __half22float2(*(const __half2*)&h2ph[(size_t)s3*32 + l16*2]);
    accx = fmaf(e0, v0.x, accx); accy = fmaf(e0, v0.y, accy);
    accx = fmaf(e1, v1.x, accx); accy = fmaf(e1, v1.y, accy);
    accx = fmaf(e2, v2.x, accx); accy = fmaf(e2, v2.y, accy);
    accx = fmaf(e3, v3.x, accx); accy = fmaf(e3, v3.y, accy);
    den += (e0 + e1) + (e2 + e3);
  }
  for (; j < end; j += 2){
    int s0 = csr_src[j];
    float e0 = __expf(lrelu(a_s2[s0] + ad));
    float2 v0 = __half22float2(*(const __half2*)&h2ph[(size_t)s0*32 + l16*2]);
    accx = fmaf(e0, v0.x, accx); accy = fmaf(e0, v0.y, accy);
    den += e0;
  }
  // combine the two groups
  accx += __shfl_xor(accx, 16);
  accy += __shfl_xor(accy, 16);
  den  += __shfl_xor(den, 16);
  float2 bb = *(const float2*)&b2[l16*2];
  float vx = accx/den + bb.x;
  float vy = accy/den + bb.y;
  // log_softmax over 32 classes held as 2/lane across 16 lanes
  float mx = fmaxf(vx, vy);
  #pragma unroll
  for (int m=8;m;m>>=1) mx = fmaxf(mx, __shfl_xor(mx, m));
  float sm = __expf(vx-mx) + __expf(vy-mx);
  #pragma unroll
  for (int m=8;m;m>>=1) sm += __shfl_xor(sm, m);
  float lg = mx + __logf(sm);
  if (grp == 0){
    float2 o = make_float2(vx - lg, vy - lg);
    *(float2*)&out[(size_t)d*32 + l16*2] = o;
  }
}

extern "C" void kernel_launch(void* const* d_in, const int* in_sizes, int n_in,
                              void* d_out, int out_size, void* d_ws, size_t ws_size,
                              hipStream_t stream){
  const float* x   = (const float*)d_in[0];
  const int*   ei  = (const int*)d_in[1];
  const float* W1  = (const float*)d_in[3];
  const float* as1 = (const float*)d_in[4];
  const float* ad1 = (const float*)d_in[5];
  const float* b1  = (const float*)d_in[6];
  const float* W2  = (const float*)d_in[7];
  const float* as2 = (const float*)d_in[8];
  const float* ad2 = (const float*)d_in[9];
  const float* b2  = (const float*)d_in[10];

  int N  = in_sizes[0] / 256;
  int E  = in_sizes[2];
  int EE = E + N;
  const int* src = ei;
  const int* dst = ei + E;

  int NB = (N + 127) >> 7;   // 128 nodes per bucket; <=1024 for N<=131072

  // ---- workspace layout: ints first (16B-aligned blocks), then floats, then halfs ----
  int* iw = (int*)d_ws;
  int* bh      = iw;                 iw += 1024*NBLK;          // per-(bucket,block) counts/offsets
  int* btot    = iw;                 iw += 1024;
  int* bbase   = iw;                 iw += 1028;               // NB+1, padded
  int* start_  = iw;                 iw += ((N+1+3)/4)*4;
  int* csr_src = iw;                 iw += ((EE+3)/4)*4;

  float* w = (float*)iw;
  float* a_s1   = w; w += (size_t)N*8;
  float* a_d1   = w; w += (size_t)N*8;
  float* acc1   = w; w += (size_t)N*128;
  float* a_s2   = w; w += (size_t)N;
  float* a_d2   = w; w += (size_t)N;
  _Float16* h1h  = (_Float16*)w; w += (size_t)N*64;   // N*128 halfs
  _Float16* h2ph = (_Float16*)w; w += (size_t)N*16;   // N*32 halfs
  _Float16* Wt   = (_Float16*)w; w += 32768/2;        // 128*256 halfs
  float* out    = (float*)d_out;

  // pairs buffer overlays acc1 (dead until k_agg1, which runs after k_pb)
  uint2* pairs = (uint2*)acc1;

  // W1 -> fp16 transpose
  hipLaunchKernelGGL(k_prepw, dim3(128), dim3(256), 0, stream, W1, Wt);
  // dense transforms
  hipLaunchKernelGGL(k_gemm1, dim3((N+127)/128), dim3(256), 0, stream, x, Wt, h1h, N);
  hipLaunchKernelGGL(k_att1, dim3((N*8+255)/256), dim3(256), 0, stream, (const __half*)h1h, as1, ad1, a_s1, a_d1, N);
  // CSR build: stable bucket partition + per-bucket local sort
  hipLaunchKernelGGL(k_bh,    dim3(NBLK), dim3(256), 0, stream, dst, bh, E, EE, NB);
  hipLaunchKernelGGL(k_scanA, dim3(NB),   dim3(256), 0, stream, bh, btot);
  hipLaunchKernelGGL(k_bscan, dim3(1),    dim3(256), 0, stream, btot, bbase, start_, NB, N, EE);
  hipLaunchKernelGGL(k_bfill, dim3(NBLK), dim3(256), 0, stream, src, dst, bh, bbase, pairs, E, EE, NB);
  hipLaunchKernelGGL(k_pb,    dim3(NB),   dim3(256), 0, stream, bbase, pairs, start_, csr_src, N);
  // layer 1: gather aggregation (no atomics)
  hipLaunchKernelGGL(k_agg1, dim3((N+3)/4), dim3(256), 0, stream, start_, csr_src, a_s1, a_d1, (const __half*)h1h, acc1, N);
  // layer 2: elu + projection + logits
  hipLaunchKernelGGL(k_layer2, dim3((N+7)/8), dim3(256), 0, stream, acc1, b1, W2, as2, ad2, (__half*)h2ph, a_s2, a_d2, N);
  // layer 2 aggregation fused with bias + log_softmax
  hipLaunchKernelGGL(k_agg2, dim3((N+7)/8), dim3(256), 0, stream, start_, csr_src, a_s2, a_d2, (const __half*)h2ph, b2, out, N);
}

// Round 11
// 259.818 us; speedup vs baseline: 9.7311x; 1.1241x over previous
//
#include <hip/hip_runtime.h>
#include <hip/hip_fp16.h>
#include <math.h>

#define NEG_SLOPE 0.2f
#define NBLK 256   // partition blocks; bh layout depends on this

typedef _Float16 half8 __attribute__((ext_vector_type(8)));
typedef _Float16 half4 __attribute__((ext_vector_type(4)));
typedef float f32x4 __attribute__((ext_vector_type(4)));
typedef float f32x2 __attribute__((ext_vector_type(2)));

__device__ __forceinline__ float lrelu(float x){ return x > 0.f ? x : NEG_SLOPE*x; }

// ---------------- prep: Wt[128][256] fp16 = transpose(W1[256,128]) ----------------
__global__ void k_prepw(const float* __restrict__ W, _Float16* __restrict__ Wt){
  int t = blockIdx.x*blockDim.x + threadIdx.x;   // 32768
  int c = t >> 8, k = t & 255;
  Wt[t] = (_Float16)W[k*128 + c];
}

// ---------------- K1: h1h[N,128](fp16) = x[N,256] @ W1 via MFMA f16 ----------------
// 128x128 tile, 4 waves, BK=32, register-prefetch + LDS double-buffer.
__global__ __launch_bounds__(256) void k_gemm1(const float* __restrict__ x,
                                               const _Float16* __restrict__ Wt,
                                               _Float16* __restrict__ h1h, int N){
  __shared__ _Float16 aL[2][128*40];
  __shared__ _Float16 bL[2][128*40];
  int tid = threadIdx.x;
  int w = tid >> 6, lane = tid & 63;
  int fq = lane >> 4, fr = lane & 15;
  int row0 = blockIdx.x * 128;
  f32x4 acc[2][8];
  #pragma unroll
  for (int m=0;m<2;m++)
    #pragma unroll
    for (int n=0;n<8;n++) acc[m][n] = (f32x4){0.f,0.f,0.f,0.f};

  int rA = tid>>3, kcA = (tid&7)*4;
  float4 va[4]; half8 vb[2];

  #pragma unroll
  for (int it=0; it<4; it++){
    int gr = row0 + it*32 + rA;
    va[it] = make_float4(0.f,0.f,0.f,0.f);
    if (gr < N) va[it] = *(const float4*)&x[(size_t)gr*256 + kcA];
  }
  #pragma unroll
  for (int it=0; it<2; it++){
    int chunk = it*256 + tid;
    vb[it] = *(const half8*)&Wt[(size_t)(chunk>>2)*256 + (chunk&3)*8];
  }
  #pragma unroll
  for (int it=0; it<4; it++){
    half4 hv; hv[0]=(_Float16)va[it].x; hv[1]=(_Float16)va[it].y;
    hv[2]=(_Float16)va[it].z; hv[3]=(_Float16)va[it].w;
    *(half4*)&aL[0][(it*32+rA)*40 + kcA] = hv;
  }
  #pragma unroll
  for (int it=0; it<2; it++){
    int chunk = it*256 + tid;
    *(half8*)&bL[0][(chunk>>2)*40 + (chunk&3)*8] = vb[it];
  }
  __syncthreads();

  int cur = 0;
  for (int ki=0; ki<8; ki++){
    int kk = ki*32;
    if (ki < 7){
      #pragma unroll
      for (int it=0; it<4; it++){
        int gr = row0 + it*32 + rA;
        va[it] = make_float4(0.f,0.f,0.f,0.f);
        if (gr < N) va[it] = *(const float4*)&x[(size_t)gr*256 + kk + 32 + kcA];
      }
      #pragma unroll
      for (int it=0; it<2; it++){
        int chunk = it*256 + tid;
        vb[it] = *(const half8*)&Wt[(size_t)(chunk>>2)*256 + kk + 32 + (chunk&3)*8];
      }
    }
    int kb = fq*8;
    half8 afrag[2], bfrag[8];
    #pragma unroll
    for (int m=0;m<2;m++) afrag[m] = *(half8*)&aL[cur][(w*32 + m*16 + fr)*40 + kb];
    #pragma unroll
    for (int n=0;n<8;n++) bfrag[n] = *(half8*)&bL[cur][(n*16 + fr)*40 + kb];
    #pragma unroll
    for (int m=0;m<2;m++)
      #pragma unroll
      for (int n=0;n<8;n++)
        acc[m][n] = __builtin_amdgcn_mfma_f32_16x16x32_f16(afrag[m], bfrag[n], acc[m][n], 0, 0, 0);
    if (ki < 7){
      #pragma unroll
      for (int it=0; it<4; it++){
        half4 hv; hv[0]=(_Float16)va[it].x; hv[1]=(_Float16)va[it].y;
        hv[2]=(_Float16)va[it].z; hv[3]=(_Float16)va[it].w;
        *(half4*)&aL[cur^1][(it*32+rA)*40 + kcA] = hv;
      }
      #pragma unroll
      for (int it=0; it<2; it++){
        int chunk = it*256 + tid;
        *(half8*)&bL[cur^1][(chunk>>2)*40 + (chunk&3)*8] = vb[it];
      }
      __syncthreads();
      cur ^= 1;
    }
  }
  #pragma unroll
  for (int m=0;m<2;m++){
    #pragma unroll
    for (int j=0;j<4;j++){
      int gr = row0 + w*32 + m*16 + fq*4 + j;
      if (gr < N){
        #pragma unroll
        for (int n=0;n<8;n++)
          h1h[(size_t)gr*128 + n*16 + fr] = (_Float16)acc[m][n][j];
      }
    }
  }
}

// ---------------- K2: fp16 h -> fp8 payload + fused attention logits ----------------
// thread t: row = t>>4, chans (t&15)*8..+7. Packs 8 fp8 bytes (2 u32) and
// computes per-head a_s/a_d partials (2 threads per head, shfl_xor(1) combine).
__global__ void k_cvt8(const _Float16* __restrict__ h1h,
                       const float* __restrict__ as_w, const float* __restrict__ ad_w,
                       unsigned* __restrict__ h1p, float* __restrict__ a_s,
                       float* __restrict__ a_d, int N){
  int t = blockIdx.x*blockDim.x + threadIdx.x;
  if (t >= N*16) return;
  int row = t >> 4, c8 = t & 15;
  half8 hv = *(const half8*)&h1h[(size_t)row*128 + c8*8];
  float f[8];
  #pragma unroll
  for (int j=0;j<8;j++) f[j] = (float)hv[j];
  int w0 = 0, w1 = 0;
  w0 = __builtin_amdgcn_cvt_pk_fp8_f32(f[0], f[1], w0, false);
  w0 = __builtin_amdgcn_cvt_pk_fp8_f32(f[2], f[3], w0, true);
  w1 = __builtin_amdgcn_cvt_pk_fp8_f32(f[4], f[5], w1, false);
  w1 = __builtin_amdgcn_cvt_pk_fp8_f32(f[6], f[7], w1, true);
  *(uint2*)&h1p[(size_t)row*32 + c8*2] = make_uint2((unsigned)w0,(unsigned)w1);
  int head = c8 >> 1;
  const float* wsp = &as_w[head*16 + (c8&1)*8];
  const float* wdp = &ad_w[head*16 + (c8&1)*8];
  float s=0.f, d=0.f;
  #pragma unroll
  for (int j=0;j<8;j++){ s = fmaf(f[j], wsp[j], s); d = fmaf(f[j], wdp[j], d); }
  s += __shfl_xor(s, 1);
  d += __shfl_xor(d, 1);
  if ((c8&1)==0){ a_s[(size_t)row*8+head]=s; a_d[(size_t)row*8+head]=d; }
}

// ---------------- CSR: per-block bucket histogram ----------------
__global__ __launch_bounds__(256) void k_bh(const int* __restrict__ dst, int* __restrict__ bh,
                                            int E, int EE, int NB){
  __shared__ int h[1024];
  int tid = threadIdx.x, blk = blockIdx.x;
  for (int i=tid;i<1024;i+=256) h[i]=0;
  __syncthreads();
  int chunk = (EE + NBLK - 1)/NBLK;
  int e0 = blk*chunk, e1 = min(e0+chunk, EE);
  for (int e=e0+tid; e<e1; e+=256){
    int d = (e<E)? dst[e] : (e-E);
    atomicAdd(&h[d>>7], 1);
  }
  __syncthreads();
  for (int i=tid;i<NB;i+=256) bh[i*NBLK + blk] = h[i];
}

// ---------------- CSR: per-bucket scan over blocks ----------------
__global__ __launch_bounds__(256) void k_scanA(int* __restrict__ bh, int* __restrict__ btot){
  __shared__ int t[256];
  int b = blockIdx.x, tid = threadIdx.x;
  int v = bh[b*NBLK + tid];
  t[tid] = v;
  __syncthreads();
  for (int off=1; off<256; off<<=1){
    int p = (tid>=off)? t[tid-off] : 0;
    __syncthreads();
    t[tid] += p;
    __syncthreads();
  }
  bh[b*NBLK + tid] = t[tid] - v;
  if (tid==255) btot[b] = t[255];
}

// ---------------- CSR: scan of bucket totals -> bucket bases ----------------
__global__ __launch_bounds__(256) void k_bscan(const int* __restrict__ btot, int* __restrict__ bbase,
                                               int* __restrict__ start_, int NB, int N, int EE){
  __shared__ int t[256];
  int tid = threadIdx.x;
  int i0 = tid*4;
  int a0 = (i0+0<NB)? btot[i0+0] : 0;
  int a1 = (i0+1<NB)? btot[i0+1] : 0;
  int a2 = (i0+2<NB)? btot[i0+2] : 0;
  int a3 = (i0+3<NB)? btot[i0+3] : 0;
  int s = a0+a1+a2+a3;
  t[tid] = s;
  __syncthreads();
  for (int off=1; off<256; off<<=1){
    int p = (tid>=off)? t[tid-off] : 0;
    __syncthreads();
    t[tid] += p;
    __syncthreads();
  }
  int excl = t[tid] - s;
  int e0=excl, e1=e0+a0, e2=e1+a1, e3=e2+a2;
  if (i0+0<NB) bbase[i0+0]=e0;
  if (i0+1<NB) bbase[i0+1]=e1;
  if (i0+2<NB) bbase[i0+2]=e2;
  if (i0+3<NB) bbase[i0+3]=e3;
  if (tid==0){ bbase[NB] = EE; start_[N] = EE; }
}

// ---------------- CSR: stable partition fill (packed u32 pairs) ----------------
__global__ __launch_bounds__(256) void k_bfill(const int* __restrict__ src, const int* __restrict__ dst,
                       const int* __restrict__ bh, const int* __restrict__ bbase,
                       unsigned* __restrict__ pairs, int E, int EE, int NB){
  __shared__ int cur[1024];
  int tid = threadIdx.x, blk = blockIdx.x;
  for (int i=tid;i<NB;i+=256) cur[i] = bbase[i] + bh[i*NBLK + blk];
  __syncthreads();
  int chunk = (EE + NBLK - 1)/NBLK;
  int e0 = blk*chunk, e1 = min(e0+chunk, EE);
  for (int e=e0+tid; e<e1; e+=256){
    int s,d;
    if (e<E){ s=src[e]; d=dst[e]; } else { s=e-E; d=s; }
    int p = atomicAdd(&cur[d>>7], 1);
    pairs[p] = ((unsigned)s << 7) | (unsigned)(d & 127);
  }
}

// ---------------- CSR: per-bucket local sort -> start_[] + csr_src ----------------
__global__ __launch_bounds__(256) void k_pb(const int* __restrict__ bbase, const unsigned* __restrict__ pairs,
                    int* __restrict__ start_, int* __restrict__ csr_src, int N){
  __shared__ int hist[128];
  __shared__ int excl[128];
  int b = blockIdx.x;
  int tid = threadIdx.x;
  int base = bbase[b], cnt = bbase[b+1] - base;
  if (tid<128) hist[tid]=0;
  __syncthreads();
  for (int i=tid;i<cnt;i+=256){
    unsigned p = pairs[base+i];
    atomicAdd(&hist[p & 127], 1);
  }
  __syncthreads();
  if (tid < 128) excl[tid] = hist[tid];
  __syncthreads();
  for (int off=1; off<128; off<<=1){
    int p=0;
    if (tid<128 && tid>=off) p = excl[tid-off];
    __syncthreads();
    if (tid<128) excl[tid] += p;
    __syncthreads();
  }
  if (tid < 128){
    int e = excl[tid] - hist[tid];
    int node = (b<<7) + tid;
    if (node < N) start_[node] = base + e;
    hist[tid] = e;
  }
  __syncthreads();
  for (int i=tid;i<cnt;i+=256){
    unsigned p = pairs[base+i];
    int pos = atomicAdd(&hist[p & 127], 1);
    csr_src[base + pos] = (int)(p >> 7);
  }
}

// ---------------- K4: gather-side aggregation layer 1 (fp8 payload, fp16 out) ----------------
// Wave per dst node; two half-waves each own an edge chain (4x unroll = 8 chains).
// lane l32 covers channels [4*l32..4*l32+3] via one u32 of 4 fp8 (head = l32>>2).
__global__ __launch_bounds__(256) void k_agg1(const int* __restrict__ start, const int* __restrict__ csr_src,
                      const float* __restrict__ a_s, const float* __restrict__ a_d,
                      const unsigned* __restrict__ h1p, _Float16* __restrict__ acc1h, int N){
  int wid = (blockIdx.x*blockDim.x + threadIdx.x) >> 6;
  int lane = threadIdx.x & 63;
  if (wid >= N) return;
  int d = wid;
  int half = lane >> 5;
  int l32  = lane & 31;
  int head = l32 >> 2;
  float ad = a_d[(size_t)d*8 + head];
  int beg = start[d], end = start[d+1];
  float ax=0.f, ay=0.f, az=0.f, aw=0.f, den=0.f;
  int j = beg + half;
  for (; j + 6 < end; j += 8){
    int s0 = csr_src[j];
    int s1 = csr_src[j+2];
    int s2 = csr_src[j+4];
    int s3 = csr_src[j+6];
    float e0 = __expf(lrelu(a_s[(size_t)s0*8 + head] + ad));
    float e1 = __expf(lrelu(a_s[(size_t)s1*8 + head] + ad));
    float e2 = __expf(lrelu(a_s[(size_t)s2*8 + head] + ad));
    float e3 = __expf(lrelu(a_s[(size_t)s3*8 + head] + ad));
    unsigned u0 = h1p[(size_t)s0*32 + l32];
    unsigned u1 = h1p[(size_t)s1*32 + l32];
    unsigned u2 = h1p[(size_t)s2*32 + l32];
    unsigned u3 = h1p[(size_t)s3*32 + l32];
    f32x2 l0 = __builtin_amdgcn_cvt_pk_f32_fp8((int)u0, false), h0 = __builtin_amdgcn_cvt_pk_f32_fp8((int)u0, true);
    f32x2 l1 = __builtin_amdgcn_cvt_pk_f32_fp8((int)u1, false), h1 = __builtin_amdgcn_cvt_pk_f32_fp8((int)u1, true);
    f32x2 l2 = __builtin_amdgcn_cvt_pk_f32_fp8((int)u2, false), h2 = __builtin_amdgcn_cvt_pk_f32_fp8((int)u2, true);
    f32x2 l3 = __builtin_amdgcn_cvt_pk_f32_fp8((int)u3, false), h3 = __builtin_amdgcn_cvt_pk_f32_fp8((int)u3, true);
    ax = fmaf(e0, l0.x, ax); ay = fmaf(e0, l0.y, ay); az = fmaf(e0, h0.x, az); aw = fmaf(e0, h0.y, aw);
    ax = fmaf(e1, l1.x, ax); ay = fmaf(e1, l1.y, ay); az = fmaf(e1, h1.x, az); aw = fmaf(e1, h1.y, aw);
    ax = fmaf(e2, l2.x, ax); ay = fmaf(e2, l2.y, ay); az = fmaf(e2, h2.x, az); aw = fmaf(e2, h2.y, aw);
    ax = fmaf(e3, l3.x, ax); ay = fmaf(e3, l3.y, ay); az = fmaf(e3, h3.x, az); aw = fmaf(e3, h3.y, aw);
    den += (e0 + e1) + (e2 + e3);
  }
  for (; j < end; j += 2){
    int s0 = csr_src[j];
    float e0 = __expf(lrelu(a_s[(size_t)s0*8 + head] + ad));
    unsigned u0 = h1p[(size_t)s0*32 + l32];
    f32x2 l0 = __builtin_amdgcn_cvt_pk_f32_fp8((int)u0, false), h0 = __builtin_amdgcn_cvt_pk_f32_fp8((int)u0, true);
    ax = fmaf(e0, l0.x, ax); ay = fmaf(e0, l0.y, ay); az = fmaf(e0, h0.x, az); aw = fmaf(e0, h0.y, aw);
    den += e0;
  }
  ax += __shfl_xor(ax, 32);
  ay += __shfl_xor(ay, 32);
  az += __shfl_xor(az, 32);
  aw += __shfl_xor(aw, 32);
  den += __shfl_xor(den, 32);
  float inv = (den > 0.f) ? 1.f/den : 0.f;
  if (half == 0){
    half4 o;
    o[0]=(_Float16)(ax*inv); o[1]=(_Float16)(ay*inv);
    o[2]=(_Float16)(az*inv); o[3]=(_Float16)(aw*inv);
    *(half4*)&acc1h[(size_t)d*128 + l32*4] = o;
  }
}

// ---------------- K5: elu + per-node [128]x[128,32] projection + layer-2 logits ----------------
__global__ __launch_bounds__(256) void k_layer2(const _Float16* __restrict__ acc1h, const float* __restrict__ b1,
                        const float* __restrict__ W2, const float* __restrict__ as2w,
                        const float* __restrict__ ad2w,
                        __half* __restrict__ h2ph, float* __restrict__ a_s2,
                        float* __restrict__ a_d2, int N){
  __shared__ float w2s[128][32];
  __shared__ float hs[8][128];
  int tid = threadIdx.x;
  #pragma unroll
  for (int it=0; it<16; it++){
    int idx = it*256 + tid;
    ((float*)w2s)[idx] = W2[idx];
  }
  int sub = tid>>5, ln = tid&31;
  int n = blockIdx.x*8 + sub;
  if (n < N){
    half4 hv = *(const half4*)&acc1h[(size_t)n*128 + ln*4];
    float4 bb = *(const float4*)&b1[ln*4];
    float v0 = (float)hv[0] + bb.x;
    float v1 = (float)hv[1] + bb.y;
    float v2 = (float)hv[2] + bb.z;
    float v3 = (float)hv[3] + bb.w;
    hs[sub][ln*4+0] = v0 > 0.f ? v0 : (__expf(v0) - 1.f);
    hs[sub][ln*4+1] = v1 > 0.f ? v1 : (__expf(v1) - 1.f);
    hs[sub][ln*4+2] = v2 > 0.f ? v2 : (__expf(v2) - 1.f);
    hs[sub][ln*4+3] = v3 > 0.f ? v3 : (__expf(v3) - 1.f);
  }
  __syncthreads();
  if (n >= N) return;
  float o = 0.f;
  #pragma unroll
  for (int k=0;k<128;k++) o = fmaf(hs[sub][k], w2s[k][ln], o);
  h2ph[(size_t)n*32+ln] = __float2half_rn(o);
  float ps = o*as2w[ln], pd = o*ad2w[ln];
  #pragma unroll
  for (int m=16;m;m>>=1){ ps += __shfl_xor(ps,m); pd += __shfl_xor(pd,m); }
  if (ln==0){ a_s2[n]=ps; a_d2[n]=pd; }
}

// ---------------- K6: gather aggregation layer 2 + bias + log_softmax ----------------
__global__ __launch_bounds__(256) void k_agg2(const int* __restrict__ start, const int* __restrict__ csr_src,
                      const float* __restrict__ a_s2, const float* __restrict__ a_d2,
                      const __half* __restrict__ h2ph, const float* __restrict__ b2,
                      float* __restrict__ out, int N){
  int g = (blockIdx.x*blockDim.x + threadIdx.x) >> 5;
  int ln = threadIdx.x & 31;
  if (g >= N) return;
  int d = g;
  int grp = ln >> 4;
  int l16 = ln & 15;
  float ad = a_d2[d];
  int beg = start[d], end = start[d+1];
  float accx=0.f, accy=0.f, den=0.f;
  int j = beg + grp;
  for (; j + 6 < end; j += 8){
    int s0 = csr_src[j];
    int s1 = csr_src[j+2];
    int s2 = csr_src[j+4];
    int s3 = csr_src[j+6];
    float e0 = __expf(lrelu(a_s2[s0] + ad));
    float e1 = __expf(lrelu(a_s2[s1] + ad));
    float e2 = __expf(lrelu(a_s2[s2] + ad));
    float e3 = __expf(lrelu(a_s2[s3] + ad));
    float2 v0 = __half22float2(*(const __half2*)&h2ph[(size_t)s0*32 + l16*2]);
    float2 v1 = __half22float2(*(const __half2*)&h2ph[(size_t)s1*32 + l16*2]);
    float2 v2 = __half22float2(*(const __half2*)&h2ph[(size_t)s2*32 + l16*2]);
    float2 v3 = __half22float2(*(const __half2*)&h2ph[(size_t)s3*32 + l16*2]);
    accx = fmaf(e0, v0.x, accx); accy = fmaf(e0, v0.y, accy);
    accx = fmaf(e1, v1.x, accx); accy = fmaf(e1, v1.y, accy);
    accx = fmaf(e2, v2.x, accx); accy = fmaf(e2, v2.y, accy);
    accx = fmaf(e3, v3.x, accx); accy = fmaf(e3, v3.y, accy);
    den += (e0 + e1) + (e2 + e3);
  }
  for (; j < end; j += 2){
    int s0 = csr_src[j];
    float e0 = __expf(lrelu(a_s2[s0] + ad));
    float2 v0 = __half22float2(*(const __half2*)&h2ph[(size_t)s0*32 + l16*2]);
    accx = fmaf(e0, v0.x, accx); accy = fmaf(e0, v0.y, accy);
    den += e0;
  }
  accx += __shfl_xor(accx, 16);
  accy += __shfl_xor(accy, 16);
  den  += __shfl_xor(den, 16);
  float2 bb = *(const float2*)&b2[l16*2];
  float vx = accx/den + bb.x;
  float vy = accy/den + bb.y;
  float mx = fmaxf(vx, vy);
  #pragma unroll
  for (int m=8;m;m>>=1) mx = fmaxf(mx, __shfl_xor(mx, m));
  float sm = __expf(vx-mx) + __expf(vy-mx);
  #pragma unroll
  for (int m=8;m;m>>=1) sm += __shfl_xor(sm, m);
  float lg = mx + __logf(sm);
  if (grp == 0){
    float2 o = make_float2(vx - lg, vy - lg);
    *(float2*)&out[(size_t)d*32 + l16*2] = o;
  }
}

extern "C" void kernel_launch(void* const* d_in, const int* in_sizes, int n_in,
                              void* d_out, int out_size, void* d_ws, size_t ws_size,
                              hipStream_t stream){
  const float* x   = (const float*)d_in[0];
  const int*   ei  = (const int*)d_in[1];
  const float* W1  = (const float*)d_in[3];
  const float* as1 = (const float*)d_in[4];
  const float* ad1 = (const float*)d_in[5];
  const float* b1  = (const float*)d_in[6];
  const float* W2  = (const float*)d_in[7];
  const float* as2 = (const float*)d_in[8];
  const float* ad2 = (const float*)d_in[9];
  const float* b2  = (const float*)d_in[10];

  int N  = in_sizes[0] / 256;
  int E  = in_sizes[2];
  int EE = E + N;
  const int* src = ei;
  const int* dst = ei + E;

  int NB = (N + 127) >> 7;   // 128 nodes per bucket

  // ---- workspace layout ----
  int* iw = (int*)d_ws;
  int* bh      = iw;                 iw += 1024*NBLK;
  int* btot    = iw;                 iw += 1024;
  int* bbase   = iw;                 iw += 1028;
  int* start_  = iw;                 iw += ((N+1+3)/4)*4;
  int* csr_src = iw;                 iw += ((EE+3)/4)*4;

  float* w = (float*)iw;
  float* a_s1   = w; w += (size_t)N*8;
  float* a_d1   = w; w += (size_t)N*8;
  float* a_s2   = w; w += (size_t)N;
  float* a_d2   = w; w += (size_t)N;
  _Float16* acc1h = (_Float16*)w; w += (size_t)N*64;   // N*128 halfs
  _Float16* h1h  = (_Float16*)w; w += (size_t)N*64;    // N*128 halfs
  _Float16* h2ph = (_Float16*)w; w += (size_t)N*16;    // N*32 halfs
  _Float16* Wt   = (_Float16*)w; w += 32768/2;
  unsigned* h1p  = (unsigned*)w; w += (size_t)N*16;    // N*32 u32 (fp8 payload)
  float* out    = (float*)d_out;

  // pairs (u32, EE) overlays acc1h (dead until k_agg1)
  unsigned* pairs = (unsigned*)acc1h;

  hipLaunchKernelGGL(k_prepw, dim3(128), dim3(256), 0, stream, W1, Wt);
  hipLaunchKernelGGL(k_gemm1, dim3((N+127)/128), dim3(256), 0, stream, x, Wt, h1h, N);
  hipLaunchKernelGGL(k_cvt8, dim3((N*16+255)/256), dim3(256), 0, stream, h1h, as1, ad1, h1p, a_s1, a_d1, N);
  // CSR build
  hipLaunchKernelGGL(k_bh,    dim3(NBLK), dim3(256), 0, stream, dst, bh, E, EE, NB);
  hipLaunchKernelGGL(k_scanA, dim3(NB),   dim3(256), 0, stream, bh, btot);
  hipLaunchKernelGGL(k_bscan, dim3(1),    dim3(256), 0, stream, btot, bbase, start_, NB, N, EE);
  hipLaunchKernelGGL(k_bfill, dim3(NBLK), dim3(256), 0, stream, src, dst, bh, bbase, pairs, E, EE, NB);
  hipLaunchKernelGGL(k_pb,    dim3(NB),   dim3(256), 0, stream, bbase, pairs, start_, csr_src, N);
  // layer 1 aggregation
  hipLaunchKernelGGL(k_agg1, dim3((N+3)/4), dim3(256), 0, stream, start_, csr_src, a_s1, a_d1, h1p, acc1h, N);
  // layer 2
  hipLaunchKernelGGL(k_layer2, dim3((N+7)/8), dim3(256), 0, stream, acc1h, b1, W2, as2, ad2, (__half*)h2ph, a_s2, a_d2, N);
  hipLaunchKernelGGL(k_agg2, dim3((N+7)/8), dim3(256), 0, stream, start_, csr_src, a_s2, a_d2, (const __half*)h2ph, b2, out, N);
}

// Round 13
// 251.181 us; speedup vs baseline: 10.0657x; 1.0344x over previous
//
#include <hip/hip_runtime.h>
#include <hip/hip_fp16.h>
#include <math.h>

#define NEG_SLOPE 0.2f
#define NBLK 256   // partition blocks; bh layout depends on this

typedef _Float16 half8 __attribute__((ext_vector_type(8)));
typedef _Float16 half4 __attribute__((ext_vector_type(4)));
typedef float f32x4 __attribute__((ext_vector_type(4)));
typedef float f32x2 __attribute__((ext_vector_type(2)));

__device__ __forceinline__ float lrelu(float x){ return x > 0.f ? x : NEG_SLOPE*x; }

// ---------------- prep: Wt[p][256] fp16 = W1[k][pi(p)], pi(p)=(p&15)*8+(p>>4) ----------------
// Column permutation makes each MFMA lane's 8 outputs 8 CONSECUTIVE channels.
__global__ void k_prepw(const float* __restrict__ W, _Float16* __restrict__ Wt){
  int t = blockIdx.x*blockDim.x + threadIdx.x;   // 32768
  int p = t >> 8, k = t & 255;
  int c = ((p & 15) << 3) | (p >> 4);
  Wt[t] = (_Float16)W[k*128 + c];
}

// ---------------- K1: fused GEMM + fp8 pack + attention logits ----------------
// 128x128 tile, 4 waves, BK=32, reg-prefetch + LDS dbuf. Epilogue: lane (fq,fr)
// holds channels fr*8..fr*8+7 of rows w*32+m*16+fq*4+j -> packs 2 u32 fp8,
// computes per-head a_s/a_d partial (head=fr>>1), shfl_xor(1) combine.
__global__ __launch_bounds__(256) void k_gemm1(const float* __restrict__ x,
                                               const _Float16* __restrict__ Wt,
                                               const float* __restrict__ as_w,
                                               const float* __restrict__ ad_w,
                                               unsigned* __restrict__ h1p,
                                               float* __restrict__ a_s,
                                               float* __restrict__ a_d, int N){
  __shared__ _Float16 aL[2][128*40];
  __shared__ _Float16 bL[2][128*40];
  int tid = threadIdx.x;
  int w = tid >> 6, lane = tid & 63;
  int fq = lane >> 4, fr = lane & 15;
  int row0 = blockIdx.x * 128;
  f32x4 acc[2][8];
  #pragma unroll
  for (int m=0;m<2;m++)
    #pragma unroll
    for (int n=0;n<8;n++) acc[m][n] = (f32x4){0.f,0.f,0.f,0.f};

  int rA = tid>>3, kcA = (tid&7)*4;
  float4 va[4]; half8 vb[2];

  #pragma unroll
  for (int it=0; it<4; it++){
    int gr = row0 + it*32 + rA;
    va[it] = make_float4(0.f,0.f,0.f,0.f);
    if (gr < N) va[it] = *(const float4*)&x[(size_t)gr*256 + kcA];
  }
  #pragma unroll
  for (int it=0; it<2; it++){
    int chunk = it*256 + tid;
    vb[it] = *(const half8*)&Wt[(size_t)(chunk>>2)*256 + (chunk&3)*8];
  }
  #pragma unroll
  for (int it=0; it<4; it++){
    half4 hv; hv[0]=(_Float16)va[it].x; hv[1]=(_Float16)va[it].y;
    hv[2]=(_Float16)va[it].z; hv[3]=(_Float16)va[it].w;
    *(half4*)&aL[0][(it*32+rA)*40 + kcA] = hv;
  }
  #pragma unroll
  for (int it=0; it<2; it++){
    int chunk = it*256 + tid;
    *(half8*)&bL[0][(chunk>>2)*40 + (chunk&3)*8] = vb[it];
  }
  __syncthreads();

  int cur = 0;
  for (int ki=0; ki<8; ki++){
    int kk = ki*32;
    if (ki < 7){
      #pragma unroll
      for (int it=0; it<4; it++){
        int gr = row0 + it*32 + rA;
        va[it] = make_float4(0.f,0.f,0.f,0.f);
        if (gr < N) va[it] = *(const float4*)&x[(size_t)gr*256 + kk + 32 + kcA];
      }
      #pragma unroll
      for (int it=0; it<2; it++){
        int chunk = it*256 + tid;
        vb[it] = *(const half8*)&Wt[(size_t)(chunk>>2)*256 + kk + 32 + (chunk&3)*8];
      }
    }
    int kb = fq*8;
    half8 afrag[2], bfrag[8];
    #pragma unroll
    for (int m=0;m<2;m++) afrag[m] = *(half8*)&aL[cur][(w*32 + m*16 + fr)*40 + kb];
    #pragma unroll
    for (int n=0;n<8;n++) bfrag[n] = *(half8*)&bL[cur][(n*16 + fr)*40 + kb];
    #pragma unroll
    for (int m=0;m<2;m++)
      #pragma unroll
      for (int n=0;n<8;n++)
        acc[m][n] = __builtin_amdgcn_mfma_f32_16x16x32_f16(afrag[m], bfrag[n], acc[m][n], 0, 0, 0);
    if (ki < 7){
      #pragma unroll
      for (int it=0; it<4; it++){
        half4 hv; hv[0]=(_Float16)va[it].x; hv[1]=(_Float16)va[it].y;
        hv[2]=(_Float16)va[it].z; hv[3]=(_Float16)va[it].w;
        *(half4*)&aL[cur^1][(it*32+rA)*40 + kcA] = hv;
      }
      #pragma unroll
      for (int it=0; it<2; it++){
        int chunk = it*256 + tid;
        *(half8*)&bL[cur^1][(chunk>>2)*40 + (chunk&3)*8] = vb[it];
      }
      __syncthreads();
      cur ^= 1;
    }
  }
  // fused epilogue
  int head = fr >> 1;
  const float* wsp = &as_w[head*16 + (fr&1)*8];
  const float* wdp = &ad_w[head*16 + (fr&1)*8];
  #pragma unroll
  for (int m=0;m<2;m++){
    #pragma unroll
    for (int j=0;j<4;j++){
      int gr = row0 + w*32 + m*16 + fq*4 + j;   // same for all fr lanes
      if (gr < N){
        float f[8];
        #pragma unroll
        for (int n=0;n<8;n++) f[n] = acc[m][n][j];
        int w0 = 0, w1 = 0;
        w0 = __builtin_amdgcn_cvt_pk_fp8_f32(f[0], f[1], w0, false);
        w0 = __builtin_amdgcn_cvt_pk_fp8_f32(f[2], f[3], w0, true);
        w1 = __builtin_amdgcn_cvt_pk_fp8_f32(f[4], f[5], w1, false);
        w1 = __builtin_amdgcn_cvt_pk_fp8_f32(f[6], f[7], w1, true);
        *(uint2*)&h1p[(size_t)gr*32 + fr*2] = make_uint2((unsigned)w0,(unsigned)w1);
        float s=0.f, dd=0.f;
        #pragma unroll
        for (int n=0;n<8;n++){ s = fmaf(f[n], wsp[n], s); dd = fmaf(f[n], wdp[n], dd); }
        s  += __shfl_xor(s, 1);
        dd += __shfl_xor(dd, 1);
        if (!(fr & 1)){ a_s[(size_t)gr*8+head] = s; a_d[(size_t)gr*8+head] = dd; }
      }
    }
  }
}

// ---------------- CSR: per-block bucket histogram ----------------
__global__ __launch_bounds__(256) void k_bh(const int* __restrict__ dst, int* __restrict__ bh,
                                            int E, int EE, int NB){
  __shared__ int h[1024];
  int tid = threadIdx.x, blk = blockIdx.x;
  for (int i=tid;i<1024;i+=256) h[i]=0;
  __syncthreads();
  int chunk = (EE + NBLK - 1)/NBLK;
  int e0 = blk*chunk, e1 = min(e0+chunk, EE);
  for (int e=e0+tid; e<e1; e+=256){
    int d = (e<E)? dst[e] : (e-E);
    atomicAdd(&h[d>>7], 1);
  }
  __syncthreads();
  for (int i=tid;i<NB;i+=256) bh[i*NBLK + blk] = h[i];
}

// ---------------- CSR: per-bucket scan over blocks ----------------
__global__ __launch_bounds__(256) void k_scanA(int* __restrict__ bh, int* __restrict__ btot){
  __shared__ int t[256];
  int b = blockIdx.x, tid = threadIdx.x;
  int v = bh[b*NBLK + tid];
  t[tid] = v;
  __syncthreads();
  for (int off=1; off<256; off<<=1){
    int p = (tid>=off)? t[tid-off] : 0;
    __syncthreads();
    t[tid] += p;
    __syncthreads();
  }
  bh[b*NBLK + tid] = t[tid] - v;
  if (tid==255) btot[b] = t[255];
}

// ---------------- CSR: scan of bucket totals -> bucket bases ----------------
__global__ __launch_bounds__(256) void k_bscan(const int* __restrict__ btot, int* __restrict__ bbase,
                                               int* __restrict__ start_, int NB, int N, int EE){
  __shared__ int t[256];
  int tid = threadIdx.x;
  int i0 = tid*4;
  int a0 = (i0+0<NB)? btot[i0+0] : 0;
  int a1 = (i0+1<NB)? btot[i0+1] : 0;
  int a2 = (i0+2<NB)? btot[i0+2] : 0;
  int a3 = (i0+3<NB)? btot[i0+3] : 0;
  int s = a0+a1+a2+a3;
  t[tid] = s;
  __syncthreads();
  for (int off=1; off<256; off<<=1){
    int p = (tid>=off)? t[tid-off] : 0;
    __syncthreads();
    t[tid] += p;
    __syncthreads();
  }
  int excl = t[tid] - s;
  int e0=excl, e1=e0+a0, e2=e1+a1, e3=e2+a2;
  if (i0+0<NB) bbase[i0+0]=e0;
  if (i0+1<NB) bbase[i0+1]=e1;
  if (i0+2<NB) bbase[i0+2]=e2;
  if (i0+3<NB) bbase[i0+3]=e3;
  if (tid==0){ bbase[NB] = EE; start_[N] = EE; }
}

// ---------------- CSR: stable partition fill (packed u32 pairs) ----------------
__global__ __launch_bounds__(256) void k_bfill(const int* __restrict__ src, const int* __restrict__ dst,
                       const int* __restrict__ bh, const int* __restrict__ bbase,
                       unsigned* __restrict__ pairs, int E, int EE, int NB){
  __shared__ int cur[1024];
  int tid = threadIdx.x, blk = blockIdx.x;
  for (int i=tid;i<NB;i+=256) cur[i] = bbase[i] + bh[i*NBLK + blk];
  __syncthreads();
  int chunk = (EE + NBLK - 1)/NBLK;
  int e0 = blk*chunk, e1 = min(e0+chunk, EE);
  for (int e=e0+tid; e<e1; e+=256){
    int s,d;
    if (e<E){ s=src[e]; d=dst[e]; } else { s=e-E; d=s; }
    int p = atomicAdd(&cur[d>>7], 1);
    pairs[p] = ((unsigned)s << 7) | (unsigned)(d & 127);
  }
}

// ---------------- CSR: per-bucket local sort -> start_[] + csr_src ----------------
__global__ __launch_bounds__(256) void k_pb(const int* __restrict__ bbase, const unsigned* __restrict__ pairs,
                    int* __restrict__ start_, int* __restrict__ csr_src, int N){
  __shared__ int hist[128];
  __shared__ int excl[128];
  int b = blockIdx.x;
  int tid = threadIdx.x;
  int base = bbase[b], cnt = bbase[b+1] - base;
  if (tid<128) hist[tid]=0;
  __syncthreads();
  for (int i=tid;i<cnt;i+=256){
    unsigned p = pairs[base+i];
    atomicAdd(&hist[p & 127], 1);
  }
  __syncthreads();
  if (tid < 128) excl[tid] = hist[tid];
  __syncthreads();
  for (int off=1; off<128; off<<=1){
    int p=0;
    if (tid<128 && tid>=off) p = excl[tid-off];
    __syncthreads();
    if (tid<128) excl[tid] += p;
    __syncthreads();
  }
  if (tid < 128){
    int e = excl[tid] - hist[tid];
    int node = (b<<7) + tid;
    if (node < N) start_[node] = base + e;
    hist[tid] = e;
  }
  __syncthreads();
  for (int i=tid;i<cnt;i+=256){
    unsigned p = pairs[base+i];
    int pos = atomicAdd(&hist[p & 127], 1);
    csr_src[base + pos] = (int)(p >> 7);
  }
}

// ---------------- K4: gather aggregation layer 1 (fp8, 16 lanes/edge) ----------------
// Wave per dst; 4 groups of 16 lanes each own an edge chain (stride 4, 2x unroll
// = 8 chains). Lane fr covers channels fr*8..fr*8+7 (one uint2); head = fr>>1.
__global__ __launch_bounds__(256) void k_agg1(const int* __restrict__ start, const int* __restrict__ csr_src,
                      const float* __restrict__ a_s, const float* __restrict__ a_d,
                      const unsigned* __restrict__ h1p, _Float16* __restrict__ acc1h, int N){
  int wid = (blockIdx.x*blockDim.x + threadIdx.x) >> 6;
  int lane = threadIdx.x & 63;
  if (wid >= N) return;
  int d = wid;
  int grp = lane >> 4;
  int fr  = lane & 15;
  int head = fr >> 1;
  float ad = a_d[(size_t)d*8 + head];
  int beg = start[d], end = start[d+1];
  float a0=0.f,a1=0.f,a2=0.f,a3=0.f,a4=0.f,a5=0.f,a6=0.f,a7=0.f,den=0.f;
  int j = beg + grp;
  for (; j + 4 < end; j += 8){
    int s0 = csr_src[j];
    int s1 = csr_src[j+4];
    float e0 = __expf(lrelu(a_s[(size_t)s0*8 + head] + ad));
    float e1 = __expf(lrelu(a_s[(size_t)s1*8 + head] + ad));
    uint2 u0 = *(const uint2*)&h1p[(size_t)s0*32 + fr*2];
    uint2 u1 = *(const uint2*)&h1p[(size_t)s1*32 + fr*2];
    f32x2 p0 = __builtin_amdgcn_cvt_pk_f32_fp8((int)u0.x, false), p1 = __builtin_amdgcn_cvt_pk_f32_fp8((int)u0.x, true);
    f32x2 p2 = __builtin_amdgcn_cvt_pk_f32_fp8((int)u0.y, false), p3 = __builtin_amdgcn_cvt_pk_f32_fp8((int)u0.y, true);
    f32x2 q0 = __builtin_amdgcn_cvt_pk_f32_fp8((int)u1.x, false), q1 = __builtin_amdgcn_cvt_pk_f32_fp8((int)u1.x, true);
    f32x2 q2 = __builtin_amdgcn_cvt_pk_f32_fp8((int)u1.y, false), q3 = __builtin_amdgcn_cvt_pk_f32_fp8((int)u1.y, true);
    a0 = fmaf(e0, p0.x, a0); a1 = fmaf(e0, p0.y, a1); a2 = fmaf(e0, p1.x, a2); a3 = fmaf(e0, p1.y, a3);
    a4 = fmaf(e0, p2.x, a4); a5 = fmaf(e0, p2.y, a5); a6 = fmaf(e0, p3.x, a6); a7 = fmaf(e0, p3.y, a7);
    a0 = fmaf(e1, q0.x, a0); a1 = fmaf(e1, q0.y, a1); a2 = fmaf(e1, q1.x, a2); a3 = fmaf(e1, q1.y, a3);
    a4 = fmaf(e1, q2.x, a4); a5 = fmaf(e1, q2.y, a5); a6 = fmaf(e1, q3.x, a6); a7 = fmaf(e1, q3.y, a7);
    den += e0 + e1;
  }
  if (j < end){
    int s0 = csr_src[j];
    float e0 = __expf(lrelu(a_s[(size_t)s0*8 + head] + ad));
    uint2 u0 = *(const uint2*)&h1p[(size_t)s0*32 + fr*2];
    f32x2 p0 = __builtin_amdgcn_cvt_pk_f32_fp8((int)u0.x, false), p1 = __builtin_amdgcn_cvt_pk_f32_fp8((int)u0.x, true);
    f32x2 p2 = __builtin_amdgcn_cvt_pk_f32_fp8((int)u0.y, false), p3 = __builtin_amdgcn_cvt_pk_f32_fp8((int)u0.y, true);
    a0 = fmaf(e0, p0.x, a0); a1 = fmaf(e0, p0.y, a1); a2 = fmaf(e0, p1.x, a2); a3 = fmaf(e0, p1.y, a3);
    a4 = fmaf(e0, p2.x, a4); a5 = fmaf(e0, p2.y, a5); a6 = fmaf(e0, p3.x, a6); a7 = fmaf(e0, p3.y, a7);
    den += e0;
  }
  // combine the 4 groups
  a0 += __shfl_xor(a0,16); a1 += __shfl_xor(a1,16); a2 += __shfl_xor(a2,16); a3 += __shfl_xor(a3,16);
  a4 += __shfl_xor(a4,16); a5 += __shfl_xor(a5,16); a6 += __shfl_xor(a6,16); a7 += __shfl_xor(a7,16);
  den += __shfl_xor(den,16);
  a0 += __shfl_xor(a0,32); a1 += __shfl_xor(a1,32); a2 += __shfl_xor(a2,32); a3 += __shfl_xor(a3,32);
  a4 += __shfl_xor(a4,32); a5 += __shfl_xor(a5,32); a6 += __shfl_xor(a6,32); a7 += __shfl_xor(a7,32);
  den += __shfl_xor(den,32);
  float inv = (den > 0.f) ? 1.f/den : 0.f;
  if (grp == 0){
    half8 o;
    o[0]=(_Float16)(a0*inv); o[1]=(_Float16)(a1*inv); o[2]=(_Float16)(a2*inv); o[3]=(_Float16)(a3*inv);
    o[4]=(_Float16)(a4*inv); o[5]=(_Float16)(a5*inv); o[6]=(_Float16)(a6*inv); o[7]=(_Float16)(a7*inv);
    *(half8*)&acc1h[(size_t)d*128 + fr*8] = o;
  }
}

// ---------------- K5: elu + per-node [128]x[128,32] projection + layer-2 logits ----------------
__global__ __launch_bounds__(256) void k_layer2(const _Float16* __restrict__ acc1h, const float* __restrict__ b1,
                        const float* __restrict__ W2, const float* __restrict__ as2w,
                        const float* __restrict__ ad2w,
                        __half* __restrict__ h2ph, float* __restrict__ a_s2,
                        float* __restrict__ a_d2, int N){
  __shared__ float w2s[128][32];
  __shared__ float hs[8][128];
  int tid = threadIdx.x;
  #pragma unroll
  for (int it=0; it<16; it++){
    int idx = it*256 + tid;
    ((float*)w2s)[idx] = W2[idx];
  }
  int sub = tid>>5, ln = tid&31;
  int n = blockIdx.x*8 + sub;
  if (n < N){
    half4 hv = *(const half4*)&acc1h[(size_t)n*128 + ln*4];
    float4 bb = *(const float4*)&b1[ln*4];
    float v0 = (float)hv[0] + bb.x;
    float v1 = (float)hv[1] + bb.y;
    float v2 = (float)hv[2] + bb.z;
    float v3 = (float)hv[3] + bb.w;
    hs[sub][ln*4+0] = v0 > 0.f ? v0 : (__expf(v0) - 1.f);
    hs[sub][ln*4+1] = v1 > 0.f ? v1 : (__expf(v1) - 1.f);
    hs[sub][ln*4+2] = v2 > 0.f ? v2 : (__expf(v2) - 1.f);
    hs[sub][ln*4+3] = v3 > 0.f ? v3 : (__expf(v3) - 1.f);
  }
  __syncthreads();
  if (n >= N) return;
  float o = 0.f;
  #pragma unroll
  for (int k=0;k<128;k++) o = fmaf(hs[sub][k], w2s[k][ln], o);
  h2ph[(size_t)n*32+ln] = __float2half_rn(o);
  float ps = o*as2w[ln], pd = o*ad2w[ln];
  #pragma unroll
  for (int m=16;m;m>>=1){ ps += __shfl_xor(ps,m); pd += __shfl_xor(pd,m); }
  if (ln==0){ a_s2[n]=ps; a_d2[n]=pd; }
}

// ---------------- K6: gather aggregation layer 2 + bias + log_softmax ----------------
__global__ __launch_bounds__(256) void k_agg2(const int* __restrict__ start, const int* __restrict__ csr_src,
                      const float* __restrict__ a_s2, const float* __restrict__ a_d2,
                      const __half* __restrict__ h2ph, const float* __restrict__ b2,
                      float* __restrict__ out, int N){
  int g = (blockIdx.x*blockDim.x + threadIdx.x) >> 5;
  int ln = threadIdx.x & 31;
  if (g >= N) return;
  int d = g;
  int grp = ln >> 4;
  int l16 = ln & 15;
  float ad = a_d2[d];
  int beg = start[d], end = start[d+1];
  float accx=0.f, accy=0.f, den=0.f;
  int j = beg + grp;
  for (; j + 6 < end; j += 8){
    int s0 = csr_src[j];
    int s1 = csr_src[j+2];
    int s2 = csr_src[j+4];
    int s3 = csr_src[j+6];
    float e0 = __expf(lrelu(a_s2[s0] + ad));
    float e1 = __expf(lrelu(a_s2[s1] + ad));
    float e2 = __expf(lrelu(a_s2[s2] + ad));
    float e3 = __expf(lrelu(a_s2[s3] + ad));
    float2 v0 = __half22float2(*(const __half2*)&h2ph[(size_t)s0*32 + l16*2]);
    float2 v1 = __half22float2(*(const __half2*)&h2ph[(size_t)s1*32 + l16*2]);
    float2 v2 = __half22float2(*(const __half2*)&h2ph[(size_t)s2*32 + l16*2]);
    float2 v3 = __half22float2(*(const __half2*)&h2ph[(size_t)s3*32 + l16*2]);
    accx = fmaf(e0, v0.x, accx); accy = fmaf(e0, v0.y, accy);
    accx = fmaf(e1, v1.x, accx); accy = fmaf(e1, v1.y, accy);
    accx = fmaf(e2, v2.x, accx); accy = fmaf(e2, v2.y, accy);
    accx = fmaf(e3, v3.x, accx); accy = fmaf(e3, v3.y, accy);
    den += (e0 + e1) + (e2 + e3);
  }
  for (; j < end; j += 2){
    int s0 = csr_src[j];
    float e0 = __expf(lrelu(a_s2[s0] + ad));
    float2 v0 = __half22float2(*(const __half2*)&h2ph[(size_t)s0*32 + l16*2]);
    accx = fmaf(e0, v0.x, accx); accy = fmaf(e0, v0.y, accy);
    den += e0;
  }
  accx += __shfl_xor(accx, 16);
  accy += __shfl_xor(accy, 16);
  den  += __shfl_xor(den, 16);
  float2 bb = *(const float2*)&b2[l16*2];
  float vx = accx/den + bb.x;
  float vy = accy/den + bb.y;
  float mx = fmaxf(vx, vy);
  #pragma unroll
  for (int m=8;m;m>>=1) mx = fmaxf(mx, __shfl_xor(mx, m));
  float sm = __expf(vx-mx) + __expf(vy-mx);
  #pragma unroll
  for (int m=8;m;m>>=1) sm += __shfl_xor(sm, m);
  float lg = mx + __logf(sm);
  if (grp == 0){
    float2 o = make_float2(vx - lg, vy - lg);
    *(float2*)&out[(size_t)d*32 + l16*2] = o;
  }
}

extern "C" void kernel_launch(void* const* d_in, const int* in_sizes, int n_in,
                              void* d_out, int out_size, void* d_ws, size_t ws_size,
                              hipStream_t stream){
  const float* x   = (const float*)d_in[0];
  const int*   ei  = (const int*)d_in[1];
  const float* W1  = (const float*)d_in[3];
  const float* as1 = (const float*)d_in[4];
  const float* ad1 = (const float*)d_in[5];
  const float* b1  = (const float*)d_in[6];
  const float* W2  = (const float*)d_in[7];
  const float* as2 = (const float*)d_in[8];
  const float* ad2 = (const float*)d_in[9];
  const float* b2  = (const float*)d_in[10];

  int N  = in_sizes[0] / 256;
  int E  = in_sizes[2];
  int EE = E + N;
  const int* src = ei;
  const int* dst = ei + E;

  int NB = (N + 127) >> 7;   // 128 nodes per bucket

  // ---- workspace layout ----
  int* iw = (int*)d_ws;
  int* bh      = iw;                 iw += 1024*NBLK;
  int* btot    = iw;                 iw += 1024;
  int* bbase   = iw;                 iw += 1028;
  int* start_  = iw;                 iw += ((N+1+3)/4)*4;
  int* csr_src = iw;                 iw += ((EE+3)/4)*4;

  float* w = (float*)iw;
  float* a_s1   = w; w += (size_t)N*8;
  float* a_d1   = w; w += (size_t)N*8;
  float* a_s2   = w; w += (size_t)N;
  float* a_d2   = w; w += (size_t)N;
  _Float16* acc1h = (_Float16*)w; w += (size_t)N*64;   // N*128 halfs
  _Float16* h2ph = (_Float16*)w; w += (size_t)N*16;    // N*32 halfs
  _Float16* Wt   = (_Float16*)w; w += 32768/2;
  unsigned* h1p  = (unsigned*)w; w += (size_t)N*16;    // N*32 u32 (fp8 payload)
  float* out    = (float*)d_out;

  // pairs (u32, EE) overlays acc1h (dead until k_agg1)
  unsigned* pairs = (unsigned*)acc1h;

  hipLaunchKernelGGL(k_prepw, dim3(128), dim3(256), 0, stream, W1, Wt);
  hipLaunchKernelGGL(k_gemm1, dim3((N+127)/128), dim3(256), 0, stream, x, Wt, as1, ad1, h1p, a_s1, a_d1, N);
  // CSR build
  hipLaunchKernelGGL(k_bh,    dim3(NBLK), dim3(256), 0, stream, dst, bh, E, EE, NB);
  hipLaunchKernelGGL(k_scanA, dim3(NB),   dim3(256), 0, stream, bh, btot);
  hipLaunchKernelGGL(k_bscan, dim3(1),    dim3(256), 0, stream, btot, bbase, start_, NB, N, EE);
  hipLaunchKernelGGL(k_bfill, dim3(NBLK), dim3(256), 0, stream, src, dst, bh, bbase, pairs, E, EE, NB);
  hipLaunchKernelGGL(k_pb,    dim3(NB),   dim3(256), 0, stream, bbase, pairs, start_, csr_src, N);
  // layer 1 aggregation
  hipLaunchKernelGGL(k_agg1, dim3((N+3)/4), dim3(256), 0, stream, start_, csr_src, a_s1, a_d1, h1p, acc1h, N);
  // layer 2
  hipLaunchKernelGGL(k_layer2, dim3((N+7)/8), dim3(256), 0, stream, acc1h, b1, W2, as2, ad2, (__half*)h2ph, a_s2, a_d2, N);
  hipLaunchKernelGGL(k_agg2, dim3((N+7)/8), dim3(256), 0, stream, start_, csr_src, a_s2, a_d2, (const __half*)h2ph, b2, out, N);
}

// Round 15
// 242.302 us; speedup vs baseline: 10.4346x; 1.0366x over previous
//
#include <hip/hip_runtime.h>
#include <hip/hip_fp16.h>
#include <math.h>

#define NEG_SLOPE 0.2f
#define NBLK 256   // partition blocks; bh layout depends on this

typedef _Float16 half8 __attribute__((ext_vector_type(8)));
typedef _Float16 half4 __attribute__((ext_vector_type(4)));
typedef float f32x4 __attribute__((ext_vector_type(4)));
typedef float f32x2 __attribute__((ext_vector_type(2)));

__device__ __forceinline__ float lrelu(float x){ return x > 0.f ? x : NEG_SLOPE*x; }

// ---------------- prep: Wt[p][256] fp16 = W1[k][pi(p)], pi(p)=(p&15)*8+(p>>4) ----------------
__global__ void k_prepw(const float* __restrict__ W, _Float16* __restrict__ Wt){
  int t = blockIdx.x*blockDim.x + threadIdx.x;   // 32768
  int p = t >> 8, k = t & 255;
  int c = ((p & 15) << 3) | (p >> 4);
  Wt[t] = (_Float16)W[k*128 + c];
}

// ---------------- K1: fused GEMM + fp8 pack + attention logits ----------------
// 128x128 tile, 8 waves (512 thr), BK=32, reg-prefetch + LDS dbuf. Wave w owns
// rows w*16..w*16+15 (1 M-frag x 8 N-frags). Occupancy-first: 3 blk/CU x 8 waves.
__global__ __launch_bounds__(512) void k_gemm1(const float* __restrict__ x,
                                               const _Float16* __restrict__ Wt,
                                               const float* __restrict__ as_w,
                                               const float* __restrict__ ad_w,
                                               unsigned* __restrict__ h1p,
                                               float* __restrict__ a_s,
                                               float* __restrict__ a_d, int N){
  __shared__ _Float16 aL[2][128*40];
  __shared__ _Float16 bL[2][128*40];
  int tid = threadIdx.x;
  int w = tid >> 6, lane = tid & 63;
  int fq = lane >> 4, fr = lane & 15;
  int row0 = blockIdx.x * 128;
  f32x4 acc[8];
  #pragma unroll
  for (int n=0;n<8;n++) acc[n] = (f32x4){0.f,0.f,0.f,0.f};

  int rA = tid>>2, kcA = (tid&3)*8;     // A: 8 floats/thread (2 float4)
  float4 va0, va1; half8 vb;

  // ---- load tile 0 ----
  {
    int gr = row0 + rA;
    va0 = make_float4(0.f,0.f,0.f,0.f);
    va1 = make_float4(0.f,0.f,0.f,0.f);
    if (gr < N){
      va0 = *(const float4*)&x[(size_t)gr*256 + kcA];
      va1 = *(const float4*)&x[(size_t)gr*256 + kcA + 4];
    }
    vb = *(const half8*)&Wt[(size_t)rA*256 + kcA];
  }
  // ---- write tile 0 ----
  {
    half8 hv;
    hv[0]=(_Float16)va0.x; hv[1]=(_Float16)va0.y; hv[2]=(_Float16)va0.z; hv[3]=(_Float16)va0.w;
    hv[4]=(_Float16)va1.x; hv[5]=(_Float16)va1.y; hv[6]=(_Float16)va1.z; hv[7]=(_Float16)va1.w;
    *(half8*)&aL[0][rA*40 + kcA] = hv;
    *(half8*)&bL[0][rA*40 + kcA] = vb;
  }
  __syncthreads();

  int cur = 0;
  for (int ki=0; ki<8; ki++){
    int kk = ki*32;
    if (ki < 7){   // prefetch next K-tile into registers
      int gr = row0 + rA;
      va0 = make_float4(0.f,0.f,0.f,0.f);
      va1 = make_float4(0.f,0.f,0.f,0.f);
      if (gr < N){
        va0 = *(const float4*)&x[(size_t)gr*256 + kk + 32 + kcA];
        va1 = *(const float4*)&x[(size_t)gr*256 + kk + 32 + kcA + 4];
      }
      vb = *(const half8*)&Wt[(size_t)rA*256 + kk + 32 + kcA];
    }
    int kb = fq*8;
    half8 afrag = *(half8*)&aL[cur][(w*16 + fr)*40 + kb];
    half8 bfrag[8];
    #pragma unroll
    for (int n=0;n<8;n++) bfrag[n] = *(half8*)&bL[cur][(n*16 + fr)*40 + kb];
    #pragma unroll
    for (int n=0;n<8;n++)
      acc[n] = __builtin_amdgcn_mfma_f32_16x16x32_f16(afrag, bfrag[n], acc[n], 0, 0, 0);
    if (ki < 7){
      half8 hv;
      hv[0]=(_Float16)va0.x; hv[1]=(_Float16)va0.y; hv[2]=(_Float16)va0.z; hv[3]=(_Float16)va0.w;
      hv[4]=(_Float16)va1.x; hv[5]=(_Float16)va1.y; hv[6]=(_Float16)va1.z; hv[7]=(_Float16)va1.w;
      *(half8*)&aL[cur^1][rA*40 + kcA] = hv;
      *(half8*)&bL[cur^1][rA*40 + kcA] = vb;
      __syncthreads();
      cur ^= 1;
    }
  }
  // fused epilogue: lane (fq,fr) holds channels fr*8..fr*8+7 of rows w*16+fq*4+j
  int head = fr >> 1;
  const float* wsp = &as_w[head*16 + (fr&1)*8];
  const float* wdp = &ad_w[head*16 + (fr&1)*8];
  #pragma unroll
  for (int j=0;j<4;j++){
    int gr = row0 + w*16 + fq*4 + j;   // same for all fr lanes
    if (gr < N){
      float f[8];
      #pragma unroll
      for (int n=0;n<8;n++) f[n] = acc[n][j];
      int w0 = 0, w1 = 0;
      w0 = __builtin_amdgcn_cvt_pk_fp8_f32(f[0], f[1], w0, false);
      w0 = __builtin_amdgcn_cvt_pk_fp8_f32(f[2], f[3], w0, true);
      w1 = __builtin_amdgcn_cvt_pk_fp8_f32(f[4], f[5], w1, false);
      w1 = __builtin_amdgcn_cvt_pk_fp8_f32(f[6], f[7], w1, true);
      *(uint2*)&h1p[(size_t)gr*32 + fr*2] = make_uint2((unsigned)w0,(unsigned)w1);
      float s=0.f, dd=0.f;
      #pragma unroll
      for (int n=0;n<8;n++){ s = fmaf(f[n], wsp[n], s); dd = fmaf(f[n], wdp[n], dd); }
      s  += __shfl_xor(s, 1);
      dd += __shfl_xor(dd, 1);
      if (!(fr & 1)){ a_s[(size_t)gr*8+head] = s; a_d[(size_t)gr*8+head] = dd; }
    }
  }
}

// ---------------- CSR: per-block bucket histogram ----------------
__global__ __launch_bounds__(256) void k_bh(const int* __restrict__ dst, int* __restrict__ bh,
                                            int E, int EE, int NB){
  __shared__ int h[1024];
  int tid = threadIdx.x, blk = blockIdx.x;
  for (int i=tid;i<1024;i+=256) h[i]=0;
  __syncthreads();
  int chunk = (EE + NBLK - 1)/NBLK;
  int e0 = blk*chunk, e1 = min(e0+chunk, EE);
  for (int e=e0+tid; e<e1; e+=256){
    int d = (e<E)? dst[e] : (e-E);
    atomicAdd(&h[d>>7], 1);
  }
  __syncthreads();
  for (int i=tid;i<NB;i+=256) bh[i*NBLK + blk] = h[i];
}

// ---------------- CSR: per-bucket scan over blocks ----------------
__global__ __launch_bounds__(256) void k_scanA(int* __restrict__ bh, int* __restrict__ btot){
  __shared__ int t[256];
  int b = blockIdx.x, tid = threadIdx.x;
  int v = bh[b*NBLK + tid];
  t[tid] = v;
  __syncthreads();
  for (int off=1; off<256; off<<=1){
    int p = (tid>=off)? t[tid-off] : 0;
    __syncthreads();
    t[tid] += p;
    __syncthreads();
  }
  bh[b*NBLK + tid] = t[tid] - v;
  if (tid==255) btot[b] = t[255];
}

// ---------------- CSR: scan of bucket totals -> bucket bases ----------------
__global__ __launch_bounds__(256) void k_bscan(const int* __restrict__ btot, int* __restrict__ bbase,
                                               int* __restrict__ start_, int NB, int N, int EE){
  __shared__ int t[256];
  int tid = threadIdx.x;
  int i0 = tid*4;
  int a0 = (i0+0<NB)? btot[i0+0] : 0;
  int a1 = (i0+1<NB)? btot[i0+1] : 0;
  int a2 = (i0+2<NB)? btot[i0+2] : 0;
  int a3 = (i0+3<NB)? btot[i0+3] : 0;
  int s = a0+a1+a2+a3;
  t[tid] = s;
  __syncthreads();
  for (int off=1; off<256; off<<=1){
    int p = (tid>=off)? t[tid-off] : 0;
    __syncthreads();
    t[tid] += p;
    __syncthreads();
  }
  int excl = t[tid] - s;
  int e0=excl, e1=e0+a0, e2=e1+a1, e3=e2+a2;
  if (i0+0<NB) bbase[i0+0]=e0;
  if (i0+1<NB) bbase[i0+1]=e1;
  if (i0+2<NB) bbase[i0+2]=e2;
  if (i0+3<NB) bbase[i0+3]=e3;
  if (tid==0){ bbase[NB] = EE; start_[N] = EE; }
}

// ---------------- CSR: stable partition fill (packed u32 pairs) ----------------
__global__ __launch_bounds__(256) void k_bfill(const int* __restrict__ src, const int* __restrict__ dst,
                       const int* __restrict__ bh, const int* __restrict__ bbase,
                       unsigned* __restrict__ pairs, int E, int EE, int NB){
  __shared__ int cur[1024];
  int tid = threadIdx.x, blk = blockIdx.x;
  for (int i=tid;i<NB;i+=256) cur[i] = bbase[i] + bh[i*NBLK + blk];
  __syncthreads();
  int chunk = (EE + NBLK - 1)/NBLK;
  int e0 = blk*chunk, e1 = min(e0+chunk, EE);
  for (int e=e0+tid; e<e1; e+=256){
    int s,d;
    if (e<E){ s=src[e]; d=dst[e]; } else { s=e-E; d=s; }
    int p = atomicAdd(&cur[d>>7], 1);
    pairs[p] = ((unsigned)s << 7) | (unsigned)(d & 127);
  }
}

// ---------------- CSR: per-bucket local sort -> start_[] + csr_src ----------------
__global__ __launch_bounds__(256) void k_pb(const int* __restrict__ bbase, const unsigned* __restrict__ pairs,
                    int* __restrict__ start_, int* __restrict__ csr_src, int N){
  __shared__ int hist[128];
  __shared__ int excl[128];
  int b = blockIdx.x;
  int tid = threadIdx.x;
  int base = bbase[b], cnt = bbase[b+1] - base;
  if (tid<128) hist[tid]=0;
  __syncthreads();
  for (int i=tid;i<cnt;i+=256){
    unsigned p = pairs[base+i];
    atomicAdd(&hist[p & 127], 1);
  }
  __syncthreads();
  if (tid < 128) excl[tid] = hist[tid];
  __syncthreads();
  for (int off=1; off<128; off<<=1){
    int p=0;
    if (tid<128 && tid>=off) p = excl[tid-off];
    __syncthreads();
    if (tid<128) excl[tid] += p;
    __syncthreads();
  }
  if (tid < 128){
    int e = excl[tid] - hist[tid];
    int node = (b<<7) + tid;
    if (node < N) start_[node] = base + e;
    hist[tid] = e;
  }
  __syncthreads();
  for (int i=tid;i<cnt;i+=256){
    unsigned p = pairs[base+i];
    int pos = atomicAdd(&hist[p & 127], 1);
    csr_src[base + pos] = (int)(p >> 7);
  }
}

// ---------------- K4: gather aggregation layer 1 (fp8, 16 lanes/edge) ----------------
__global__ __launch_bounds__(256) void k_agg1(const int* __restrict__ start, const int* __restrict__ csr_src,
                      const float* __restrict__ a_s, const float* __restrict__ a_d,
                      const unsigned* __restrict__ h1p, _Float16* __restrict__ acc1h, int N){
  int wid = (blockIdx.x*blockDim.x + threadIdx.x) >> 6;
  int lane = threadIdx.x & 63;
  if (wid >= N) return;
  int d = wid;
  int grp = lane >> 4;
  int fr  = lane & 15;
  int head = fr >> 1;
  float ad = a_d[(size_t)d*8 + head];
  int beg = start[d], end = start[d+1];
  float a0=0.f,a1=0.f,a2=0.f,a3=0.f,a4=0.f,a5=0.f,a6=0.f,a7=0.f,den=0.f;
  int j = beg + grp;
  for (; j + 4 < end; j += 8){
    int s0 = csr_src[j];
    int s1 = csr_src[j+4];
    float e0 = __expf(lrelu(a_s[(size_t)s0*8 + head] + ad));
    float e1 = __expf(lrelu(a_s[(size_t)s1*8 + head] + ad));
    uint2 u0 = *(const uint2*)&h1p[(size_t)s0*32 + fr*2];
    uint2 u1 = *(const uint2*)&h1p[(size_t)s1*32 + fr*2];
    f32x2 p0 = __builtin_amdgcn_cvt_pk_f32_fp8((int)u0.x, false), p1 = __builtin_amdgcn_cvt_pk_f32_fp8((int)u0.x, true);
    f32x2 p2 = __builtin_amdgcn_cvt_pk_f32_fp8((int)u0.y, false), p3 = __builtin_amdgcn_cvt_pk_f32_fp8((int)u0.y, true);
    f32x2 q0 = __builtin_amdgcn_cvt_pk_f32_fp8((int)u1.x, false), q1 = __builtin_amdgcn_cvt_pk_f32_fp8((int)u1.x, true);
    f32x2 q2 = __builtin_amdgcn_cvt_pk_f32_fp8((int)u1.y, false), q3 = __builtin_amdgcn_cvt_pk_f32_fp8((int)u1.y, true);
    a0 = fmaf(e0, p0.x, a0); a1 = fmaf(e0, p0.y, a1); a2 = fmaf(e0, p1.x, a2); a3 = fmaf(e0, p1.y, a3);
    a4 = fmaf(e0, p2.x, a4); a5 = fmaf(e0, p2.y, a5); a6 = fmaf(e0, p3.x, a6); a7 = fmaf(e0, p3.y, a7);
    a0 = fmaf(e1, q0.x, a0); a1 = fmaf(e1, q0.y, a1); a2 = fmaf(e1, q1.x, a2); a3 = fmaf(e1, q1.y, a3);
    a4 = fmaf(e1, q2.x, a4); a5 = fmaf(e1, q2.y, a5); a6 = fmaf(e1, q3.x, a6); a7 = fmaf(e1, q3.y, a7);
    den += e0 + e1;
  }
  if (j < end){
    int s0 = csr_src[j];
    float e0 = __expf(lrelu(a_s[(size_t)s0*8 + head] + ad));
    uint2 u0 = *(const uint2*)&h1p[(size_t)s0*32 + fr*2];
    f32x2 p0 = __builtin_amdgcn_cvt_pk_f32_fp8((int)u0.x, false), p1 = __builtin_amdgcn_cvt_pk_f32_fp8((int)u0.x, true);
    f32x2 p2 = __builtin_amdgcn_cvt_pk_f32_fp8((int)u0.y, false), p3 = __builtin_amdgcn_cvt_pk_f32_fp8((int)u0.y, true);
    a0 = fmaf(e0, p0.x, a0); a1 = fmaf(e0, p0.y, a1); a2 = fmaf(e0, p1.x, a2); a3 = fmaf(e0, p1.y, a3);
    a4 = fmaf(e0, p2.x, a4); a5 = fmaf(e0, p2.y, a5); a6 = fmaf(e0, p3.x, a6); a7 = fmaf(e0, p3.y, a7);
    den += e0;
  }
  a0 += __shfl_xor(a0,16); a1 += __shfl_xor(a1,16); a2 += __shfl_xor(a2,16); a3 += __shfl_xor(a3,16);
  a4 += __shfl_xor(a4,16); a5 += __shfl_xor(a5,16); a6 += __shfl_xor(a6,16); a7 += __shfl_xor(a7,16);
  den += __shfl_xor(den,16);
  a0 += __shfl_xor(a0,32); a1 += __shfl_xor(a1,32); a2 += __shfl_xor(a2,32); a3 += __shfl_xor(a3,32);
  a4 += __shfl_xor(a4,32); a5 += __shfl_xor(a5,32); a6 += __shfl_xor(a6,32); a7 += __shfl_xor(a7,32);
  den += __shfl_xor(den,32);
  float inv = (den > 0.f) ? 1.f/den : 0.f;
  if (grp == 0){
    half8 o;
    o[0]=(_Float16)(a0*inv); o[1]=(_Float16)(a1*inv); o[2]=(_Float16)(a2*inv); o[3]=(_Float16)(a3*inv);
    o[4]=(_Float16)(a4*inv); o[5]=(_Float16)(a5*inv); o[6]=(_Float16)(a6*inv); o[7]=(_Float16)(a7*inv);
    *(half8*)&acc1h[(size_t)d*128 + fr*8] = o;
  }
}

// ---------------- K5: elu + per-node [128]x[128,32] projection + layer-2 logits ----------------
__global__ __launch_bounds__(256) void k_layer2(const _Float16* __restrict__ acc1h, const float* __restrict__ b1,
                        const float* __restrict__ W2, const float* __restrict__ as2w,
                        const float* __restrict__ ad2w,
                        __half* __restrict__ h2ph, float* __restrict__ a_s2,
                        float* __restrict__ a_d2, int N){
  __shared__ float w2s[128][32];
  __shared__ float hs[8][128];
  int tid = threadIdx.x;
  #pragma unroll
  for (int it=0; it<16; it++){
    int idx = it*256 + tid;
    ((float*)w2s)[idx] = W2[idx];
  }
  int sub = tid>>5, ln = tid&31;
  int n = blockIdx.x*8 + sub;
  if (n < N){
    half4 hv = *(const half4*)&acc1h[(size_t)n*128 + ln*4];
    float4 bb = *(const float4*)&b1[ln*4];
    float v0 = (float)hv[0] + bb.x;
    float v1 = (float)hv[1] + bb.y;
    float v2 = (float)hv[2] + bb.z;
    float v3 = (float)hv[3] + bb.w;
    hs[sub][ln*4+0] = v0 > 0.f ? v0 : (__expf(v0) - 1.f);
    hs[sub][ln*4+1] = v1 > 0.f ? v1 : (__expf(v1) - 1.f);
    hs[sub][ln*4+2] = v2 > 0.f ? v2 : (__expf(v2) - 1.f);
    hs[sub][ln*4+3] = v3 > 0.f ? v3 : (__expf(v3) - 1.f);
  }
  __syncthreads();
  if (n >= N) return;
  float o = 0.f;
  #pragma unroll
  for (int k=0;k<128;k++) o = fmaf(hs[sub][k], w2s[k][ln], o);
  h2ph[(size_t)n*32+ln] = __float2half_rn(o);
  float ps = o*as2w[ln], pd = o*ad2w[ln];
  #pragma unroll
  for (int m=16;m;m>>=1){ ps += __shfl_xor(ps,m); pd += __shfl_xor(pd,m); }
  if (ln==0){ a_s2[n]=ps; a_d2[n]=pd; }
}

// ---------------- K6: gather aggregation layer 2 + bias + log_softmax ----------------
__global__ __launch_bounds__(256) void k_agg2(const int* __restrict__ start, const int* __restrict__ csr_src,
                      const float* __restrict__ a_s2, const float* __restrict__ a_d2,
                      const __half* __restrict__ h2ph, const float* __restrict__ b2,
                      float* __restrict__ out, int N){
  int g = (blockIdx.x*blockDim.x + threadIdx.x) >> 5;
  int ln = threadIdx.x & 31;
  if (g >= N) return;
  int d = g;
  int grp = ln >> 4;
  int l16 = ln & 15;
  float ad = a_d2[d];
  int beg = start[d], end = start[d+1];
  float accx=0.f, accy=0.f, den=0.f;
  int j = beg + grp;
  for (; j + 6 < end; j += 8){
    int s0 = csr_src[j];
    int s1 = csr_src[j+2];
    int s2 = csr_src[j+4];
    int s3 = csr_src[j+6];
    float e0 = __expf(lrelu(a_s2[s0] + ad));
    float e1 = __expf(lrelu(a_s2[s1] + ad));
    float e2 = __expf(lrelu(a_s2[s2] + ad));
    float e3 = __expf(lrelu(a_s2[s3] + ad));
    float2 v0 = __half22float2(*(const __half2*)&h2ph[(size_t)s0*32 + l16*2]);
    float2 v1 = __half22float2(*(const __half2*)&h2ph[(size_t)s1*32 + l16*2]);
    float2 v2 = __half22float2(*(const __half2*)&h2ph[(size_t)s2*32 + l16*2]);
    float2 v3 = __half22float2(*(const __half2*)&h2ph[(size_t)s3*32 + l16*2]);
    accx = fmaf(e0, v0.x, accx); accy = fmaf(e0, v0.y, accy);
    accx = fmaf(e1, v1.x, accx); accy = fmaf(e1, v1.y, accy);
    accx = fmaf(e2, v2.x, accx); accy = fmaf(e2, v2.y, accy);
    accx = fmaf(e3, v3.x, accx); accy = fmaf(e3, v3.y, accy);
    den += (e0 + e1) + (e2 + e3);
  }
  for (; j < end; j += 2){
    int s0 = csr_src[j];
    float e0 = __expf(lrelu(a_s2[s0] + ad));
    float2 v0 = __half22float2(*(const __half2*)&h2ph[(size_t)s0*32 + l16*2]);
    accx = fmaf(e0, v0.x, accx); accy = fmaf(e0, v0.y, accy);
    den += e0;
  }
  accx += __shfl_xor(accx, 16);
  accy += __shfl_xor(accy, 16);
  den  += __shfl_xor(den, 16);
  float2 bb = *(const float2*)&b2[l16*2];
  float vx = accx/den + bb.x;
  float vy = accy/den + bb.y;
  float mx = fmaxf(vx, vy);
  #pragma unroll
  for (int m=8;m;m>>=1) mx = fmaxf(mx, __shfl_xor(mx, m));
  float sm = __expf(vx-mx) + __expf(vy-mx);
  #pragma unroll
  for (int m=8;m;m>>=1) sm += __shfl_xor(sm, m);
  float lg = mx + __logf(sm);
  if (grp == 0){
    float2 o = make_float2(vx - lg, vy - lg);
    *(float2*)&out[(size_t)d*32 + l16*2] = o;
  }
}

extern "C" void kernel_launch(void* const* d_in, const int* in_sizes, int n_in,
                              void* d_out, int out_size, void* d_ws, size_t ws_size,
                              hipStream_t stream){
  const float* x   = (const float*)d_in[0];
  const int*   ei  = (const int*)d_in[1];
  const float* W1  = (const float*)d_in[3];
  const float* as1 = (const float*)d_in[4];
  const float* ad1 = (const float*)d_in[5];
  const float* b1  = (const float*)d_in[6];
  const float* W2  = (const float*)d_in[7];
  const float* as2 = (const float*)d_in[8];
  const float* ad2 = (const float*)d_in[9];
  const float* b2  = (const float*)d_in[10];

  int N  = in_sizes[0] / 256;
  int E  = in_sizes[2];
  int EE = E + N;
  const int* src = ei;
  const int* dst = ei + E;

  int NB = (N + 127) >> 7;   // 128 nodes per bucket

  // ---- workspace layout ----
  int* iw = (int*)d_ws;
  int* bh      = iw;                 iw += 1024*NBLK;
  int* btot    = iw;                 iw += 1024;
  int* bbase   = iw;                 iw += 1028;
  int* start_  = iw;                 iw += ((N+1+3)/4)*4;
  int* csr_src = iw;                 iw += ((EE+3)/4)*4;

  float* w = (float*)iw;
  float* a_s1   = w; w += (size_t)N*8;
  float* a_d1   = w; w += (size_t)N*8;
  float* a_s2   = w; w += (size_t)N;
  float* a_d2   = w; w += (size_t)N;
  _Float16* acc1h = (_Float16*)w; w += (size_t)N*64;   // N*128 halfs
  _Float16* h2ph = (_Float16*)w; w += (size_t)N*16;    // N*32 halfs
  _Float16* Wt   = (_Float16*)w; w += 32768/2;
  unsigned* h1p  = (unsigned*)w; w += (size_t)N*16;    // N*32 u32 (fp8 payload)
  float* out    = (float*)d_out;

  // pairs (u32, EE) overlays acc1h (dead until k_agg1)
  unsigned* pairs = (unsigned*)acc1h;

  hipLaunchKernelGGL(k_prepw, dim3(128), dim3(256), 0, stream, W1, Wt);
  hipLaunchKernelGGL(k_gemm1, dim3((N+127)/128), dim3(512), 0, stream, x, Wt, as1, ad1, h1p, a_s1, a_d1, N);
  // CSR build
  hipLaunchKernelGGL(k_bh,    dim3(NBLK), dim3(256), 0, stream, dst, bh, E, EE, NB);
  hipLaunchKernelGGL(k_scanA, dim3(NB),   dim3(256), 0, stream, bh, btot);
  hipLaunchKernelGGL(k_bscan, dim3(1),    dim3(256), 0, stream, btot, bbase, start_, NB, N, EE);
  hipLaunchKernelGGL(k_bfill, dim3(NBLK), dim3(256), 0, stream, src, dst, bh, bbase, pairs, E, EE, NB);
  hipLaunchKernelGGL(k_pb,    dim3(NB),   dim3(256), 0, stream, bbase, pairs, start_, csr_src, N);
  // layer 1 aggregation
  hipLaunchKernelGGL(k_agg1, dim3((N+3)/4), dim3(256), 0, stream, start_, csr_src, a_s1, a_d1, h1p, acc1h, N);
  // layer 2
  hipLaunchKernelGGL(k_layer2, dim3((N+7)/8), dim3(256), 0, stream, acc1h, b1, W2, as2, ad2, (__half*)h2ph, a_s2, a_d2, N);
  hipLaunchKernelGGL(k_agg2, dim3((N+7)/8), dim3(256), 0, stream, start_, csr_src, a_s2, a_d2, (const __half*)h2ph, b2, out, N);
}